// Round 3
// baseline (1448.322 us; speedup 1.0000x reference)
//
#include <hip/hip_runtime.h>
#include <hip/hip_bf16.h>
#include <math.h>

typedef __hip_bfloat16 bf16;

#define NB 32
#define NC 32
#define NNODE 300
#define NT 64
#define NDIM 40
#define KTOP 20
#define NSKIP 64
#define NTOUT 58
#define SLAB 17400        // NNODE*NTOUT (out layout)
#define BSLAB 556800      // NC*SLAB
#define XEL 17817600      // NB*BSLAB
#define PSLAB 2048        // NC*64 padded node slab
#define BPSLAB 614400     // NNODE*PSLAB
#define XPEL 19660800     // NB*BPSLAB

__device__ __forceinline__ float b2f(bf16 v){ return __bfloat162float(v); }
__device__ __forceinline__ bf16 f2b(float v){ return __float2bfloat16(v); }
__device__ __forceinline__ float fsig(float x){ return 1.0f/(1.0f + __expf(-x)); }
__device__ __forceinline__ float ftanh(float x){ return 2.0f*fsig(2.0f*x) - 1.0f; }

// XCD-aware swizzle for 9600-block graph kernels: XCD k gets b in [k*4, k*4+4)
__device__ __forceinline__ void bv_swz(int bid, int& b, int& v){
  int xcd = bid & 7, i = bid >> 3;
  int nb = xcd*1200 + i;
  b = nb / NNODE; v = nb - b*NNODE;
}

// ---------------- graph construction ----------------
__global__ void k_nodes(const float* __restrict__ emb1, const float* __restrict__ emb2,
                        const float* __restrict__ l1w, const float* __restrict__ l1b,
                        const float* __restrict__ l2w, const float* __restrict__ l2b,
                        const int* __restrict__ idxp,
                        float* __restrict__ n1, float* __restrict__ n2){
  int i = blockIdx.x; int d = threadIdx.x;
  if (d >= NDIM) return;
  int r = idxp[i];
  float a1 = l1b[d], a2 = l2b[d];
  for (int k=0;k<NDIM;++k){
    a1 = fmaf(emb1[r*NDIM+k], l1w[d*NDIM+k], a1);
    a2 = fmaf(emb2[r*NDIM+k], l2w[d*NDIM+k], a2);
  }
  n1[i*NDIM+d] = tanhf(3.0f*a1);
  n2[i*NDIM+d] = tanhf(3.0f*a2);
}

__global__ void __launch_bounds__(64) k_adjrow(const float* __restrict__ n1,
                                               const float* __restrict__ n2,
                                               float* __restrict__ Am){
  int i = blockIdx.x; int lane = threadIdx.x;
  __shared__ float rowo[NNODE];
  __shared__ float rowv[NNODE];
  __shared__ int   sel[NNODE];
  for (int j=lane;j<NNODE;j+=64){
    float a = 0.f;
    #pragma unroll
    for (int k=0;k<NDIM;++k){
      float a1 = n1[i*NDIM+k], a2 = n2[i*NDIM+k];
      a = fmaf(a1, n2[j*NDIM+k], a);
      a = fmaf(-a2, n1[j*NDIM+k], a);
    }
    float v = tanhf(3.0f*a);
    v = v > 0.f ? v : 0.f;
    rowo[j]=v; rowv[j]=v; sel[j]=0;
  }
  __syncthreads();
  for (int it=0; it<KTOP; ++it){
    float best = -1.f; int bi = 0x7fffffff;
    for (int j=lane;j<NNODE;j+=64){
      float v = rowv[j];
      if (v > best){ best=v; bi=j; }
    }
    #pragma unroll
    for (int off=32; off; off>>=1){
      float ov = __shfl_xor(best, off);
      int   oi = __shfl_xor(bi, off);
      if (ov > best || (ov == best && oi < bi)){ best=ov; bi=oi; }
    }
    if (lane==0){ sel[bi]=1; rowv[bi]=-2.f; }
    __syncthreads();
  }
  for (int j=lane;j<NNODE;j+=64)
    Am[i*NNODE+j] = sel[j] ? rowo[j] : 0.f;
}

__global__ void __launch_bounds__(64) k_csr(const float* __restrict__ Am,
                                            int* __restrict__ aidx, float* __restrict__ aval,
                                            int* __restrict__ acnt){
  int r = blockIdx.x; int lane = threadIdx.x;
  int v = (r < NNODE) ? r : r - NNODE;
  int*   ip = aidx + r*304;
  float* vp = aval + r*304;
  if (lane==0){ ip[0]=v; vp[0]=1.0f; }
  int cnt = 1; float s = 1.0f;
  for (int base=0; base<NNODE; base+=64){
    int j = base + lane; float val = 0.f; bool p = false;
    if (j < NNODE){
      val = (r < NNODE) ? Am[v*NNODE + j] : Am[j*NNODE + v];
      p = val > 0.f;
    }
    unsigned long long m = __ballot(p);
    int pre = __popcll(m & ((1ull << lane) - 1ull));
    if (p){ ip[cnt+pre]=j; vp[cnt+pre]=val; }
    cnt += __popcll(m);
    float vs = p ? val : 0.f;
    #pragma unroll
    for (int off=32; off; off>>=1) vs += __shfl_xor(vs, off);
    s += vs;
  }
  for (int e=lane; e<cnt; e+=64) vp[e] = vp[e] / s;
  if (lane==0) acnt[r]=cnt;
}

// ---------------- weight packing ----------------
// wp[ic*288 + w*72 + path*36 + oo*18 + s], o = 2w+oo
__global__ void k_wpack(const float* __restrict__ fw2,const float* __restrict__ fw3,
                        const float* __restrict__ fw6,const float* __restrict__ fw7,
                        const float* __restrict__ gw2,const float* __restrict__ gw3,
                        const float* __restrict__ gw6,const float* __restrict__ gw7,
                        float* __restrict__ wp){
  int T = blockIdx.x*blockDim.x + threadIdx.x;
  if (T >= 9216) return;
  int ic = T / 288, rem = T % 288;
  int w = rem / 72, r2 = rem % 72;
  int path = r2 / 36, r3 = r2 % 36;
  int oo = r3 / 18, s = r3 % 18;
  int o = w*2 + oo;
  float val;
  if (path == 0){
    if (s < 2)       val = fw2[(o*NC+ic)*2 + s];
    else if (s < 5)  val = fw3[(o*NC+ic)*3 + (s-2)];
    else if (s < 11) val = fw6[(o*NC+ic)*6 + (s-5)];
    else             val = fw7[(o*NC+ic)*7 + (s-11)];
  } else {
    if (s < 2)       val = gw2[(o*NC+ic)*2 + s];
    else if (s < 5)  val = gw3[(o*NC+ic)*3 + (s-2)];
    else if (s < 11) val = gw6[(o*NC+ic)*6 + (s-5)];
    else             val = gw7[(o*NC+ic)*7 + (s-11)];
  }
  wp[T] = val;
}

// mix weights transposed+packed:
// pk0[c2*96 + seg*32 + c]: seg0 = m1w[c,c2]+m2w[c,c2]; seg1 = m1w[c,32+c2]; seg2 = m1w[c,64+c2]
// pk1[c2*64 + seg*32 + c]: seg0 = m2w[c,32+c2]; seg1 = m2w[c,64+c2]
__global__ void k_wprep(const float* __restrict__ m1w, const float* __restrict__ m2w,
                        float* __restrict__ pk0, float* __restrict__ pk1){
  int id = blockIdx.x*blockDim.x + threadIdx.x;
  if (id < 3072){
    int c2 = id / 96, r = id % 96, seg = r / 32, c = r % 32;
    float val;
    if (seg==0)      val = m1w[c*96 + c2] + m2w[c*96 + c2];
    else if (seg==1) val = m1w[c*96 + 32 + c2];
    else             val = m1w[c*96 + 64 + c2];
    pk0[c2*96 + seg*32 + c] = val;
  } else if (id < 5120){
    int id2 = id - 3072;
    int c2 = id2 / 64, r = id2 % 64, seg = r / 32, c = r % 32;
    pk1[c2*64 + seg*32 + c] = seg==0 ? m2w[c*96 + 32 + c2] : m2w[c*96 + 64 + c2];
  }
}

// ---------------- dilated inception -> Xp[b][n][c][64] bf16 ----------------
__global__ void __launch_bounds__(256) k_incep(const float* __restrict__ x,
    const float* __restrict__ wp,
    const float* __restrict__ fb2,const float* __restrict__ fb3,const float* __restrict__ fb6,const float* __restrict__ fb7,
    const float* __restrict__ gb2,const float* __restrict__ gb3,const float* __restrict__ gb6,const float* __restrict__ gb7,
    bf16* __restrict__ Xp){
  int bn = blockIdx.x; int b = bn / NNODE, n = bn - b*NNODE;
  __shared__ float xs[PSLAB];
  {
    int tid = threadIdx.x;
    int c = tid >> 3, t0 = (tid & 7) * 8;
    const float* src = x + ((size_t)(b*NC + c)*NNODE + n)*NT + t0;
    float4 v0 = *reinterpret_cast<const float4*>(src);
    float4 v1 = *reinterpret_cast<const float4*>(src + 4);
    *reinterpret_cast<float4*>(&xs[c*64 + t0])     = v0;
    *reinterpret_cast<float4*>(&xs[c*64 + t0 + 4]) = v1;
  }
  __syncthreads();
  int lane = threadIdx.x & 63, w = threadIdx.x >> 6;
  int o0 = 2*w;
  float af[8], ag[8];
  af[0]=fb2[o0]; af[1]=fb2[o0+1]; af[2]=fb3[o0]; af[3]=fb3[o0+1];
  af[4]=fb6[o0]; af[5]=fb6[o0+1]; af[6]=fb7[o0]; af[7]=fb7[o0+1];
  ag[0]=gb2[o0]; ag[1]=gb2[o0+1]; ag[2]=gb3[o0]; ag[3]=gb3[o0+1];
  ag[4]=gb6[o0]; ag[5]=gb6[o0+1]; ag[6]=gb7[o0]; ag[7]=gb7[o0+1];
  int tc = lane < NTOUT ? lane : NTOUT-1;
  for (int ic=0; ic<NC; ++ic){
    float xv[7];
    #pragma unroll
    for (int d=0;d<7;++d) xv[d] = xs[ic*64 + tc + d];
    const float* wv = wp + ic*288 + w*72;
    #pragma unroll
    for (int oo=0;oo<2;++oo){
      const float* wf = wv + oo*18;
      const float* wg = wv + 36 + oo*18;
      af[0+oo] = fmaf(wf[0], xv[5], fmaf(wf[1], xv[6], af[0+oo]));
      ag[0+oo] = fmaf(wg[0], xv[5], fmaf(wg[1], xv[6], ag[0+oo]));
      af[2+oo] = fmaf(wf[2], xv[4], fmaf(wf[3], xv[5], fmaf(wf[4], xv[6], af[2+oo])));
      ag[2+oo] = fmaf(wg[2], xv[4], fmaf(wg[3], xv[5], fmaf(wg[4], xv[6], ag[2+oo])));
      #pragma unroll
      for (int tp=0;tp<6;++tp){ af[4+oo] = fmaf(wf[5+tp], xv[1+tp], af[4+oo]); ag[4+oo] = fmaf(wg[5+tp], xv[1+tp], ag[4+oo]); }
      #pragma unroll
      for (int tp=0;tp<7;++tp){ af[6+oo] = fmaf(wf[11+tp], xv[tp], af[6+oo]);  ag[6+oo] = fmaf(wg[11+tp], xv[tp], ag[6+oo]); }
    }
  }
  if (lane < NTOUT){
    size_t base = (size_t)bn*PSLAB + lane;
    #pragma unroll
    for (int cls=0; cls<4; ++cls){
      #pragma unroll
      for (int oo=0; oo<2; ++oo){
        int c = cls*8 + o0 + oo;
        float val = ftanh(af[cls*2+oo]) * fsig(ag[cls*2+oo]);
        Xp[base + (size_t)c*64] = f2b(val);
      }
    }
  }
}

// ---------------- skip path ----------------
__global__ void k_wT(const float* __restrict__ sw, float* __restrict__ wT){
  int id = blockIdx.x*blockDim.x + threadIdx.x;
  if (id >= 1856*64) return;
  int kk = id >> 6, sc = id & 63;
  wT[kk*64 + sc] = sw[sc*1856 + kk];
}

__global__ void __launch_bounds__(256) k_skip(const bf16* __restrict__ Xp, const float* __restrict__ wT,
      const float* __restrict__ skip_b, const float* __restrict__ x_skip, float* __restrict__ out){
  __shared__ float Xs[8*1856];
  int tid = threadIdx.x;
  int bp0 = blockIdx.x*8;
  for (int idx = tid; idx < 8*1856; idx += 256){
    int p = idx / 1856, kk = idx - p*1856;
    int c = kk / NTOUT, t = kk - c*NTOUT;
    int gp = bp0 + p; int b = gp / NNODE, n = gp - b*NNODE;
    Xs[idx] = b2f(Xp[(size_t)(b*NNODE+n)*PSLAB + c*64 + t]);
  }
  __syncthreads();
  int lane = tid & 63, w = tid >> 6;
  int kk0 = w*464;
  float acc[8] = {0,0,0,0,0,0,0,0};
  for (int kk = kk0; kk < kk0+464; kk += 4){
    float wv0 = wT[(kk+0)*64 + lane];
    float wv1 = wT[(kk+1)*64 + lane];
    float wv2 = wT[(kk+2)*64 + lane];
    float wv3 = wT[(kk+3)*64 + lane];
    #pragma unroll
    for (int p=0;p<8;++p){
      const float4 xv = *reinterpret_cast<const float4*>(&Xs[p*1856 + kk]);
      acc[p] = fmaf(xv.x, wv0, acc[p]);
      acc[p] = fmaf(xv.y, wv1, acc[p]);
      acc[p] = fmaf(xv.z, wv2, acc[p]);
      acc[p] = fmaf(xv.w, wv3, acc[p]);
    }
  }
  __syncthreads();
  float* red = Xs;
  #pragma unroll
  for (int p=0;p<8;++p) red[w*512 + p*64 + lane] = acc[p];
  __syncthreads();
  #pragma unroll
  for (int pi=0; pi<2; ++pi){
    int p = w*2 + pi;
    float s = red[p*64+lane] + red[512+p*64+lane] + red[1024+p*64+lane] + red[1536+p*64+lane];
    int gp = bp0 + p, b = gp / NNODE, n = gp - b*NNODE;
    size_t so = (size_t)b*NSKIP*NNODE + (size_t)lane*NNODE + n;
    out[(size_t)XEL + so] = s + skip_b[lane] + x_skip[so];
  }
}

// ---------------- hop1: HA = 0.05*Xp + 0.95*(Ah (x) Xp) ----------------
__global__ void __launch_bounds__(256) k_prop(const bf16* __restrict__ Xp, bf16* __restrict__ HA,
    const int* __restrict__ aidx, const float* __restrict__ aval, const int* __restrict__ acnt,
    int rowoff){
  __shared__ int   sidx[304];
  __shared__ float sval[304];
  int b, v; bv_swz(blockIdx.x, b, v);
  int r = rowoff + v;
  int cnt = acnt[r];
  for (int e = threadIdx.x; e < cnt; e += 256){
    sidx[e] = aidx[r*304 + e] * PSLAB;
    sval[e] = aval[r*304 + e];
  }
  __syncthreads();
  int lane = threadIdx.x & 63, w = threadIdx.x >> 6;
  int c0 = w*8;
  const bf16* base = Xp + (size_t)b*BPSLAB + c0*64 + lane;
  float acc[8] = {0,0,0,0,0,0,0,0};
  for (int j=0;j<cnt;++j){
    float vv = sval[j];
    const bf16* p = base + sidx[j];
    #pragma unroll
    for (int q=0;q<8;++q)
      acc[q] = fmaf(vv, b2f(p[q*64]), acc[q]);
  }
  if (lane < NTOUT){
    size_t o = (size_t)b*BPSLAB + (size_t)v*PSLAB + c0*64 + lane;
    #pragma unroll
    for (int q=0;q<8;++q){
      size_t oi = o + (size_t)q*64;
      HA[oi] = f2b(0.05f*b2f(Xp[oi]) + 0.95f*acc[q]);
    }
  }
}

// ---------------- hop2 + 1x1 mix conv, fused ----------------
// side 0: out = bias + Wsum*X + W1h1*HA + W1h2*H2          (pk0, 3 segs)
// side 1: out += W2h1*HA + W2h2*H2 + residual x[...,6+t]   (pk1, 2 segs)
__global__ void __launch_bounds__(256) k_fuse(const bf16* __restrict__ Xp, const bf16* __restrict__ HA,
    float* __restrict__ out, const float* __restrict__ x,
    const int* __restrict__ aidx, const float* __restrict__ aval, const int* __restrict__ acnt,
    const float* __restrict__ pk, const float* __restrict__ b1, const float* __restrict__ b2,
    int rowoff, int side){
  __shared__ int   sidx[304];
  __shared__ float sval[304];
  __shared__ float h2[PSLAB];
  int b, v; bv_swz(blockIdx.x, b, v);
  int r = rowoff + v;
  int cnt = acnt[r];
  for (int e = threadIdx.x; e < cnt; e += 256){
    sidx[e] = aidx[r*304 + e] * PSLAB;
    sval[e] = aval[r*304 + e];
  }
  __syncthreads();
  int lane = threadIdx.x & 63, w = threadIdx.x >> 6;
  int c0 = w*8;
  size_t bbase = (size_t)b*BPSLAB;
  size_t vbase = bbase + (size_t)v*PSLAB;
  {
    const bf16* base = HA + bbase + c0*64 + lane;
    float acc[8] = {0,0,0,0,0,0,0,0};
    for (int j=0;j<cnt;++j){
      float vv = sval[j];
      const bf16* p = base + sidx[j];
      #pragma unroll
      for (int q=0;q<8;++q)
        acc[q] = fmaf(vv, b2f(p[q*64]), acc[q]);
    }
    #pragma unroll
    for (int q=0;q<8;++q){
      float xl = b2f(Xp[vbase + (c0+q)*64 + lane]);
      h2[(c0+q)*64 + lane] = 0.05f*xl + 0.95f*acc[q];
    }
  }
  __syncthreads();
  float acc2[8];
  if (side == 0){
    #pragma unroll
    for (int q=0;q<8;++q) acc2[q] = b1[c0+q] + b2[c0+q];
    for (int c2=0;c2<NC;++c2){
      const float* wrow = pk + c2*96 + c0;
      float xl  = b2f(Xp[vbase + c2*64 + lane]);
      float hal = b2f(HA[vbase + c2*64 + lane]);
      float h2l = h2[c2*64 + lane];
      #pragma unroll
      for (int q=0;q<8;++q){
        acc2[q] = fmaf(wrow[q], xl, acc2[q]);
        acc2[q] = fmaf(wrow[32+q], hal, acc2[q]);
        acc2[q] = fmaf(wrow[64+q], h2l, acc2[q]);
      }
    }
    if (lane < NTOUT){
      #pragma unroll
      for (int q=0;q<8;++q){
        size_t o = ((size_t)(b*NC + c0+q)*NNODE + v)*NTOUT + lane;
        out[o] = acc2[q];
      }
    }
  } else {
    #pragma unroll
    for (int q=0;q<8;++q) acc2[q] = 0.f;
    for (int c2=0;c2<NC;++c2){
      const float* wrow = pk + c2*64 + c0;
      float hal = b2f(HA[vbase + c2*64 + lane]);
      float h2l = h2[c2*64 + lane];
      #pragma unroll
      for (int q=0;q<8;++q){
        acc2[q] = fmaf(wrow[q], hal, acc2[q]);
        acc2[q] = fmaf(wrow[32+q], h2l, acc2[q]);
      }
    }
    if (lane < NTOUT){
      #pragma unroll
      for (int q=0;q<8;++q){
        int c = c0 + q;
        size_t o = ((size_t)(b*NC + c)*NNODE + v)*NTOUT + lane;
        float res = x[((size_t)(b*NC + c)*NNODE + v)*NT + 6 + lane];
        out[o] = out[o] + acc2[q] + res;
      }
    }
  }
}

// ---------------- layernorm ----------------
__global__ void __launch_bounds__(256) k_lnstat(const float* __restrict__ out, double* __restrict__ part){
  int blk = blockIdx.x; int b = blk >> 3, seg = blk & 7;
  const float* p = out + (size_t)b*BSLAB;
  int start = seg*69600, end = start + 69600;
  double s = 0.0, s2 = 0.0;
  for (int i = start + threadIdx.x; i < end; i += 256){
    double v = (double)p[i]; s += v; s2 += v*v;
  }
  #pragma unroll
  for (int off=32; off; off>>=1){ s += __shfl_down(s, off); s2 += __shfl_down(s2, off); }
  __shared__ double ls[4], ls2[4];
  int lane = threadIdx.x & 63, w = threadIdx.x >> 6;
  if (lane==0){ ls[w]=s; ls2[w]=s2; }
  __syncthreads();
  if (threadIdx.x==0){
    double a=0.0, a2=0.0;
    for (int i=0;i<4;++i){ a+=ls[i]; a2+=ls2[i]; }
    part[blk*2]=a; part[blk*2+1]=a2;
  }
}

__global__ void k_lnfin(const double* __restrict__ part, float* __restrict__ stats){
  int b = threadIdx.x; if (b >= 32) return;
  double s=0.0, s2=0.0;
  for (int seg=0; seg<8; ++seg){ s += part[(b*8+seg)*2]; s2 += part[(b*8+seg)*2+1]; }
  double n = (double)BSLAB;
  double mean = s/n;
  double var = s2/n - mean*mean;
  stats[b*2]   = (float)mean;
  stats[b*2+1] = (float)(1.0/sqrt(var + 1e-5));
}

__global__ void __launch_bounds__(256) k_lnapply(float* __restrict__ out, const float* __restrict__ stats,
        const float* __restrict__ lnw, const float* __restrict__ lnb, const int* __restrict__ idxp){
  int o = blockIdx.x*256 + threadIdx.x;
  int t = o % NTOUT; int v = (o / NTOUT) % NNODE; int c = (o / SLAB) % NC; int b = o / BSLAB;
  float mean = stats[b*2], rstd = stats[b*2+1];
  int vn = idxp[v];
  float wv = lnw[((size_t)c*NNODE + vn)*NTOUT + t];
  float bv = lnb[((size_t)c*NNODE + vn)*NTOUT + t];
  float vx = out[o];
  out[o] = (vx - mean)*rstd*wv + bv;
}

extern "C" void kernel_launch(void* const* d_in, const int* in_sizes, int n_in,
                              void* d_out, int out_size, void* d_ws, size_t ws_size,
                              hipStream_t stream) {
  (void)in_sizes; (void)n_in; (void)out_size; (void)ws_size;
  const float* x     = (const float*)d_in[0];
  const float* xskip = (const float*)d_in[1];
  const int*   idxp  = (const int*)d_in[2];
  const float* emb1  = (const float*)d_in[3];
  const float* emb2  = (const float*)d_in[4];
  const float* l1w   = (const float*)d_in[5];
  const float* l1b   = (const float*)d_in[6];
  const float* l2w   = (const float*)d_in[7];
  const float* l2b   = (const float*)d_in[8];
  const float* skw   = (const float*)d_in[9];
  const float* skb   = (const float*)d_in[10];
  const float* m1w   = (const float*)d_in[11];
  const float* m1b   = (const float*)d_in[12];
  const float* m2w   = (const float*)d_in[13];
  const float* m2b   = (const float*)d_in[14];
  const float* lnw   = (const float*)d_in[15];
  const float* lnb   = (const float*)d_in[16];
  const float* fw2=(const float*)d_in[17]; const float* fb2=(const float*)d_in[18];
  const float* gw2=(const float*)d_in[19]; const float* gb2=(const float*)d_in[20];
  const float* fw3=(const float*)d_in[21]; const float* fb3=(const float*)d_in[22];
  const float* gw3=(const float*)d_in[23]; const float* gb3=(const float*)d_in[24];
  const float* fw6=(const float*)d_in[25]; const float* fb6=(const float*)d_in[26];
  const float* gw6=(const float*)d_in[27]; const float* gb6=(const float*)d_in[28];
  const float* fw7=(const float*)d_in[29]; const float* fb7=(const float*)d_in[30];
  const float* gw7=(const float*)d_in[31]; const float* gb7=(const float*)d_in[32];
  float* out = (float*)d_out;

  char* wsbase = (char*)d_ws;
  size_t cur = 0;
  auto alloc = [&](size_t bytes)->char*{
    char* p = wsbase + cur;
    cur = (cur + bytes + 255) & ~(size_t)255;
    return p;
  };
  bf16*  Xp   = (bf16*) alloc((size_t)XPEL*2);
  bf16*  HA   = (bf16*) alloc((size_t)XPEL*2);
  float* n1   = (float*)alloc(12000*4);
  float* n2   = (float*)alloc(12000*4);
  float* Am   = (float*)alloc(90000*4);
  int*   aidx = (int*)  alloc(600*304*4);
  float* aval = (float*)alloc(600*304*4);
  int*   acnt = (int*)  alloc(600*4);
  float* wT   = (float*)alloc(1856*64*4);
  float* wp   = (float*)alloc(9216*4);
  float* pk0  = (float*)alloc(3072*4);
  float* pk1  = (float*)alloc(2048*4);
  double* part = (double*)alloc(256*2*8);
  float* stats = (float*)alloc(64*4);

  // graph construction (tiny)
  k_nodes <<<NNODE, 64, 0, stream>>>(emb1, emb2, l1w, l1b, l2w, l2b, idxp, n1, n2);
  k_adjrow<<<NNODE, 64, 0, stream>>>(n1, n2, Am);
  k_csr   <<<2*NNODE, 64, 0, stream>>>(Am, aidx, aval, acnt);

  // weight prep
  k_wpack<<<36, 256, 0, stream>>>(fw2,fw3,fw6,fw7, gw2,gw3,gw6,gw7, wp);
  k_wprep<<<20, 256, 0, stream>>>(m1w, m2w, pk0, pk1);
  k_wT   <<<464, 256, 0, stream>>>(skw, wT);

  // dilated inception -> Xp
  k_incep<<<NB*NNODE, 256, 0, stream>>>(x, wp, fb2,fb3,fb6,fb7, gb2,gb3,gb6,gb7, Xp);

  // skip path
  k_skip<<<(NB*NNODE)/8, 256, 0, stream>>>(Xp, wT, skb, xskip, out);

  // mixprop side 0 (A)
  k_prop<<<NB*NNODE, 256, 0, stream>>>(Xp, HA, aidx, aval, acnt, 0);
  k_fuse<<<NB*NNODE, 256, 0, stream>>>(Xp, HA, out, x, aidx, aval, acnt, pk0, m1b, m2b, 0, 0);

  // mixprop side 1 (A^T)
  k_prop<<<NB*NNODE, 256, 0, stream>>>(Xp, HA, aidx, aval, acnt, NNODE);
  k_fuse<<<NB*NNODE, 256, 0, stream>>>(Xp, HA, out, x, aidx, aval, acnt, pk1, m1b, m2b, NNODE, 1);

  // layernorm
  k_lnstat<<<256, 256, 0, stream>>>(out, part);
  k_lnfin<<<1, 32, 0, stream>>>(part, stats);
  k_lnapply<<<XEL/256, 256, 0, stream>>>(out, stats, lnw, lnb, idxp);
}

// Round 4
// 1002.210 us; speedup vs baseline: 1.4451x; 1.4451x over previous
//
#include <hip/hip_runtime.h>
#include <hip/hip_bf16.h>
#include <math.h>

typedef __hip_bfloat16 bf16;

#define NB 32
#define NC 32
#define NNODE 300
#define NT 64
#define NDIM 40
#define KTOP 20
#define NSKIP 64
#define NTOUT 58
#define SLAB 17400        // NNODE*NTOUT (out layout)
#define BSLAB 556800      // NC*SLAB
#define XEL 17817600      // NB*BSLAB
#define PSLAB 2048        // NC*64 padded node slab
#define BPSLAB 614400     // NNODE*PSLAB
#define XPEL 19660800     // NB*BPSLAB

__device__ __forceinline__ float b2f(bf16 v){ return __bfloat162float(v); }
__device__ __forceinline__ bf16 f2b(float v){ return __float2bfloat16(v); }
__device__ __forceinline__ float fsig(float x){ return 1.0f/(1.0f + __expf(-x)); }
__device__ __forceinline__ float ftanh(float x){ return 2.0f*fsig(2.0f*x) - 1.0f; }

// XCD-aware swizzle for 9600-block graph kernels: XCD k gets b in [k*4, k*4+4)
__device__ __forceinline__ void bv_swz(int bid, int& b, int& v){
  int xcd = bid & 7, i = bid >> 3;
  int nb = xcd*1200 + i;
  b = nb / NNODE; v = nb - b*NNODE;
}

// ---------------- graph construction ----------------
__global__ void k_nodes(const float* __restrict__ emb1, const float* __restrict__ emb2,
                        const float* __restrict__ l1w, const float* __restrict__ l1b,
                        const float* __restrict__ l2w, const float* __restrict__ l2b,
                        const int* __restrict__ idxp,
                        float* __restrict__ n1, float* __restrict__ n2){
  int i = blockIdx.x; int d = threadIdx.x;
  if (d >= NDIM) return;
  int r = idxp[i];
  float a1 = l1b[d], a2 = l2b[d];
  for (int k=0;k<NDIM;++k){
    a1 = fmaf(emb1[r*NDIM+k], l1w[d*NDIM+k], a1);
    a2 = fmaf(emb2[r*NDIM+k], l2w[d*NDIM+k], a2);
  }
  n1[i*NDIM+d] = tanhf(3.0f*a1);
  n2[i*NDIM+d] = tanhf(3.0f*a2);
}

__global__ void __launch_bounds__(64) k_adjrow(const float* __restrict__ n1,
                                               const float* __restrict__ n2,
                                               float* __restrict__ Am){
  int i = blockIdx.x; int lane = threadIdx.x;
  __shared__ float rowo[NNODE];
  __shared__ float rowv[NNODE];
  __shared__ int   sel[NNODE];
  for (int j=lane;j<NNODE;j+=64){
    float a = 0.f;
    #pragma unroll
    for (int k=0;k<NDIM;++k){
      float a1 = n1[i*NDIM+k], a2 = n2[i*NDIM+k];
      a = fmaf(a1, n2[j*NDIM+k], a);
      a = fmaf(-a2, n1[j*NDIM+k], a);
    }
    float v = tanhf(3.0f*a);
    v = v > 0.f ? v : 0.f;
    rowo[j]=v; rowv[j]=v; sel[j]=0;
  }
  __syncthreads();
  for (int it=0; it<KTOP; ++it){
    float best = -1.f; int bi = 0x7fffffff;
    for (int j=lane;j<NNODE;j+=64){
      float v = rowv[j];
      if (v > best){ best=v; bi=j; }
    }
    #pragma unroll
    for (int off=32; off; off>>=1){
      float ov = __shfl_xor(best, off);
      int   oi = __shfl_xor(bi, off);
      if (ov > best || (ov == best && oi < bi)){ best=ov; bi=oi; }
    }
    if (lane==0){ sel[bi]=1; rowv[bi]=-2.f; }
    __syncthreads();
  }
  for (int j=lane;j<NNODE;j+=64)
    Am[i*NNODE+j] = sel[j] ? rowo[j] : 0.f;
}

__global__ void __launch_bounds__(64) k_csr(const float* __restrict__ Am,
                                            int* __restrict__ aidx, float* __restrict__ aval,
                                            int* __restrict__ acnt){
  int r = blockIdx.x; int lane = threadIdx.x;
  int v = (r < NNODE) ? r : r - NNODE;
  int*   ip = aidx + r*304;
  float* vp = aval + r*304;
  if (lane==0){ ip[0]=v; vp[0]=1.0f; }
  int cnt = 1; float s = 1.0f;
  for (int base=0; base<NNODE; base+=64){
    int j = base + lane; float val = 0.f; bool p = false;
    if (j < NNODE){
      val = (r < NNODE) ? Am[v*NNODE + j] : Am[j*NNODE + v];
      p = val > 0.f;
    }
    unsigned long long m = __ballot(p);
    int pre = __popcll(m & ((1ull << lane) - 1ull));
    if (p){ ip[cnt+pre]=j; vp[cnt+pre]=val; }
    cnt += __popcll(m);
    float vs = p ? val : 0.f;
    #pragma unroll
    for (int off=32; off; off>>=1) vs += __shfl_xor(vs, off);
    s += vs;
  }
  for (int e=lane; e<cnt; e+=64) vp[e] = vp[e] / s;
  if (lane==0) acnt[r]=cnt;
}

// ---------------- weight packing ----------------
// wp[w*2304 + ic*72 + path*36 + oo*18 + s], o = 2w+oo  (per-wave contiguous 9KB)
__global__ void k_wpack(const float* __restrict__ fw2,const float* __restrict__ fw3,
                        const float* __restrict__ fw6,const float* __restrict__ fw7,
                        const float* __restrict__ gw2,const float* __restrict__ gw3,
                        const float* __restrict__ gw6,const float* __restrict__ gw7,
                        float* __restrict__ wp){
  int T = blockIdx.x*blockDim.x + threadIdx.x;
  if (T >= 9216) return;
  int w = T / 2304, rem = T % 2304;
  int ic = rem / 72, r2 = rem % 72;
  int path = r2 / 36, r3 = r2 % 36;
  int oo = r3 / 18, s = r3 % 18;
  int o = w*2 + oo;
  float val;
  if (path == 0){
    if (s < 2)       val = fw2[(o*NC+ic)*2 + s];
    else if (s < 5)  val = fw3[(o*NC+ic)*3 + (s-2)];
    else if (s < 11) val = fw6[(o*NC+ic)*6 + (s-5)];
    else             val = fw7[(o*NC+ic)*7 + (s-11)];
  } else {
    if (s < 2)       val = gw2[(o*NC+ic)*2 + s];
    else if (s < 5)  val = gw3[(o*NC+ic)*3 + (s-2)];
    else if (s < 11) val = gw6[(o*NC+ic)*6 + (s-5)];
    else             val = gw7[(o*NC+ic)*7 + (s-11)];
  }
  wp[T] = val;
}

// mix weights transposed+packed:
// pk0[c2*96 + seg*32 + c]: seg0 = m1w[c,c2]+m2w[c,c2]; seg1 = m1w[c,32+c2]; seg2 = m1w[c,64+c2]
// pk1[c2*64 + seg*32 + c]: seg0 = m2w[c,32+c2]; seg1 = m2w[c,64+c2]
__global__ void k_wprep(const float* __restrict__ m1w, const float* __restrict__ m2w,
                        float* __restrict__ pk0, float* __restrict__ pk1){
  int id = blockIdx.x*blockDim.x + threadIdx.x;
  if (id < 3072){
    int c2 = id / 96, r = id % 96, seg = r / 32, c = r % 32;
    float val;
    if (seg==0)      val = m1w[c*96 + c2] + m2w[c*96 + c2];
    else if (seg==1) val = m1w[c*96 + 32 + c2];
    else             val = m1w[c*96 + 64 + c2];
    pk0[c2*96 + seg*32 + c] = val;
  } else if (id < 5120){
    int id2 = id - 3072;
    int c2 = id2 / 64, r = id2 % 64, seg = r / 32, c = r % 32;
    pk1[c2*64 + seg*32 + c] = seg==0 ? m2w[c*96 + 32 + c2] : m2w[c*96 + 64 + c2];
  }
}

// ---------------- dilated inception -> Xp[b][n][c][64] bf16 ----------------
__global__ void __launch_bounds__(256) k_incep(const float* __restrict__ x,
    const float* __restrict__ wp,
    const float* __restrict__ fb2,const float* __restrict__ fb3,const float* __restrict__ fb6,const float* __restrict__ fb7,
    const float* __restrict__ gb2,const float* __restrict__ gb3,const float* __restrict__ gb6,const float* __restrict__ gb7,
    bf16* __restrict__ Xp){
  int bn = blockIdx.x; int b = bn / NNODE, n = bn - b*NNODE;
  __shared__ float xs[PSLAB];
  {
    int tid = threadIdx.x;
    int c = tid >> 3, t0 = (tid & 7) * 8;
    const float* src = x + ((size_t)(b*NC + c)*NNODE + n)*NT + t0;
    float4 v0 = *reinterpret_cast<const float4*>(src);
    float4 v1 = *reinterpret_cast<const float4*>(src + 4);
    *reinterpret_cast<float4*>(&xs[c*64 + t0])     = v0;
    *reinterpret_cast<float4*>(&xs[c*64 + t0 + 4]) = v1;
  }
  __syncthreads();
  int lane = threadIdx.x & 63;
  // wave-uniform scalar index -> weight/bias loads become s_load streams
  int wq = __builtin_amdgcn_readfirstlane(threadIdx.x >> 6);
  int o0 = 2*wq;
  const float* wpw = wp + wq*2304;
  float af[8], ag[8];
  af[0]=fb2[o0]; af[1]=fb2[o0+1]; af[2]=fb3[o0]; af[3]=fb3[o0+1];
  af[4]=fb6[o0]; af[5]=fb6[o0+1]; af[6]=fb7[o0]; af[7]=fb7[o0+1];
  ag[0]=gb2[o0]; ag[1]=gb2[o0+1]; ag[2]=gb3[o0]; ag[3]=gb3[o0+1];
  ag[4]=gb6[o0]; ag[5]=gb6[o0+1]; ag[6]=gb7[o0]; ag[7]=gb7[o0+1];
  int tc = lane < NTOUT ? lane : NTOUT-1;
  for (int ic=0; ic<NC; ++ic){
    float xv[7];
    #pragma unroll
    for (int d=0;d<7;++d) xv[d] = xs[ic*64 + tc + d];
    const float* wv = wpw + ic*72;
    #pragma unroll
    for (int oo=0;oo<2;++oo){
      const float* wf = wv + oo*18;
      const float* wg = wv + 36 + oo*18;
      af[0+oo] = fmaf(wf[0], xv[5], fmaf(wf[1], xv[6], af[0+oo]));
      ag[0+oo] = fmaf(wg[0], xv[5], fmaf(wg[1], xv[6], ag[0+oo]));
      af[2+oo] = fmaf(wf[2], xv[4], fmaf(wf[3], xv[5], fmaf(wf[4], xv[6], af[2+oo])));
      ag[2+oo] = fmaf(wg[2], xv[4], fmaf(wg[3], xv[5], fmaf(wg[4], xv[6], ag[2+oo])));
      #pragma unroll
      for (int tp=0;tp<6;++tp){ af[4+oo] = fmaf(wf[5+tp], xv[1+tp], af[4+oo]); ag[4+oo] = fmaf(wg[5+tp], xv[1+tp], ag[4+oo]); }
      #pragma unroll
      for (int tp=0;tp<7;++tp){ af[6+oo] = fmaf(wf[11+tp], xv[tp], af[6+oo]);  ag[6+oo] = fmaf(wg[11+tp], xv[tp], ag[6+oo]); }
    }
  }
  if (lane < NTOUT){
    size_t base = (size_t)bn*PSLAB + lane;
    #pragma unroll
    for (int cls=0; cls<4; ++cls){
      #pragma unroll
      for (int oo=0; oo<2; ++oo){
        int c = cls*8 + o0 + oo;
        float val = ftanh(af[cls*2+oo]) * fsig(ag[cls*2+oo]);
        Xp[base + (size_t)c*64] = f2b(val);
      }
    }
  }
}

// ---------------- skip path ----------------
__global__ void k_wT(const float* __restrict__ sw, float* __restrict__ wT){
  int id = blockIdx.x*blockDim.x + threadIdx.x;
  if (id >= 1856*64) return;
  int kk = id >> 6, sc = id & 63;
  wT[kk*64 + sc] = sw[sc*1856 + kk];
}

__global__ void __launch_bounds__(256) k_skip(const bf16* __restrict__ Xp, const float* __restrict__ wT,
      const float* __restrict__ skip_b, const float* __restrict__ x_skip, float* __restrict__ out){
  __shared__ float Xs[8*1856];
  int tid = threadIdx.x;
  int bp0 = blockIdx.x*8;
  for (int idx = tid; idx < 8*1856; idx += 256){
    int p = idx / 1856, kk = idx - p*1856;
    int c = kk / NTOUT, t = kk - c*NTOUT;
    int gp = bp0 + p; int b = gp / NNODE, n = gp - b*NNODE;
    Xs[idx] = b2f(Xp[(size_t)(b*NNODE+n)*PSLAB + c*64 + t]);
  }
  __syncthreads();
  int lane = tid & 63, w = tid >> 6;
  int kk0 = w*464;
  float acc[8] = {0,0,0,0,0,0,0,0};
  for (int kk = kk0; kk < kk0+464; kk += 4){
    float wv0 = wT[(kk+0)*64 + lane];
    float wv1 = wT[(kk+1)*64 + lane];
    float wv2 = wT[(kk+2)*64 + lane];
    float wv3 = wT[(kk+3)*64 + lane];
    #pragma unroll
    for (int p=0;p<8;++p){
      const float4 xv = *reinterpret_cast<const float4*>(&Xs[p*1856 + kk]);
      acc[p] = fmaf(xv.x, wv0, acc[p]);
      acc[p] = fmaf(xv.y, wv1, acc[p]);
      acc[p] = fmaf(xv.z, wv2, acc[p]);
      acc[p] = fmaf(xv.w, wv3, acc[p]);
    }
  }
  __syncthreads();
  float* red = Xs;
  #pragma unroll
  for (int p=0;p<8;++p) red[w*512 + p*64 + lane] = acc[p];
  __syncthreads();
  #pragma unroll
  for (int pi=0; pi<2; ++pi){
    int p = w*2 + pi;
    float s = red[p*64+lane] + red[512+p*64+lane] + red[1024+p*64+lane] + red[1536+p*64+lane];
    int gp = bp0 + p, b = gp / NNODE, n = gp - b*NNODE;
    size_t so = (size_t)b*NSKIP*NNODE + (size_t)lane*NNODE + n;
    out[(size_t)XEL + so] = s + skip_b[lane] + x_skip[so];
  }
}

// ---------------- hop1: HA = 0.05*Xp + 0.95*(Ah (x) Xp) ----------------
__global__ void __launch_bounds__(256) k_prop(const bf16* __restrict__ Xp, bf16* __restrict__ HA,
    const int* __restrict__ aidx, const float* __restrict__ aval, const int* __restrict__ acnt,
    int rowoff){
  __shared__ int   sidx[304];
  __shared__ float sval[304];
  int b, v; bv_swz(blockIdx.x, b, v);
  int r = rowoff + v;
  int cnt = acnt[r];
  for (int e = threadIdx.x; e < cnt; e += 256){
    sidx[e] = aidx[r*304 + e] * PSLAB;
    sval[e] = aval[r*304 + e];
  }
  __syncthreads();
  int lane = threadIdx.x & 63, w = threadIdx.x >> 6;
  int c0 = w*8;
  const bf16* base = Xp + (size_t)b*BPSLAB + c0*64 + lane;
  float acc[8] = {0,0,0,0,0,0,0,0};
  for (int j=0;j<cnt;++j){
    float vv = sval[j];
    const bf16* p = base + sidx[j];
    #pragma unroll
    for (int q=0;q<8;++q)
      acc[q] = fmaf(vv, b2f(p[q*64]), acc[q]);
  }
  if (lane < NTOUT){
    size_t o = (size_t)b*BPSLAB + (size_t)v*PSLAB + c0*64 + lane;
    #pragma unroll
    for (int q=0;q<8;++q){
      size_t oi = o + (size_t)q*64;
      HA[oi] = f2b(0.05f*b2f(Xp[oi]) + 0.95f*acc[q]);
    }
  }
}

// ---------------- hop2 + 1x1 mix conv, fused ----------------
// side 0: out = bias + Wsum*X + W1h1*HA + W1h2*H2          (pk0, 3 segs)
// side 1: out += W2h1*HA + W2h2*H2 + residual x[...,6+t]   (pk1, 2 segs)
__global__ void __launch_bounds__(256) k_fuse(const bf16* __restrict__ Xp, const bf16* __restrict__ HA,
    float* __restrict__ out, const float* __restrict__ x,
    const int* __restrict__ aidx, const float* __restrict__ aval, const int* __restrict__ acnt,
    const float* __restrict__ pk, const float* __restrict__ b1, const float* __restrict__ b2,
    int rowoff, int side){
  __shared__ int   sidx[304];
  __shared__ float sval[304];
  __shared__ float h2[PSLAB];
  int b, v; bv_swz(blockIdx.x, b, v);
  int r = rowoff + v;
  int cnt = acnt[r];
  for (int e = threadIdx.x; e < cnt; e += 256){
    sidx[e] = aidx[r*304 + e] * PSLAB;
    sval[e] = aval[r*304 + e];
  }
  __syncthreads();
  int lane = threadIdx.x & 63, w = threadIdx.x >> 6;
  int c0 = w*8;
  size_t bbase = (size_t)b*BPSLAB;
  size_t vbase = bbase + (size_t)v*PSLAB;
  {
    const bf16* base = HA + bbase + c0*64 + lane;
    float acc[8] = {0,0,0,0,0,0,0,0};
    for (int j=0;j<cnt;++j){
      float vv = sval[j];
      const bf16* p = base + sidx[j];
      #pragma unroll
      for (int q=0;q<8;++q)
        acc[q] = fmaf(vv, b2f(p[q*64]), acc[q]);
    }
    #pragma unroll
    for (int q=0;q<8;++q){
      float xl = b2f(Xp[vbase + (c0+q)*64 + lane]);
      h2[(c0+q)*64 + lane] = 0.05f*xl + 0.95f*acc[q];
    }
  }
  __syncthreads();
  float acc2[8];
  if (side == 0){
    #pragma unroll
    for (int q=0;q<8;++q) acc2[q] = b1[c0+q] + b2[c0+q];
    for (int c2=0;c2<NC;++c2){
      const float* wrow = pk + c2*96 + c0;
      float xl  = b2f(Xp[vbase + c2*64 + lane]);
      float hal = b2f(HA[vbase + c2*64 + lane]);
      float h2l = h2[c2*64 + lane];
      #pragma unroll
      for (int q=0;q<8;++q){
        acc2[q] = fmaf(wrow[q], xl, acc2[q]);
        acc2[q] = fmaf(wrow[32+q], hal, acc2[q]);
        acc2[q] = fmaf(wrow[64+q], h2l, acc2[q]);
      }
    }
    if (lane < NTOUT){
      #pragma unroll
      for (int q=0;q<8;++q){
        size_t o = ((size_t)(b*NC + c0+q)*NNODE + v)*NTOUT + lane;
        out[o] = acc2[q];
      }
    }
  } else {
    #pragma unroll
    for (int q=0;q<8;++q) acc2[q] = 0.f;
    for (int c2=0;c2<NC;++c2){
      const float* wrow = pk + c2*64 + c0;
      float hal = b2f(HA[vbase + c2*64 + lane]);
      float h2l = h2[c2*64 + lane];
      #pragma unroll
      for (int q=0;q<8;++q){
        acc2[q] = fmaf(wrow[q], hal, acc2[q]);
        acc2[q] = fmaf(wrow[32+q], h2l, acc2[q]);
      }
    }
    if (lane < NTOUT){
      #pragma unroll
      for (int q=0;q<8;++q){
        int c = c0 + q;
        size_t o = ((size_t)(b*NC + c)*NNODE + v)*NTOUT + lane;
        float res = x[((size_t)(b*NC + c)*NNODE + v)*NT + 6 + lane];
        out[o] = out[o] + acc2[q] + res;
      }
    }
  }
}

// ---------------- layernorm ----------------
__global__ void __launch_bounds__(256) k_lnstat(const float* __restrict__ out, double* __restrict__ part){
  int blk = blockIdx.x; int b = blk >> 3, seg = blk & 7;
  const float* p = out + (size_t)b*BSLAB;
  int start = seg*69600, end = start + 69600;
  double s = 0.0, s2 = 0.0;
  for (int i = start + threadIdx.x; i < end; i += 256){
    double v = (double)p[i]; s += v; s2 += v*v;
  }
  #pragma unroll
  for (int off=32; off; off>>=1){ s += __shfl_down(s, off); s2 += __shfl_down(s2, off); }
  __shared__ double ls[4], ls2[4];
  int lane = threadIdx.x & 63, w = threadIdx.x >> 6;
  if (lane==0){ ls[w]=s; ls2[w]=s2; }
  __syncthreads();
  if (threadIdx.x==0){
    double a=0.0, a2=0.0;
    for (int i=0;i<4;++i){ a+=ls[i]; a2+=ls2[i]; }
    part[blk*2]=a; part[blk*2+1]=a2;
  }
}

__global__ void k_lnfin(const double* __restrict__ part, float* __restrict__ stats){
  int b = threadIdx.x; if (b >= 32) return;
  double s=0.0, s2=0.0;
  for (int seg=0; seg<8; ++seg){ s += part[(b*8+seg)*2]; s2 += part[(b*8+seg)*2+1]; }
  double n = (double)BSLAB;
  double mean = s/n;
  double var = s2/n - mean*mean;
  stats[b*2]   = (float)mean;
  stats[b*2+1] = (float)(1.0/sqrt(var + 1e-5));
}

__global__ void __launch_bounds__(256) k_lnapply(float* __restrict__ out, const float* __restrict__ stats,
        const float* __restrict__ lnw, const float* __restrict__ lnb, const int* __restrict__ idxp){
  int o = blockIdx.x*256 + threadIdx.x;
  int t = o % NTOUT; int v = (o / NTOUT) % NNODE; int c = (o / SLAB) % NC; int b = o / BSLAB;
  float mean = stats[b*2], rstd = stats[b*2+1];
  int vn = idxp[v];
  float wv = lnw[((size_t)c*NNODE + vn)*NTOUT + t];
  float bv = lnb[((size_t)c*NNODE + vn)*NTOUT + t];
  float vx = out[o];
  out[o] = (vx - mean)*rstd*wv + bv;
}

extern "C" void kernel_launch(void* const* d_in, const int* in_sizes, int n_in,
                              void* d_out, int out_size, void* d_ws, size_t ws_size,
                              hipStream_t stream) {
  (void)in_sizes; (void)n_in; (void)out_size; (void)ws_size;
  const float* x     = (const float*)d_in[0];
  const float* xskip = (const float*)d_in[1];
  const int*   idxp  = (const int*)d_in[2];
  const float* emb1  = (const float*)d_in[3];
  const float* emb2  = (const float*)d_in[4];
  const float* l1w   = (const float*)d_in[5];
  const float* l1b   = (const float*)d_in[6];
  const float* l2w   = (const float*)d_in[7];
  const float* l2b   = (const float*)d_in[8];
  const float* skw   = (const float*)d_in[9];
  const float* skb   = (const float*)d_in[10];
  const float* m1w   = (const float*)d_in[11];
  const float* m1b   = (const float*)d_in[12];
  const float* m2w   = (const float*)d_in[13];
  const float* m2b   = (const float*)d_in[14];
  const float* lnw   = (const float*)d_in[15];
  const float* lnb   = (const float*)d_in[16];
  const float* fw2=(const float*)d_in[17]; const float* fb2=(const float*)d_in[18];
  const float* gw2=(const float*)d_in[19]; const float* gb2=(const float*)d_in[20];
  const float* fw3=(const float*)d_in[21]; const float* fb3=(const float*)d_in[22];
  const float* gw3=(const float*)d_in[23]; const float* gb3=(const float*)d_in[24];
  const float* fw6=(const float*)d_in[25]; const float* fb6=(const float*)d_in[26];
  const float* gw6=(const float*)d_in[27]; const float* gb6=(const float*)d_in[28];
  const float* fw7=(const float*)d_in[29]; const float* fb7=(const float*)d_in[30];
  const float* gw7=(const float*)d_in[31]; const float* gb7=(const float*)d_in[32];
  float* out = (float*)d_out;

  char* wsbase = (char*)d_ws;
  size_t cur = 0;
  auto alloc = [&](size_t bytes)->char*{
    char* p = wsbase + cur;
    cur = (cur + bytes + 255) & ~(size_t)255;
    return p;
  };
  bf16*  Xp   = (bf16*) alloc((size_t)XPEL*2);
  bf16*  HA   = (bf16*) alloc((size_t)XPEL*2);
  float* n1   = (float*)alloc(12000*4);
  float* n2   = (float*)alloc(12000*4);
  float* Am   = (float*)alloc(90000*4);
  int*   aidx = (int*)  alloc(600*304*4);
  float* aval = (float*)alloc(600*304*4);
  int*   acnt = (int*)  alloc(600*4);
  float* wT   = (float*)alloc(1856*64*4);
  float* wp   = (float*)alloc(9216*4);
  float* pk0  = (float*)alloc(3072*4);
  float* pk1  = (float*)alloc(2048*4);
  double* part = (double*)alloc(256*2*8);
  float* stats = (float*)alloc(64*4);

  // graph construction (tiny)
  k_nodes <<<NNODE, 64, 0, stream>>>(emb1, emb2, l1w, l1b, l2w, l2b, idxp, n1, n2);
  k_adjrow<<<NNODE, 64, 0, stream>>>(n1, n2, Am);
  k_csr   <<<2*NNODE, 64, 0, stream>>>(Am, aidx, aval, acnt);

  // weight prep
  k_wpack<<<36, 256, 0, stream>>>(fw2,fw3,fw6,fw7, gw2,gw3,gw6,gw7, wp);
  k_wprep<<<20, 256, 0, stream>>>(m1w, m2w, pk0, pk1);
  k_wT   <<<464, 256, 0, stream>>>(skw, wT);

  // dilated inception -> Xp
  k_incep<<<NB*NNODE, 256, 0, stream>>>(x, wp, fb2,fb3,fb6,fb7, gb2,gb3,gb6,gb7, Xp);

  // skip path
  k_skip<<<(NB*NNODE)/8, 256, 0, stream>>>(Xp, wT, skb, xskip, out);

  // mixprop side 0 (A)
  k_prop<<<NB*NNODE, 256, 0, stream>>>(Xp, HA, aidx, aval, acnt, 0);
  k_fuse<<<NB*NNODE, 256, 0, stream>>>(Xp, HA, out, x, aidx, aval, acnt, pk0, m1b, m2b, 0, 0);

  // mixprop side 1 (A^T)
  k_prop<<<NB*NNODE, 256, 0, stream>>>(Xp, HA, aidx, aval, acnt, NNODE);
  k_fuse<<<NB*NNODE, 256, 0, stream>>>(Xp, HA, out, x, aidx, aval, acnt, pk1, m1b, m2b, NNODE, 1);

  // layernorm
  k_lnstat<<<256, 256, 0, stream>>>(out, part);
  k_lnfin<<<1, 32, 0, stream>>>(part, stats);
  k_lnapply<<<XEL/256, 256, 0, stream>>>(out, stats, lnw, lnb, idxp);
}

// Round 5
// 715.723 us; speedup vs baseline: 2.0236x; 1.4003x over previous
//
#include <hip/hip_runtime.h>
#include <hip/hip_bf16.h>
#include <math.h>

typedef __hip_bfloat16 bf16;

#define NB 32
#define NC 32
#define NNODE 300
#define NT 64
#define NDIM 40
#define KTOP 20
#define NSKIP 64
#define NTOUT 58
#define SLAB 17400        // NNODE*NTOUT (out layout)
#define BSLAB 556800      // NC*SLAB
#define XEL 17817600      // NB*BSLAB
#define PSLAB 2048        // NC*64 padded node slab
#define BPSLAB 614400     // NNODE*PSLAB
#define XPEL 19660800     // NB*BPSLAB

__device__ __forceinline__ float b2f(bf16 v){ return __bfloat162float(v); }
__device__ __forceinline__ bf16 f2b(float v){ return __float2bfloat16(v); }
__device__ __forceinline__ float fsig(float x){ return 1.0f/(1.0f + __expf(-x)); }
__device__ __forceinline__ float ftanh(float x){ return 2.0f*fsig(2.0f*x) - 1.0f; }

__device__ __forceinline__ unsigned short bbits(float v){
  bf16 h = f2b(v); unsigned short s; __builtin_memcpy(&s, &h, 2); return s;
}

// 8 bf16 in a uint4: acc[k] += vv * e[k]
__device__ __forceinline__ void fma8(float acc[8], uint4 d, float vv){
  acc[0] = fmaf(vv, __uint_as_float(d.x << 16),          acc[0]);
  acc[1] = fmaf(vv, __uint_as_float(d.x & 0xffff0000u),  acc[1]);
  acc[2] = fmaf(vv, __uint_as_float(d.y << 16),          acc[2]);
  acc[3] = fmaf(vv, __uint_as_float(d.y & 0xffff0000u),  acc[3]);
  acc[4] = fmaf(vv, __uint_as_float(d.z << 16),          acc[4]);
  acc[5] = fmaf(vv, __uint_as_float(d.z & 0xffff0000u),  acc[5]);
  acc[6] = fmaf(vv, __uint_as_float(d.w << 16),          acc[6]);
  acc[7] = fmaf(vv, __uint_as_float(d.w & 0xffff0000u),  acc[7]);
}

__device__ __forceinline__ void unp8(float f[8], uint4 d){
  f[0] = __uint_as_float(d.x << 16); f[1] = __uint_as_float(d.x & 0xffff0000u);
  f[2] = __uint_as_float(d.y << 16); f[3] = __uint_as_float(d.y & 0xffff0000u);
  f[4] = __uint_as_float(d.z << 16); f[5] = __uint_as_float(d.z & 0xffff0000u);
  f[6] = __uint_as_float(d.w << 16); f[7] = __uint_as_float(d.w & 0xffff0000u);
}

__device__ __forceinline__ uint4 pack8(const float f[8]){
  uint4 d;
  d.x = (unsigned)bbits(f[0]) | ((unsigned)bbits(f[1]) << 16);
  d.y = (unsigned)bbits(f[2]) | ((unsigned)bbits(f[3]) << 16);
  d.z = (unsigned)bbits(f[4]) | ((unsigned)bbits(f[5]) << 16);
  d.w = (unsigned)bbits(f[6]) | ((unsigned)bbits(f[7]) << 16);
  return d;
}

// XCD-aware swizzle for 9600-block graph kernels: XCD k gets b in [k*4, k*4+4)
__device__ __forceinline__ void bv_swz(int bid, int& b, int& v){
  int xcd = bid & 7, i = bid >> 3;
  int nb = xcd*1200 + i;
  b = nb / NNODE; v = nb - b*NNODE;
}

// ---------------- graph construction ----------------
__global__ void k_nodes(const float* __restrict__ emb1, const float* __restrict__ emb2,
                        const float* __restrict__ l1w, const float* __restrict__ l1b,
                        const float* __restrict__ l2w, const float* __restrict__ l2b,
                        const int* __restrict__ idxp,
                        float* __restrict__ n1, float* __restrict__ n2){
  int i = blockIdx.x; int d = threadIdx.x;
  if (d >= NDIM) return;
  int r = idxp[i];
  float a1 = l1b[d], a2 = l2b[d];
  for (int k=0;k<NDIM;++k){
    a1 = fmaf(emb1[r*NDIM+k], l1w[d*NDIM+k], a1);
    a2 = fmaf(emb2[r*NDIM+k], l2w[d*NDIM+k], a2);
  }
  n1[i*NDIM+d] = tanhf(3.0f*a1);
  n2[i*NDIM+d] = tanhf(3.0f*a2);
}

__global__ void __launch_bounds__(64) k_adjrow(const float* __restrict__ n1,
                                               const float* __restrict__ n2,
                                               float* __restrict__ Am){
  int i = blockIdx.x; int lane = threadIdx.x;
  __shared__ float rowo[NNODE];
  __shared__ float rowv[NNODE];
  __shared__ int   sel[NNODE];
  for (int j=lane;j<NNODE;j+=64){
    float a = 0.f;
    #pragma unroll
    for (int k=0;k<NDIM;++k){
      float a1 = n1[i*NDIM+k], a2 = n2[i*NDIM+k];
      a = fmaf(a1, n2[j*NDIM+k], a);
      a = fmaf(-a2, n1[j*NDIM+k], a);
    }
    float v = tanhf(3.0f*a);
    v = v > 0.f ? v : 0.f;
    rowo[j]=v; rowv[j]=v; sel[j]=0;
  }
  __syncthreads();
  for (int it=0; it<KTOP; ++it){
    float best = -1.f; int bi = 0x7fffffff;
    for (int j=lane;j<NNODE;j+=64){
      float v = rowv[j];
      if (v > best){ best=v; bi=j; }
    }
    #pragma unroll
    for (int off=32; off; off>>=1){
      float ov = __shfl_xor(best, off);
      int   oi = __shfl_xor(bi, off);
      if (ov > best || (ov == best && oi < bi)){ best=ov; bi=oi; }
    }
    if (lane==0){ sel[bi]=1; rowv[bi]=-2.f; }
    __syncthreads();
  }
  for (int j=lane;j<NNODE;j+=64)
    Am[i*NNODE+j] = sel[j] ? rowo[j] : 0.f;
}

__global__ void __launch_bounds__(64) k_csr(const float* __restrict__ Am,
                                            int* __restrict__ aidx, float* __restrict__ aval,
                                            int* __restrict__ acnt){
  int r = blockIdx.x; int lane = threadIdx.x;
  int v = (r < NNODE) ? r : r - NNODE;
  int*   ip = aidx + r*304;
  float* vp = aval + r*304;
  if (lane==0){ ip[0]=v; vp[0]=1.0f; }
  int cnt = 1; float s = 1.0f;
  for (int base=0; base<NNODE; base+=64){
    int j = base + lane; float val = 0.f; bool p = false;
    if (j < NNODE){
      val = (r < NNODE) ? Am[v*NNODE + j] : Am[j*NNODE + v];
      p = val > 0.f;
    }
    unsigned long long m = __ballot(p);
    int pre = __popcll(m & ((1ull << lane) - 1ull));
    if (p){ ip[cnt+pre]=j; vp[cnt+pre]=val; }
    cnt += __popcll(m);
    float vs = p ? val : 0.f;
    #pragma unroll
    for (int off=32; off; off>>=1) vs += __shfl_xor(vs, off);
    s += vs;
  }
  for (int e=lane; e<cnt; e+=64) vp[e] = vp[e] / s;
  if (lane==0) acnt[r]=cnt;
}

// ---------------- weight packing ----------------
// wp[w*2304 + ic*72 + path*36 + oo*18 + s], o = 2w+oo  (per-wave contiguous 9KB)
__global__ void k_wpack(const float* __restrict__ fw2,const float* __restrict__ fw3,
                        const float* __restrict__ fw6,const float* __restrict__ fw7,
                        const float* __restrict__ gw2,const float* __restrict__ gw3,
                        const float* __restrict__ gw6,const float* __restrict__ gw7,
                        float* __restrict__ wp){
  int T = blockIdx.x*blockDim.x + threadIdx.x;
  if (T >= 9216) return;
  int w = T / 2304, rem = T % 2304;
  int ic = rem / 72, r2 = rem % 72;
  int path = r2 / 36, r3 = r2 % 36;
  int oo = r3 / 18, s = r3 % 18;
  int o = w*2 + oo;
  float val;
  if (path == 0){
    if (s < 2)       val = fw2[(o*NC+ic)*2 + s];
    else if (s < 5)  val = fw3[(o*NC+ic)*3 + (s-2)];
    else if (s < 11) val = fw6[(o*NC+ic)*6 + (s-5)];
    else             val = fw7[(o*NC+ic)*7 + (s-11)];
  } else {
    if (s < 2)       val = gw2[(o*NC+ic)*2 + s];
    else if (s < 5)  val = gw3[(o*NC+ic)*3 + (s-2)];
    else if (s < 11) val = gw6[(o*NC+ic)*6 + (s-5)];
    else             val = gw7[(o*NC+ic)*7 + (s-11)];
  }
  wp[T] = val;
}

// pk0[c2*96 + seg*32 + c]: seg0 = m1w[c,c2]+m2w[c,c2]; seg1 = m1w[c,32+c2]; seg2 = m1w[c,64+c2]
// pk1[c2*64 + seg*32 + c]: seg0 = m2w[c,32+c2]; seg1 = m2w[c,64+c2]
__global__ void k_wprep(const float* __restrict__ m1w, const float* __restrict__ m2w,
                        float* __restrict__ pk0, float* __restrict__ pk1){
  int id = blockIdx.x*blockDim.x + threadIdx.x;
  if (id < 3072){
    int c2 = id / 96, r = id % 96, seg = r / 32, c = r % 32;
    float val;
    if (seg==0)      val = m1w[c*96 + c2] + m2w[c*96 + c2];
    else if (seg==1) val = m1w[c*96 + 32 + c2];
    else             val = m1w[c*96 + 64 + c2];
    pk0[c2*96 + seg*32 + c] = val;
  } else if (id < 5120){
    int id2 = id - 3072;
    int c2 = id2 / 64, r = id2 % 64, seg = r / 32, c = r % 32;
    pk1[c2*64 + seg*32 + c] = seg==0 ? m2w[c*96 + 32 + c2] : m2w[c*96 + 64 + c2];
  }
}

// ---------------- dilated inception -> Xp[b][n][c][64] bf16 (pad zeroed) ----------------
__global__ void __launch_bounds__(256) k_incep(const float* __restrict__ x,
    const float* __restrict__ wp,
    const float* __restrict__ fb2,const float* __restrict__ fb3,const float* __restrict__ fb6,const float* __restrict__ fb7,
    const float* __restrict__ gb2,const float* __restrict__ gb3,const float* __restrict__ gb6,const float* __restrict__ gb7,
    bf16* __restrict__ Xp){
  int bn = blockIdx.x; int b = bn / NNODE, n = bn - b*NNODE;
  __shared__ float xs[PSLAB];
  {
    int tid = threadIdx.x;
    int c = tid >> 3, t0 = (tid & 7) * 8;
    const float* src = x + ((size_t)(b*NC + c)*NNODE + n)*NT + t0;
    float4 v0 = *reinterpret_cast<const float4*>(src);
    float4 v1 = *reinterpret_cast<const float4*>(src + 4);
    *reinterpret_cast<float4*>(&xs[c*64 + t0])     = v0;
    *reinterpret_cast<float4*>(&xs[c*64 + t0 + 4]) = v1;
  }
  __syncthreads();
  int lane = threadIdx.x & 63;
  int wq = __builtin_amdgcn_readfirstlane(threadIdx.x >> 6);
  int o0 = 2*wq;
  const float* wpw = wp + wq*2304;
  float af[8], ag[8];
  af[0]=fb2[o0]; af[1]=fb2[o0+1]; af[2]=fb3[o0]; af[3]=fb3[o0+1];
  af[4]=fb6[o0]; af[5]=fb6[o0+1]; af[6]=fb7[o0]; af[7]=fb7[o0+1];
  ag[0]=gb2[o0]; ag[1]=gb2[o0+1]; ag[2]=gb3[o0]; ag[3]=gb3[o0+1];
  ag[4]=gb6[o0]; ag[5]=gb6[o0+1]; ag[6]=gb7[o0]; ag[7]=gb7[o0+1];
  bool act = lane < NTOUT;
  int tc = act ? lane : NTOUT-1;
  for (int ic=0; ic<NC; ++ic){
    float xv[7];
    #pragma unroll
    for (int d=0;d<7;++d) xv[d] = xs[ic*64 + tc + d];
    const float* wv = wpw + ic*72;
    #pragma unroll
    for (int oo=0;oo<2;++oo){
      const float* wf = wv + oo*18;
      const float* wg = wv + 36 + oo*18;
      af[0+oo] = fmaf(wf[0], xv[5], fmaf(wf[1], xv[6], af[0+oo]));
      ag[0+oo] = fmaf(wg[0], xv[5], fmaf(wg[1], xv[6], ag[0+oo]));
      af[2+oo] = fmaf(wf[2], xv[4], fmaf(wf[3], xv[5], fmaf(wf[4], xv[6], af[2+oo])));
      ag[2+oo] = fmaf(wg[2], xv[4], fmaf(wg[3], xv[5], fmaf(wg[4], xv[6], ag[2+oo])));
      #pragma unroll
      for (int tp=0;tp<6;++tp){ af[4+oo] = fmaf(wf[5+tp], xv[1+tp], af[4+oo]); ag[4+oo] = fmaf(wg[5+tp], xv[1+tp], ag[4+oo]); }
      #pragma unroll
      for (int tp=0;tp<7;++tp){ af[6+oo] = fmaf(wf[11+tp], xv[tp], af[6+oo]);  ag[6+oo] = fmaf(wg[11+tp], xv[tp], ag[6+oo]); }
    }
  }
  {
    size_t base = (size_t)bn*PSLAB + lane;
    #pragma unroll
    for (int cls=0; cls<4; ++cls){
      #pragma unroll
      for (int oo=0; oo<2; ++oo){
        int c = cls*8 + o0 + oo;
        float val = act ? (ftanh(af[cls*2+oo]) * fsig(ag[cls*2+oo])) : 0.f;
        Xp[base + (size_t)c*64] = f2b(val);
      }
    }
  }
}

// ---------------- skip path ----------------
__global__ void k_wT(const float* __restrict__ sw, float* __restrict__ wT){
  int id = blockIdx.x*blockDim.x + threadIdx.x;
  if (id >= 1856*64) return;
  int kk = id >> 6, sc = id & 63;
  wT[kk*64 + sc] = sw[sc*1856 + kk];
}

__global__ void __launch_bounds__(256) k_skip(const bf16* __restrict__ Xp, const float* __restrict__ wT,
      const float* __restrict__ skip_b, const float* __restrict__ x_skip, float* __restrict__ out){
  __shared__ float Xs[8*1856];
  int tid = threadIdx.x;
  int bp0 = blockIdx.x*8;
  for (int idx = tid; idx < 8*1856; idx += 256){
    int p = idx / 1856, kk = idx - p*1856;
    int c = kk / NTOUT, t = kk - c*NTOUT;
    int gp = bp0 + p; int b = gp / NNODE, n = gp - b*NNODE;
    Xs[idx] = b2f(Xp[(size_t)(b*NNODE+n)*PSLAB + c*64 + t]);
  }
  __syncthreads();
  int lane = tid & 63, w = tid >> 6;
  int kk0 = w*464;
  float acc[8] = {0,0,0,0,0,0,0,0};
  for (int kk = kk0; kk < kk0+464; kk += 4){
    float wv0 = wT[(kk+0)*64 + lane];
    float wv1 = wT[(kk+1)*64 + lane];
    float wv2 = wT[(kk+2)*64 + lane];
    float wv3 = wT[(kk+3)*64 + lane];
    #pragma unroll
    for (int p=0;p<8;++p){
      const float4 xv = *reinterpret_cast<const float4*>(&Xs[p*1856 + kk]);
      acc[p] = fmaf(xv.x, wv0, acc[p]);
      acc[p] = fmaf(xv.y, wv1, acc[p]);
      acc[p] = fmaf(xv.z, wv2, acc[p]);
      acc[p] = fmaf(xv.w, wv3, acc[p]);
    }
  }
  __syncthreads();
  float* red = Xs;
  #pragma unroll
  for (int p=0;p<8;++p) red[w*512 + p*64 + lane] = acc[p];
  __syncthreads();
  #pragma unroll
  for (int pi=0; pi<2; ++pi){
    int p = w*2 + pi;
    float s = red[p*64+lane] + red[512+p*64+lane] + red[1024+p*64+lane] + red[1536+p*64+lane];
    int gp = bp0 + p, b = gp / NNODE, n = gp - b*NNODE;
    size_t so = (size_t)b*NSKIP*NNODE + (size_t)lane*NNODE + n;
    out[(size_t)XEL + so] = s + skip_b[lane] + x_skip[so];
  }
}

// ---------------- hop1: HA = 0.05*Xp + 0.95*(Ah (x) Xp) ----------------
// lane = (channel c = w*8 + lane>>3, t-block tb = (lane&7)*8); one dwordx4 per neighbor
__global__ void __launch_bounds__(256) k_prop(const bf16* __restrict__ Xp, bf16* __restrict__ HA,
    const int* __restrict__ aidx, const float* __restrict__ aval, const int* __restrict__ acnt,
    int rowoff){
  __shared__ int   sidx[304];
  __shared__ float sval[304];
  int b, v; bv_swz(blockIdx.x, b, v);
  int r = rowoff + v;
  int cnt = acnt[r];
  for (int e = threadIdx.x; e < cnt; e += 256){
    sidx[e] = aidx[r*304 + e] * PSLAB;
    sval[e] = aval[r*304 + e];
  }
  __syncthreads();
  int lane = threadIdx.x & 63, w = threadIdx.x >> 6;
  int c = w*8 + (lane >> 3);
  int tb = (lane & 7) * 8;
  size_t cbase = (size_t)b*BPSLAB + c*64 + tb;
  size_t own   = cbase + (size_t)v*PSLAB;
  const bf16* base = Xp + cbase;
  float acc[8] = {0,0,0,0,0,0,0,0};
  #pragma unroll 2
  for (int j=0;j<cnt;++j){
    uint4 d = *reinterpret_cast<const uint4*>(base + sidx[j]);
    fma8(acc, d, sval[j]);
  }
  uint4 dx = *reinterpret_cast<const uint4*>(Xp + own);
  float xf[8]; unp8(xf, dx);
  float h[8];
  #pragma unroll
  for (int k=0;k<8;++k) h[k] = fmaf(0.95f, acc[k], 0.05f*xf[k]);
  *reinterpret_cast<uint4*>(HA + own) = pack8(h);
}

// ---------------- hop2 + 1x1 mix conv, fused ----------------
__global__ void __launch_bounds__(256) k_fuse(const bf16* __restrict__ Xp, const bf16* __restrict__ HA,
    float* __restrict__ out, const float* __restrict__ x,
    const int* __restrict__ aidx, const float* __restrict__ aval, const int* __restrict__ acnt,
    const float* __restrict__ pk, const float* __restrict__ b1, const float* __restrict__ b2,
    int rowoff, int side){
  __shared__ int   sidx[304];
  __shared__ float sval[304];
  __shared__ uint4 h2s[256];     // [c][tbi] 8 bf16 each
  __shared__ float wlds[3072];
  int b, v; bv_swz(blockIdx.x, b, v);
  int r = rowoff + v;
  int cnt = acnt[r];
  for (int e = threadIdx.x; e < cnt; e += 256){
    sidx[e] = aidx[r*304 + e] * PSLAB;
    sval[e] = aval[r*304 + e];
  }
  int npk = (side == 0) ? 3072 : 2048;
  for (int e = threadIdx.x; e < npk; e += 256) wlds[e] = pk[e];
  __syncthreads();
  int lane = threadIdx.x & 63, w = threadIdx.x >> 6;
  int c   = w*8 + (lane >> 3);
  int tbi = lane & 7;
  int tb  = tbi * 8;
  size_t bbase = (size_t)b*BPSLAB;
  size_t vbase = bbase + (size_t)v*PSLAB;
  size_t own   = vbase + c*64 + tb;
  // phase A: hop2 gather over HA
  {
    const bf16* base = HA + bbase + c*64 + tb;
    float acc[8] = {0,0,0,0,0,0,0,0};
    #pragma unroll 2
    for (int j=0;j<cnt;++j){
      uint4 d = *reinterpret_cast<const uint4*>(base + sidx[j]);
      fma8(acc, d, sval[j]);
    }
    uint4 dx = *reinterpret_cast<const uint4*>(Xp + own);
    float xf[8]; unp8(xf, dx);
    float h[8];
    #pragma unroll
    for (int k=0;k<8;++k) h[k] = fmaf(0.95f, acc[k], 0.05f*xf[k]);
    h2s[c*8 + tbi] = pack8(h);
  }
  __syncthreads();
  // phase B: 1x1 conv accumulation
  float acc2[8];
  if (side == 0){
    float bias = b1[c] + b2[c];
    #pragma unroll
    for (int k=0;k<8;++k) acc2[k] = bias;
  } else {
    #pragma unroll
    for (int k=0;k<8;++k) acc2[k] = 0.f;
  }
  const bf16* xslab = Xp + vbase + tb;
  const bf16* hslab = HA + vbase + tb;
  if (side == 0){
    for (int c2=0;c2<NC;++c2){
      float w0 = wlds[c2*96 + c];
      float w1 = wlds[c2*96 + 32 + c];
      float w2 = wlds[c2*96 + 64 + c];
      uint4 dX = *reinterpret_cast<const uint4*>(xslab + c2*64);
      uint4 dH = *reinterpret_cast<const uint4*>(hslab + c2*64);
      uint4 d2 = h2s[c2*8 + tbi];
      fma8(acc2, dX, w0);
      fma8(acc2, dH, w1);
      fma8(acc2, d2, w2);
    }
  } else {
    for (int c2=0;c2<NC;++c2){
      float w0 = wlds[c2*64 + c];
      float w1 = wlds[c2*64 + 32 + c];
      uint4 dH = *reinterpret_cast<const uint4*>(hslab + c2*64);
      uint4 d2 = h2s[c2*8 + tbi];
      fma8(acc2, dH, w0);
      fma8(acc2, d2, w1);
    }
  }
  // store (out layout [b][c][v][58])
  size_t obase = ((size_t)(b*NC + c)*NNODE + v)*NTOUT + tb;
  float* po = out + obase;
  if (side == 0){
    if (tb < 56){
      #pragma unroll
      for (int k=0;k<4;++k)
        *reinterpret_cast<float2*>(po + 2*k) = make_float2(acc2[2*k], acc2[2*k+1]);
    } else {
      *reinterpret_cast<float2*>(po) = make_float2(acc2[0], acc2[1]);
    }
  } else {
    const float* rx = x + ((size_t)(b*NC + c)*NNODE + v)*NT + 6 + tb;
    if (tb < 56){
      #pragma unroll
      for (int k=0;k<4;++k){
        float2 ov = *reinterpret_cast<const float2*>(po + 2*k);
        float2 rv = *reinterpret_cast<const float2*>(rx + 2*k);
        ov.x += acc2[2*k]   + rv.x;
        ov.y += acc2[2*k+1] + rv.y;
        *reinterpret_cast<float2*>(po + 2*k) = ov;
      }
    } else {
      float2 ov = *reinterpret_cast<const float2*>(po);
      float2 rv = *reinterpret_cast<const float2*>(rx);
      ov.x += acc2[0] + rv.x;
      ov.y += acc2[1] + rv.y;
      *reinterpret_cast<float2*>(po) = ov;
    }
  }
}

// ---------------- layernorm ----------------
__global__ void __launch_bounds__(256) k_lnstat(const float* __restrict__ out, double* __restrict__ part){
  int blk = blockIdx.x; int b = blk >> 3, seg = blk & 7;
  const float* p = out + (size_t)b*BSLAB;
  int start = seg*69600, end = start + 69600;
  double s = 0.0, s2 = 0.0;
  for (int i = start + threadIdx.x; i < end; i += 256){
    double v = (double)p[i]; s += v; s2 += v*v;
  }
  #pragma unroll
  for (int off=32; off; off>>=1){ s += __shfl_down(s, off); s2 += __shfl_down(s2, off); }
  __shared__ double ls[4], ls2[4];
  int lane = threadIdx.x & 63, w = threadIdx.x >> 6;
  if (lane==0){ ls[w]=s; ls2[w]=s2; }
  __syncthreads();
  if (threadIdx.x==0){
    double a=0.0, a2=0.0;
    for (int i=0;i<4;++i){ a+=ls[i]; a2+=ls2[i]; }
    part[blk*2]=a; part[blk*2+1]=a2;
  }
}

__global__ void k_lnfin(const double* __restrict__ part, float* __restrict__ stats){
  int b = threadIdx.x; if (b >= 32) return;
  double s=0.0, s2=0.0;
  for (int seg=0; seg<8; ++seg){ s += part[(b*8+seg)*2]; s2 += part[(b*8+seg)*2+1]; }
  double n = (double)BSLAB;
  double mean = s/n;
  double var = s2/n - mean*mean;
  stats[b*2]   = (float)mean;
  stats[b*2+1] = (float)(1.0/sqrt(var + 1e-5));
}

__global__ void __launch_bounds__(256) k_lnapply(float* __restrict__ out, const float* __restrict__ stats,
        const float* __restrict__ lnw, const float* __restrict__ lnb, const int* __restrict__ idxp){
  int o = blockIdx.x*256 + threadIdx.x;
  int t = o % NTOUT; int v = (o / NTOUT) % NNODE; int c = (o / SLAB) % NC; int b = o / BSLAB;
  float mean = stats[b*2], rstd = stats[b*2+1];
  int vn = idxp[v];
  float wv = lnw[((size_t)c*NNODE + vn)*NTOUT + t];
  float bv = lnb[((size_t)c*NNODE + vn)*NTOUT + t];
  float vx = out[o];
  out[o] = (vx - mean)*rstd*wv + bv;
}

extern "C" void kernel_launch(void* const* d_in, const int* in_sizes, int n_in,
                              void* d_out, int out_size, void* d_ws, size_t ws_size,
                              hipStream_t stream) {
  (void)in_sizes; (void)n_in; (void)out_size; (void)ws_size;
  const float* x     = (const float*)d_in[0];
  const float* xskip = (const float*)d_in[1];
  const int*   idxp  = (const int*)d_in[2];
  const float* emb1  = (const float*)d_in[3];
  const float* emb2  = (const float*)d_in[4];
  const float* l1w   = (const float*)d_in[5];
  const float* l1b   = (const float*)d_in[6];
  const float* l2w   = (const float*)d_in[7];
  const float* l2b   = (const float*)d_in[8];
  const float* skw   = (const float*)d_in[9];
  const float* skb   = (const float*)d_in[10];
  const float* m1w   = (const float*)d_in[11];
  const float* m1b   = (const float*)d_in[12];
  const float* m2w   = (const float*)d_in[13];
  const float* m2b   = (const float*)d_in[14];
  const float* lnw   = (const float*)d_in[15];
  const float* lnb   = (const float*)d_in[16];
  const float* fw2=(const float*)d_in[17]; const float* fb2=(const float*)d_in[18];
  const float* gw2=(const float*)d_in[19]; const float* gb2=(const float*)d_in[20];
  const float* fw3=(const float*)d_in[21]; const float* fb3=(const float*)d_in[22];
  const float* gw3=(const float*)d_in[23]; const float* gb3=(const float*)d_in[24];
  const float* fw6=(const float*)d_in[25]; const float* fb6=(const float*)d_in[26];
  const float* gw6=(const float*)d_in[27]; const float* gb6=(const float*)d_in[28];
  const float* fw7=(const float*)d_in[29]; const float* fb7=(const float*)d_in[30];
  const float* gw7=(const float*)d_in[31]; const float* gb7=(const float*)d_in[32];
  float* out = (float*)d_out;

  char* wsbase = (char*)d_ws;
  size_t cur = 0;
  auto alloc = [&](size_t bytes)->char*{
    char* p = wsbase + cur;
    cur = (cur + bytes + 255) & ~(size_t)255;
    return p;
  };
  bf16*  Xp   = (bf16*) alloc((size_t)XPEL*2);
  bf16*  HA   = (bf16*) alloc((size_t)XPEL*2);
  float* n1   = (float*)alloc(12000*4);
  float* n2   = (float*)alloc(12000*4);
  float* Am   = (float*)alloc(90000*4);
  int*   aidx = (int*)  alloc(600*304*4);
  float* aval = (float*)alloc(600*304*4);
  int*   acnt = (int*)  alloc(600*4);
  float* wT   = (float*)alloc(1856*64*4);
  float* wp   = (float*)alloc(9216*4);
  float* pk0  = (float*)alloc(3072*4);
  float* pk1  = (float*)alloc(2048*4);
  double* part = (double*)alloc(256*2*8);
  float* stats = (float*)alloc(64*4);

  // graph construction (tiny)
  k_nodes <<<NNODE, 64, 0, stream>>>(emb1, emb2, l1w, l1b, l2w, l2b, idxp, n1, n2);
  k_adjrow<<<NNODE, 64, 0, stream>>>(n1, n2, Am);
  k_csr   <<<2*NNODE, 64, 0, stream>>>(Am, aidx, aval, acnt);

  // weight prep
  k_wpack<<<36, 256, 0, stream>>>(fw2,fw3,fw6,fw7, gw2,gw3,gw6,gw7, wp);
  k_wprep<<<20, 256, 0, stream>>>(m1w, m2w, pk0, pk1);
  k_wT   <<<464, 256, 0, stream>>>(skw, wT);

  // dilated inception -> Xp
  k_incep<<<NB*NNODE, 256, 0, stream>>>(x, wp, fb2,fb3,fb6,fb7, gb2,gb3,gb6,gb7, Xp);

  // skip path
  k_skip<<<(NB*NNODE)/8, 256, 0, stream>>>(Xp, wT, skb, xskip, out);

  // mixprop side 0 (A)
  k_prop<<<NB*NNODE, 256, 0, stream>>>(Xp, HA, aidx, aval, acnt, 0);
  k_fuse<<<NB*NNODE, 256, 0, stream>>>(Xp, HA, out, x, aidx, aval, acnt, pk0, m1b, m2b, 0, 0);

  // mixprop side 1 (A^T)
  k_prop<<<NB*NNODE, 256, 0, stream>>>(Xp, HA, aidx, aval, acnt, NNODE);
  k_fuse<<<NB*NNODE, 256, 0, stream>>>(Xp, HA, out, x, aidx, aval, acnt, pk1, m1b, m2b, NNODE, 1);

  // layernorm
  k_lnstat<<<256, 256, 0, stream>>>(out, part);
  k_lnfin<<<1, 32, 0, stream>>>(part, stats);
  k_lnapply<<<XEL/256, 256, 0, stream>>>(out, stats, lnw, lnb, idxp);
}

// Round 6
// 617.605 us; speedup vs baseline: 2.3451x; 1.1589x over previous
//
#include <hip/hip_runtime.h>
#include <hip/hip_bf16.h>
#include <math.h>

typedef __hip_bfloat16 bf16;
typedef __attribute__((ext_vector_type(8))) short bf16x8;
typedef __attribute__((ext_vector_type(4))) float f32x4;

#define NB 32
#define NC 32
#define NNODE 300
#define NT 64
#define NDIM 40
#define KTOP 20
#define NSKIP 64
#define NTOUT 58
#define SLAB 17400        // NNODE*NTOUT (out layout)
#define BSLAB 556800      // NC*SLAB
#define XEL 17817600      // NB*BSLAB
#define PSLAB 2048        // NC*64 padded node slab
#define BPSLAB 614400     // NNODE*PSLAB
#define XPEL 19660800     // NB*BPSLAB

__device__ __forceinline__ float b2f(bf16 v){ return __bfloat162float(v); }
__device__ __forceinline__ bf16 f2b(float v){ return __float2bfloat16(v); }
__device__ __forceinline__ float fsig(float x){ return 1.0f/(1.0f + __expf(-x)); }
__device__ __forceinline__ float ftanh(float x){ return 2.0f*fsig(2.0f*x) - 1.0f; }

__device__ __forceinline__ unsigned short bbits(float v){
  bf16 h = f2b(v); unsigned short s; __builtin_memcpy(&s, &h, 2); return s;
}

// 8 bf16 in a uint4: acc[k] += vv * e[k]
__device__ __forceinline__ void fma8(float acc[8], uint4 d, float vv){
  acc[0] = fmaf(vv, __uint_as_float(d.x << 16),          acc[0]);
  acc[1] = fmaf(vv, __uint_as_float(d.x & 0xffff0000u),  acc[1]);
  acc[2] = fmaf(vv, __uint_as_float(d.y << 16),          acc[2]);
  acc[3] = fmaf(vv, __uint_as_float(d.y & 0xffff0000u),  acc[3]);
  acc[4] = fmaf(vv, __uint_as_float(d.z << 16),          acc[4]);
  acc[5] = fmaf(vv, __uint_as_float(d.z & 0xffff0000u),  acc[5]);
  acc[6] = fmaf(vv, __uint_as_float(d.w << 16),          acc[6]);
  acc[7] = fmaf(vv, __uint_as_float(d.w & 0xffff0000u),  acc[7]);
}

__device__ __forceinline__ void unp8(float f[8], uint4 d){
  f[0] = __uint_as_float(d.x << 16); f[1] = __uint_as_float(d.x & 0xffff0000u);
  f[2] = __uint_as_float(d.y << 16); f[3] = __uint_as_float(d.y & 0xffff0000u);
  f[4] = __uint_as_float(d.z << 16); f[5] = __uint_as_float(d.z & 0xffff0000u);
  f[6] = __uint_as_float(d.w << 16); f[7] = __uint_as_float(d.w & 0xffff0000u);
}

__device__ __forceinline__ uint4 pack8(const float f[8]){
  uint4 d;
  d.x = (unsigned)bbits(f[0]) | ((unsigned)bbits(f[1]) << 16);
  d.y = (unsigned)bbits(f[2]) | ((unsigned)bbits(f[3]) << 16);
  d.z = (unsigned)bbits(f[4]) | ((unsigned)bbits(f[5]) << 16);
  d.w = (unsigned)bbits(f[6]) | ((unsigned)bbits(f[7]) << 16);
  return d;
}

// XCD-aware swizzle for 9600-block graph kernels: XCD k gets b in [k*4, k*4+4)
__device__ __forceinline__ void bv_swz(int bid, int& b, int& v){
  int xcd = bid & 7, i = bid >> 3;
  int nb = xcd*1200 + i;
  b = nb / NNODE; v = nb - b*NNODE;
}

// ---------------- graph construction ----------------
__global__ void k_nodes(const float* __restrict__ emb1, const float* __restrict__ emb2,
                        const float* __restrict__ l1w, const float* __restrict__ l1b,
                        const float* __restrict__ l2w, const float* __restrict__ l2b,
                        const int* __restrict__ idxp,
                        float* __restrict__ n1, float* __restrict__ n2){
  int i = blockIdx.x; int d = threadIdx.x;
  if (d >= NDIM) return;
  int r = idxp[i];
  float a1 = l1b[d], a2 = l2b[d];
  for (int k=0;k<NDIM;++k){
    a1 = fmaf(emb1[r*NDIM+k], l1w[d*NDIM+k], a1);
    a2 = fmaf(emb2[r*NDIM+k], l2w[d*NDIM+k], a2);
  }
  n1[i*NDIM+d] = tanhf(3.0f*a1);
  n2[i*NDIM+d] = tanhf(3.0f*a2);
}

__global__ void __launch_bounds__(64) k_adjrow(const float* __restrict__ n1,
                                               const float* __restrict__ n2,
                                               float* __restrict__ Am){
  int i = blockIdx.x; int lane = threadIdx.x;
  __shared__ float rowo[NNODE];
  __shared__ float rowv[NNODE];
  __shared__ int   sel[NNODE];
  for (int j=lane;j<NNODE;j+=64){
    float a = 0.f;
    #pragma unroll
    for (int k=0;k<NDIM;++k){
      float a1 = n1[i*NDIM+k], a2 = n2[i*NDIM+k];
      a = fmaf(a1, n2[j*NDIM+k], a);
      a = fmaf(-a2, n1[j*NDIM+k], a);
    }
    float v = tanhf(3.0f*a);
    v = v > 0.f ? v : 0.f;
    rowo[j]=v; rowv[j]=v; sel[j]=0;
  }
  __syncthreads();
  for (int it=0; it<KTOP; ++it){
    float best = -1.f; int bi = 0x7fffffff;
    for (int j=lane;j<NNODE;j+=64){
      float v = rowv[j];
      if (v > best){ best=v; bi=j; }
    }
    #pragma unroll
    for (int off=32; off; off>>=1){
      float ov = __shfl_xor(best, off);
      int   oi = __shfl_xor(bi, off);
      if (ov > best || (ov == best && oi < bi)){ best=ov; bi=oi; }
    }
    if (lane==0){ sel[bi]=1; rowv[bi]=-2.f; }
    __syncthreads();
  }
  for (int j=lane;j<NNODE;j+=64)
    Am[i*NNODE+j] = sel[j] ? rowo[j] : 0.f;
}

__global__ void __launch_bounds__(64) k_csr(const float* __restrict__ Am,
                                            int* __restrict__ aidx, float* __restrict__ aval,
                                            int* __restrict__ acnt){
  int r = blockIdx.x; int lane = threadIdx.x;
  int v = (r < NNODE) ? r : r - NNODE;
  int*   ip = aidx + r*304;
  float* vp = aval + r*304;
  if (lane==0){ ip[0]=v; vp[0]=1.0f; }
  int cnt = 1; float s = 1.0f;
  for (int base=0; base<NNODE; base+=64){
    int j = base + lane; float val = 0.f; bool p = false;
    if (j < NNODE){
      val = (r < NNODE) ? Am[v*NNODE + j] : Am[j*NNODE + v];
      p = val > 0.f;
    }
    unsigned long long m = __ballot(p);
    int pre = __popcll(m & ((1ull << lane) - 1ull));
    if (p){ ip[cnt+pre]=j; vp[cnt+pre]=val; }
    cnt += __popcll(m);
    float vs = p ? val : 0.f;
    #pragma unroll
    for (int off=32; off; off>>=1) vs += __shfl_xor(vs, off);
    s += vs;
  }
  for (int e=lane; e<cnt; e+=64) vp[e] = vp[e] / s;
  if (lane==0) acnt[r]=cnt;
}

// ---------------- inception weight fragment packing for MFMA ----------------
// W rows interleaved: m = 2c+path (path 0=filter, 1=gate), K = ic*7+d (d: window pos, 7=max kernel)
// wfA[((mt*7 + ks)*64 + l)*8 + j] = Wmat[mt*16 + (l&15)][ks*32 + (l>>4)*8 + j] as bf16
// biasPk[c*2+{0,1}] = (filter bias, gate bias) for channel c
__global__ void k_wpack2(const float* __restrict__ fw2,const float* __restrict__ fw3,
                         const float* __restrict__ fw6,const float* __restrict__ fw7,
                         const float* __restrict__ gw2,const float* __restrict__ gw3,
                         const float* __restrict__ gw6,const float* __restrict__ gw7,
                         const float* __restrict__ fb2,const float* __restrict__ fb3,
                         const float* __restrict__ fb6,const float* __restrict__ fb7,
                         const float* __restrict__ gb2,const float* __restrict__ gb3,
                         const float* __restrict__ gb6,const float* __restrict__ gb7,
                         bf16* __restrict__ wfA, float* __restrict__ biasPk){
  int T = blockIdx.x*blockDim.x + threadIdx.x;
  if (T < 14336){
    int j = T & 7;
    int q = T >> 3;
    int l = q & 63; q >>= 6;
    int ks = q % 7, mt = q / 7;
    int m = mt*16 + (l & 15);
    int k = ks*32 + (l >> 4)*8 + j;
    int c = m >> 1, path = m & 1;
    int cls = c >> 3, o = c & 7;
    int ic = k / 7, d = k - ic*7;
    int kk = (cls==0) ? 2 : (cls==1) ? 3 : (cls==2) ? 6 : 7;
    int tp = d - (7 - kk);
    float val = 0.f;
    if (tp >= 0){
      const float* w = (path==0)
        ? (cls==0?fw2:cls==1?fw3:cls==2?fw6:fw7)
        : (cls==0?gw2:cls==1?gw3:cls==2?gw6:gw7);
      val = w[(o*NC + ic)*kk + tp];
    }
    wfA[T] = f2b(val);
  } else if (T < 14336 + 32){
    int c = T - 14336;
    int cls = c >> 3, o = c & 7;
    const float* fb = cls==0?fb2:cls==1?fb3:cls==2?fb6:fb7;
    const float* gb = cls==0?gb2:cls==1?gb3:cls==2?gb6:gb7;
    biasPk[c*2]   = fb[o];
    biasPk[c*2+1] = gb[o];
  }
}

// pk0[c2*96 + seg*32 + c]: seg0 = m1w[c,c2]+m2w[c,c2]; seg1 = m1w[c,32+c2]; seg2 = m1w[c,64+c2]
// pk1[c2*64 + seg*32 + c]: seg0 = m2w[c,32+c2]; seg1 = m2w[c,64+c2]
__global__ void k_wprep(const float* __restrict__ m1w, const float* __restrict__ m2w,
                        float* __restrict__ pk0, float* __restrict__ pk1){
  int id = blockIdx.x*blockDim.x + threadIdx.x;
  if (id < 3072){
    int c2 = id / 96, r = id % 96, seg = r / 32, c = r % 32;
    float val;
    if (seg==0)      val = m1w[c*96 + c2] + m2w[c*96 + c2];
    else if (seg==1) val = m1w[c*96 + 32 + c2];
    else             val = m1w[c*96 + 64 + c2];
    pk0[c2*96 + seg*32 + c] = val;
  } else if (id < 5120){
    int id2 = id - 3072;
    int c2 = id2 / 64, r = id2 % 64, seg = r / 32, c = r % 32;
    pk1[c2*64 + seg*32 + c] = seg==0 ? m2w[c*96 + 32 + c2] : m2w[c*96 + 64 + c2];
  }
}

// ---------------- dilated inception via MFMA -> Xp[b][n][c][64] bf16 (pad zeroed) ----------------
// C[64 m][64 t] = W[64][224] x Xc[224][64];  m=2c+path so each lane's 4 accs = (f,g) x 2 channels
__global__ void __launch_bounds__(256) k_incepM(const float* __restrict__ x,
    const bf16* __restrict__ wfA, const float* __restrict__ biasPk,
    bf16* __restrict__ Xp){
  __shared__ bf16 xsb[32*72];       // [ic][72] (t padded to 72, zeros in 64..71)
  __shared__ uint4 xim2[28*64];     // [kb][t] : 8 bf16 (k = kb*8+j)
  int b, n; bv_swz(blockIdx.x, b, n);
  int bn = b*NNODE + n;
  int tid = threadIdx.x;
  // stage x -> bf16 LDS
  {
    int c = tid >> 3, t0 = (tid & 7)*8;
    const float* src = x + ((size_t)(b*NC + c)*NNODE + n)*NT + t0;
    float4 v0 = *reinterpret_cast<const float4*>(src);
    float4 v1 = *reinterpret_cast<const float4*>(src + 4);
    float f[8] = {v0.x,v0.y,v0.z,v0.w,v1.x,v1.y,v1.z,v1.w};
    *reinterpret_cast<uint4*>(&xsb[c*72 + t0]) = pack8(f);
    if ((tid & 7) == 7)
      *reinterpret_cast<uint4*>(&xsb[c*72 + 64]) = make_uint4(0,0,0,0);
  }
  __syncthreads();
  // im2col: xim2[kb][t][j] = xsb[ic(kb*8+j)][t + d(kb*8+j)]
  #pragma unroll
  for (int i=0;i<7;++i){
    int pr = tid + i*256;          // 0..1791
    int kb = pr >> 6, t = pr & 63;
    int k0 = kb*8;
    int ic = k0 / 7, d = k0 - ic*7;
    unsigned sh[8];
    #pragma unroll
    for (int j=0;j<8;++j){
      sh[j] = *reinterpret_cast<const unsigned short*>(&xsb[ic*72 + t + d]);
      ++d; if (d == 7){ d = 0; ++ic; }
    }
    xim2[kb*64 + t] = make_uint4(sh[0]|(sh[1]<<16), sh[2]|(sh[3]<<16),
                                 sh[4]|(sh[5]<<16), sh[6]|(sh[7]<<16));
  }
  __syncthreads();
  // MFMA phase: wave mt owns rows mt*16..mt*16+15
  int lane = tid & 63;
  int mt = __builtin_amdgcn_readfirstlane(tid >> 6);
  bf16x8 wA[7];
  #pragma unroll
  for (int ks=0; ks<7; ++ks)
    wA[ks] = *reinterpret_cast<const bf16x8*>(wfA + (size_t)((mt*7 + ks)*64 + lane)*8);
  int g = lane >> 4;
  int c0 = mt*8 + 2*g;
  float4 bias2 = *reinterpret_cast<const float4*>(biasPk + c0*2);
  #pragma unroll
  for (int nt=0; nt<4; ++nt){
    int t = (lane & 15) + nt*16;
    f32x4 acc = {0.f, 0.f, 0.f, 0.f};
    #pragma unroll
    for (int ks=0; ks<7; ++ks){
      bf16x8 bfr = __builtin_bit_cast(bf16x8, xim2[(ks*4 + g)*64 + t]);
      acc = __builtin_amdgcn_mfma_f32_16x16x32_bf16(wA[ks], bfr, acc, 0, 0, 0);
    }
    bool act = t < NTOUT;
    float X0 = ftanh(acc[0] + bias2.x) * fsig(acc[1] + bias2.y);
    float X1 = ftanh(acc[2] + bias2.z) * fsig(acc[3] + bias2.w);
    size_t base = (size_t)bn*PSLAB + t;
    Xp[base + (size_t)c0*64]       = f2b(act ? X0 : 0.f);
    Xp[base + (size_t)(c0+1)*64]   = f2b(act ? X1 : 0.f);
  }
}

// ---------------- skip path ----------------
__global__ void k_wT(const float* __restrict__ sw, float* __restrict__ wT){
  int id = blockIdx.x*blockDim.x + threadIdx.x;
  if (id >= 1856*64) return;
  int kk = id >> 6, sc = id & 63;
  wT[kk*64 + sc] = sw[sc*1856 + kk];
}

__global__ void __launch_bounds__(256) k_skip(const bf16* __restrict__ Xp, const float* __restrict__ wT,
      const float* __restrict__ skip_b, const float* __restrict__ x_skip, float* __restrict__ out){
  __shared__ float Xs[8*1856];
  int tid = threadIdx.x;
  int bp0 = blockIdx.x*8;
  for (int idx = tid; idx < 8*1856; idx += 256){
    int p = idx / 1856, kk = idx - p*1856;
    int c = kk / NTOUT, t = kk - c*NTOUT;
    int gp = bp0 + p; int b = gp / NNODE, n = gp - b*NNODE;
    Xs[idx] = b2f(Xp[(size_t)(b*NNODE+n)*PSLAB + c*64 + t]);
  }
  __syncthreads();
  int lane = tid & 63, w = tid >> 6;
  int kk0 = w*464;
  float acc[8] = {0,0,0,0,0,0,0,0};
  for (int kk = kk0; kk < kk0+464; kk += 4){
    float wv0 = wT[(kk+0)*64 + lane];
    float wv1 = wT[(kk+1)*64 + lane];
    float wv2 = wT[(kk+2)*64 + lane];
    float wv3 = wT[(kk+3)*64 + lane];
    #pragma unroll
    for (int p=0;p<8;++p){
      const float4 xv = *reinterpret_cast<const float4*>(&Xs[p*1856 + kk]);
      acc[p] = fmaf(xv.x, wv0, acc[p]);
      acc[p] = fmaf(xv.y, wv1, acc[p]);
      acc[p] = fmaf(xv.z, wv2, acc[p]);
      acc[p] = fmaf(xv.w, wv3, acc[p]);
    }
  }
  __syncthreads();
  float* red = Xs;
  #pragma unroll
  for (int p=0;p<8;++p) red[w*512 + p*64 + lane] = acc[p];
  __syncthreads();
  #pragma unroll
  for (int pi=0; pi<2; ++pi){
    int p = w*2 + pi;
    float s = red[p*64+lane] + red[512+p*64+lane] + red[1024+p*64+lane] + red[1536+p*64+lane];
    int gp = bp0 + p, b = gp / NNODE, n = gp - b*NNODE;
    size_t so = (size_t)b*NSKIP*NNODE + (size_t)lane*NNODE + n;
    out[(size_t)XEL + so] = s + skip_b[lane] + x_skip[so];
  }
}

// ---------------- hop1: HA = 0.05*Xp + 0.95*(Ah (x) Xp) ----------------
__global__ void __launch_bounds__(256) k_prop(const bf16* __restrict__ Xp, bf16* __restrict__ HA,
    const int* __restrict__ aidx, const float* __restrict__ aval, const int* __restrict__ acnt,
    int rowoff){
  __shared__ int   sidx[304];
  __shared__ float sval[304];
  int b, v; bv_swz(blockIdx.x, b, v);
  int r = rowoff + v;
  int cnt = acnt[r];
  for (int e = threadIdx.x; e < cnt; e += 256){
    sidx[e] = aidx[r*304 + e] * PSLAB;
    sval[e] = aval[r*304 + e];
  }
  __syncthreads();
  int lane = threadIdx.x & 63, w = threadIdx.x >> 6;
  int c = w*8 + (lane >> 3);
  int tb = (lane & 7) * 8;
  size_t cbase = (size_t)b*BPSLAB + c*64 + tb;
  size_t own   = cbase + (size_t)v*PSLAB;
  const bf16* base = Xp + cbase;
  float acc[8] = {0,0,0,0,0,0,0,0};
  #pragma unroll 2
  for (int j=0;j<cnt;++j){
    uint4 d = *reinterpret_cast<const uint4*>(base + sidx[j]);
    fma8(acc, d, sval[j]);
  }
  uint4 dx = *reinterpret_cast<const uint4*>(Xp + own);
  float xf[8]; unp8(xf, dx);
  float h[8];
  #pragma unroll
  for (int k=0;k<8;++k) h[k] = fmaf(0.95f, acc[k], 0.05f*xf[k]);
  *reinterpret_cast<uint4*>(HA + own) = pack8(h);
}

// ---------------- hop2 + 1x1 mix conv, fused ----------------
__global__ void __launch_bounds__(256) k_fuse(const bf16* __restrict__ Xp, const bf16* __restrict__ HA,
    float* __restrict__ out, const float* __restrict__ x,
    const int* __restrict__ aidx, const float* __restrict__ aval, const int* __restrict__ acnt,
    const float* __restrict__ pk, const float* __restrict__ b1, const float* __restrict__ b2,
    int rowoff, int side){
  __shared__ int   sidx[304];
  __shared__ float sval[304];
  __shared__ uint4 h2s[256];     // [c][tbi] 8 bf16 each
  __shared__ float wlds[3072];
  int b, v; bv_swz(blockIdx.x, b, v);
  int r = rowoff + v;
  int cnt = acnt[r];
  for (int e = threadIdx.x; e < cnt; e += 256){
    sidx[e] = aidx[r*304 + e] * PSLAB;
    sval[e] = aval[r*304 + e];
  }
  int npk = (side == 0) ? 3072 : 2048;
  for (int e = threadIdx.x; e < npk; e += 256) wlds[e] = pk[e];
  __syncthreads();
  int lane = threadIdx.x & 63, w = threadIdx.x >> 6;
  int c   = w*8 + (lane >> 3);
  int tbi = lane & 7;
  int tb  = tbi * 8;
  size_t bbase = (size_t)b*BPSLAB;
  size_t vbase = bbase + (size_t)v*PSLAB;
  size_t own   = vbase + c*64 + tb;
  // phase A: hop2 gather over HA
  {
    const bf16* base = HA + bbase + c*64 + tb;
    float acc[8] = {0,0,0,0,0,0,0,0};
    #pragma unroll 2
    for (int j=0;j<cnt;++j){
      uint4 d = *reinterpret_cast<const uint4*>(base + sidx[j]);
      fma8(acc, d, sval[j]);
    }
    uint4 dx = *reinterpret_cast<const uint4*>(Xp + own);
    float xf[8]; unp8(xf, dx);
    float h[8];
    #pragma unroll
    for (int k=0;k<8;++k) h[k] = fmaf(0.95f, acc[k], 0.05f*xf[k]);
    h2s[c*8 + tbi] = pack8(h);
  }
  __syncthreads();
  // phase B: 1x1 conv accumulation
  float acc2[8];
  if (side == 0){
    float bias = b1[c] + b2[c];
    #pragma unroll
    for (int k=0;k<8;++k) acc2[k] = bias;
  } else {
    #pragma unroll
    for (int k=0;k<8;++k) acc2[k] = 0.f;
  }
  const bf16* xslab = Xp + vbase + tb;
  const bf16* hslab = HA + vbase + tb;
  if (side == 0){
    for (int c2=0;c2<NC;++c2){
      float w0 = wlds[c2*96 + c];
      float w1 = wlds[c2*96 + 32 + c];
      float w2 = wlds[c2*96 + 64 + c];
      uint4 dX = *reinterpret_cast<const uint4*>(xslab + c2*64);
      uint4 dH = *reinterpret_cast<const uint4*>(hslab + c2*64);
      uint4 d2 = h2s[c2*8 + tbi];
      fma8(acc2, dX, w0);
      fma8(acc2, dH, w1);
      fma8(acc2, d2, w2);
    }
  } else {
    for (int c2=0;c2<NC;++c2){
      float w0 = wlds[c2*64 + c];
      float w1 = wlds[c2*64 + 32 + c];
      uint4 dH = *reinterpret_cast<const uint4*>(hslab + c2*64);
      uint4 d2 = h2s[c2*8 + tbi];
      fma8(acc2, dH, w0);
      fma8(acc2, d2, w1);
    }
  }
  // store (out layout [b][c][v][58])
  size_t obase = ((size_t)(b*NC + c)*NNODE + v)*NTOUT + tb;
  float* po = out + obase;
  if (side == 0){
    if (tb < 56){
      #pragma unroll
      for (int k=0;k<4;++k)
        *reinterpret_cast<float2*>(po + 2*k) = make_float2(acc2[2*k], acc2[2*k+1]);
    } else {
      *reinterpret_cast<float2*>(po) = make_float2(acc2[0], acc2[1]);
    }
  } else {
    const float* rx = x + ((size_t)(b*NC + c)*NNODE + v)*NT + 6 + tb;
    if (tb < 56){
      #pragma unroll
      for (int k=0;k<4;++k){
        float2 ov = *reinterpret_cast<const float2*>(po + 2*k);
        float2 rv = *reinterpret_cast<const float2*>(rx + 2*k);
        ov.x += acc2[2*k]   + rv.x;
        ov.y += acc2[2*k+1] + rv.y;
        *reinterpret_cast<float2*>(po + 2*k) = ov;
      }
    } else {
      float2 ov = *reinterpret_cast<const float2*>(po);
      float2 rv = *reinterpret_cast<const float2*>(rx);
      ov.x += acc2[0] + rv.x;
      ov.y += acc2[1] + rv.y;
      *reinterpret_cast<float2*>(po) = ov;
    }
  }
}

// ---------------- layernorm ----------------
__global__ void __launch_bounds__(256) k_lnstat(const float* __restrict__ out, double* __restrict__ part){
  int blk = blockIdx.x; int b = blk >> 3, seg = blk & 7;
  const float* p = out + (size_t)b*BSLAB;
  int start = seg*69600, end = start + 69600;
  double s = 0.0, s2 = 0.0;
  for (int i = start + threadIdx.x; i < end; i += 256){
    double v = (double)p[i]; s += v; s2 += v*v;
  }
  #pragma unroll
  for (int off=32; off; off>>=1){ s += __shfl_down(s, off); s2 += __shfl_down(s2, off); }
  __shared__ double ls[4], ls2[4];
  int lane = threadIdx.x & 63, w = threadIdx.x >> 6;
  if (lane==0){ ls[w]=s; ls2[w]=s2; }
  __syncthreads();
  if (threadIdx.x==0){
    double a=0.0, a2=0.0;
    for (int i=0;i<4;++i){ a+=ls[i]; a2+=ls2[i]; }
    part[blk*2]=a; part[blk*2+1]=a2;
  }
}

__global__ void k_lnfin(const double* __restrict__ part, float* __restrict__ stats){
  int b = threadIdx.x; if (b >= 32) return;
  double s=0.0, s2=0.0;
  for (int seg=0; seg<8; ++seg){ s += part[(b*8+seg)*2]; s2 += part[(b*8+seg)*2+1]; }
  double n = (double)BSLAB;
  double mean = s/n;
  double var = s2/n - mean*mean;
  stats[b*2]   = (float)mean;
  stats[b*2+1] = (float)(1.0/sqrt(var + 1e-5));
}

__global__ void __launch_bounds__(256) k_lnapply(float* __restrict__ out, const float* __restrict__ stats,
        const float* __restrict__ lnw, const float* __restrict__ lnb, const int* __restrict__ idxp){
  int o = blockIdx.x*256 + threadIdx.x;
  int t = o % NTOUT; int v = (o / NTOUT) % NNODE; int c = (o / SLAB) % NC; int b = o / BSLAB;
  float mean = stats[b*2], rstd = stats[b*2+1];
  int vn = idxp[v];
  float wv = lnw[((size_t)c*NNODE + vn)*NTOUT + t];
  float bv = lnb[((size_t)c*NNODE + vn)*NTOUT + t];
  float vx = out[o];
  out[o] = (vx - mean)*rstd*wv + bv;
}

extern "C" void kernel_launch(void* const* d_in, const int* in_sizes, int n_in,
                              void* d_out, int out_size, void* d_ws, size_t ws_size,
                              hipStream_t stream) {
  (void)in_sizes; (void)n_in; (void)out_size; (void)ws_size;
  const float* x     = (const float*)d_in[0];
  const float* xskip = (const float*)d_in[1];
  const int*   idxp  = (const int*)d_in[2];
  const float* emb1  = (const float*)d_in[3];
  const float* emb2  = (const float*)d_in[4];
  const float* l1w   = (const float*)d_in[5];
  const float* l1b   = (const float*)d_in[6];
  const float* l2w   = (const float*)d_in[7];
  const float* l2b   = (const float*)d_in[8];
  const float* skw   = (const float*)d_in[9];
  const float* skb   = (const float*)d_in[10];
  const float* m1w   = (const float*)d_in[11];
  const float* m1b   = (const float*)d_in[12];
  const float* m2w   = (const float*)d_in[13];
  const float* m2b   = (const float*)d_in[14];
  const float* lnw   = (const float*)d_in[15];
  const float* lnb   = (const float*)d_in[16];
  const float* fw2=(const float*)d_in[17]; const float* fb2=(const float*)d_in[18];
  const float* gw2=(const float*)d_in[19]; const float* gb2=(const float*)d_in[20];
  const float* fw3=(const float*)d_in[21]; const float* fb3=(const float*)d_in[22];
  const float* gw3=(const float*)d_in[23]; const float* gb3=(const float*)d_in[24];
  const float* fw6=(const float*)d_in[25]; const float* fb6=(const float*)d_in[26];
  const float* gw6=(const float*)d_in[27]; const float* gb6=(const float*)d_in[28];
  const float* fw7=(const float*)d_in[29]; const float* fb7=(const float*)d_in[30];
  const float* gw7=(const float*)d_in[31]; const float* gb7=(const float*)d_in[32];
  float* out = (float*)d_out;

  char* wsbase = (char*)d_ws;
  size_t cur = 0;
  auto alloc = [&](size_t bytes)->char*{
    char* p = wsbase + cur;
    cur = (cur + bytes + 255) & ~(size_t)255;
    return p;
  };
  bf16*  Xp   = (bf16*) alloc((size_t)XPEL*2);
  bf16*  HA   = (bf16*) alloc((size_t)XPEL*2);
  float* n1   = (float*)alloc(12000*4);
  float* n2   = (float*)alloc(12000*4);
  float* Am   = (float*)alloc(90000*4);
  int*   aidx = (int*)  alloc(600*304*4);
  float* aval = (float*)alloc(600*304*4);
  int*   acnt = (int*)  alloc(600*4);
  float* wT   = (float*)alloc(1856*64*4);
  bf16*  wfA  = (bf16*) alloc(14336*2);
  float* biasPk = (float*)alloc(64*4);
  float* pk0  = (float*)alloc(3072*4);
  float* pk1  = (float*)alloc(2048*4);
  double* part = (double*)alloc(256*2*8);
  float* stats = (float*)alloc(64*4);

  // graph construction (tiny)
  k_nodes <<<NNODE, 64, 0, stream>>>(emb1, emb2, l1w, l1b, l2w, l2b, idxp, n1, n2);
  k_adjrow<<<NNODE, 64, 0, stream>>>(n1, n2, Am);
  k_csr   <<<2*NNODE, 64, 0, stream>>>(Am, aidx, aval, acnt);

  // weight prep
  k_wpack2<<<57, 256, 0, stream>>>(fw2,fw3,fw6,fw7, gw2,gw3,gw6,gw7,
                                   fb2,fb3,fb6,fb7, gb2,gb3,gb6,gb7, wfA, biasPk);
  k_wprep<<<20, 256, 0, stream>>>(m1w, m2w, pk0, pk1);
  k_wT   <<<464, 256, 0, stream>>>(skw, wT);

  // dilated inception -> Xp (MFMA)
  k_incepM<<<NB*NNODE, 256, 0, stream>>>(x, wfA, biasPk, Xp);

  // skip path
  k_skip<<<(NB*NNODE)/8, 256, 0, stream>>>(Xp, wT, skb, xskip, out);

  // mixprop side 0 (A)
  k_prop<<<NB*NNODE, 256, 0, stream>>>(Xp, HA, aidx, aval, acnt, 0);
  k_fuse<<<NB*NNODE, 256, 0, stream>>>(Xp, HA, out, x, aidx, aval, acnt, pk0, m1b, m2b, 0, 0);

  // mixprop side 1 (A^T)
  k_prop<<<NB*NNODE, 256, 0, stream>>>(Xp, HA, aidx, aval, acnt, NNODE);
  k_fuse<<<NB*NNODE, 256, 0, stream>>>(Xp, HA, out, x, aidx, aval, acnt, pk1, m1b, m2b, NNODE, 1);

  // layernorm
  k_lnstat<<<256, 256, 0, stream>>>(out, part);
  k_lnfin<<<1, 32, 0, stream>>>(part, stats);
  k_lnapply<<<XEL/256, 256, 0, stream>>>(out, stats, lnw, lnb, idxp);
}

// Round 7
// 489.648 us; speedup vs baseline: 2.9579x; 1.2613x over previous
//
#include <hip/hip_runtime.h>
#include <hip/hip_bf16.h>
#include <math.h>

typedef __hip_bfloat16 bf16;
typedef __attribute__((ext_vector_type(8))) short bf16x8;
typedef __attribute__((ext_vector_type(4))) float f32x4;

#define NB 32
#define NC 32
#define NNODE 300
#define NT 64
#define NDIM 40
#define KTOP 20
#define NSKIP 64
#define NTOUT 58
#define SLAB 17400        // NNODE*NTOUT (out layout)
#define BSLAB 556800      // NC*SLAB
#define XEL 17817600      // NB*BSLAB
#define PSLAB 2048        // 64 t x 32 c node slab (channel-minor)
#define BPSLAB 614400     // NNODE*PSLAB
#define XPEL 19660800     // NB*BPSLAB

__device__ __forceinline__ float b2f(bf16 v){ return __bfloat162float(v); }
__device__ __forceinline__ bf16 f2b(float v){ return __float2bfloat16(v); }
__device__ __forceinline__ float fsig(float x){ return 1.0f/(1.0f + __expf(-x)); }
__device__ __forceinline__ float ftanh(float x){ return 2.0f*fsig(2.0f*x) - 1.0f; }

__device__ __forceinline__ unsigned short bbits(float v){
  bf16 h = f2b(v); unsigned short s; __builtin_memcpy(&s, &h, 2); return s;
}

// 8 bf16 in a uint4: acc[k] += vv * e[k]
__device__ __forceinline__ void fma8(float acc[8], uint4 d, float vv){
  acc[0] = fmaf(vv, __uint_as_float(d.x << 16),          acc[0]);
  acc[1] = fmaf(vv, __uint_as_float(d.x & 0xffff0000u),  acc[1]);
  acc[2] = fmaf(vv, __uint_as_float(d.y << 16),          acc[2]);
  acc[3] = fmaf(vv, __uint_as_float(d.y & 0xffff0000u),  acc[3]);
  acc[4] = fmaf(vv, __uint_as_float(d.z << 16),          acc[4]);
  acc[5] = fmaf(vv, __uint_as_float(d.z & 0xffff0000u),  acc[5]);
  acc[6] = fmaf(vv, __uint_as_float(d.w << 16),          acc[6]);
  acc[7] = fmaf(vv, __uint_as_float(d.w & 0xffff0000u),  acc[7]);
}

__device__ __forceinline__ void unp8(float f[8], uint4 d){
  f[0] = __uint_as_float(d.x << 16); f[1] = __uint_as_float(d.x & 0xffff0000u);
  f[2] = __uint_as_float(d.y << 16); f[3] = __uint_as_float(d.y & 0xffff0000u);
  f[4] = __uint_as_float(d.z << 16); f[5] = __uint_as_float(d.z & 0xffff0000u);
  f[6] = __uint_as_float(d.w << 16); f[7] = __uint_as_float(d.w & 0xffff0000u);
}

__device__ __forceinline__ uint4 pack8(const float f[8]){
  uint4 d;
  d.x = (unsigned)bbits(f[0]) | ((unsigned)bbits(f[1]) << 16);
  d.y = (unsigned)bbits(f[2]) | ((unsigned)bbits(f[3]) << 16);
  d.z = (unsigned)bbits(f[4]) | ((unsigned)bbits(f[5]) << 16);
  d.w = (unsigned)bbits(f[6]) | ((unsigned)bbits(f[7]) << 16);
  return d;
}

// XCD-aware swizzle for 9600-block graph kernels
__device__ __forceinline__ void bv_swz(int bid, int& b, int& v){
  int xcd = bid & 7, i = bid >> 3;
  int nb = xcd*1200 + i;
  b = nb / NNODE; v = nb - b*NNODE;
}

// ---------------- graph construction ----------------
__global__ void k_nodes(const float* __restrict__ emb1, const float* __restrict__ emb2,
                        const float* __restrict__ l1w, const float* __restrict__ l1b,
                        const float* __restrict__ l2w, const float* __restrict__ l2b,
                        const int* __restrict__ idxp,
                        float* __restrict__ n1, float* __restrict__ n2){
  int i = blockIdx.x; int d = threadIdx.x;
  if (d >= NDIM) return;
  int r = idxp[i];
  float a1 = l1b[d], a2 = l2b[d];
  for (int k=0;k<NDIM;++k){
    a1 = fmaf(emb1[r*NDIM+k], l1w[d*NDIM+k], a1);
    a2 = fmaf(emb2[r*NDIM+k], l2w[d*NDIM+k], a2);
  }
  n1[i*NDIM+d] = tanhf(3.0f*a1);
  n2[i*NDIM+d] = tanhf(3.0f*a2);
}

__global__ void __launch_bounds__(64) k_adjrow(const float* __restrict__ n1,
                                               const float* __restrict__ n2,
                                               float* __restrict__ Am){
  int i = blockIdx.x; int lane = threadIdx.x;
  __shared__ float rowo[NNODE];
  __shared__ float rowv[NNODE];
  __shared__ int   sel[NNODE];
  for (int j=lane;j<NNODE;j+=64){
    float a = 0.f;
    #pragma unroll
    for (int k=0;k<NDIM;++k){
      float a1 = n1[i*NDIM+k], a2 = n2[i*NDIM+k];
      a = fmaf(a1, n2[j*NDIM+k], a);
      a = fmaf(-a2, n1[j*NDIM+k], a);
    }
    float v = tanhf(3.0f*a);
    v = v > 0.f ? v : 0.f;
    rowo[j]=v; rowv[j]=v; sel[j]=0;
  }
  __syncthreads();
  for (int it=0; it<KTOP; ++it){
    float best = -1.f; int bi = 0x7fffffff;
    for (int j=lane;j<NNODE;j+=64){
      float v = rowv[j];
      if (v > best){ best=v; bi=j; }
    }
    #pragma unroll
    for (int off=32; off; off>>=1){
      float ov = __shfl_xor(best, off);
      int   oi = __shfl_xor(bi, off);
      if (ov > best || (ov == best && oi < bi)){ best=ov; bi=oi; }
    }
    if (lane==0){ sel[bi]=1; rowv[bi]=-2.f; }
    __syncthreads();
  }
  for (int j=lane;j<NNODE;j+=64)
    Am[i*NNODE+j] = sel[j] ? rowo[j] : 0.f;
}

__global__ void __launch_bounds__(64) k_csr(const float* __restrict__ Am,
                                            int* __restrict__ aidx, float* __restrict__ aval,
                                            int* __restrict__ acnt){
  int r = blockIdx.x; int lane = threadIdx.x;
  int v = (r < NNODE) ? r : r - NNODE;
  int*   ip = aidx + r*304;
  float* vp = aval + r*304;
  if (lane==0){ ip[0]=v; vp[0]=1.0f; }
  int cnt = 1; float s = 1.0f;
  for (int base=0; base<NNODE; base+=64){
    int j = base + lane; float val = 0.f; bool p = false;
    if (j < NNODE){
      val = (r < NNODE) ? Am[v*NNODE + j] : Am[j*NNODE + v];
      p = val > 0.f;
    }
    unsigned long long m = __ballot(p);
    int pre = __popcll(m & ((1ull << lane) - 1ull));
    if (p){ ip[cnt+pre]=j; vp[cnt+pre]=val; }
    cnt += __popcll(m);
    float vs = p ? val : 0.f;
    #pragma unroll
    for (int off=32; off; off>>=1) vs += __shfl_xor(vs, off);
    s += vs;
  }
  for (int e=lane; e<cnt; e+=64) vp[e] = vp[e] / s;
  if (lane==0) acnt[r]=cnt;
}

// ---------------- inception weight fragment packing for MFMA ----------------
__global__ void k_wpack2(const float* __restrict__ fw2,const float* __restrict__ fw3,
                         const float* __restrict__ fw6,const float* __restrict__ fw7,
                         const float* __restrict__ gw2,const float* __restrict__ gw3,
                         const float* __restrict__ gw6,const float* __restrict__ gw7,
                         const float* __restrict__ fb2,const float* __restrict__ fb3,
                         const float* __restrict__ fb6,const float* __restrict__ fb7,
                         const float* __restrict__ gb2,const float* __restrict__ gb3,
                         const float* __restrict__ gb6,const float* __restrict__ gb7,
                         bf16* __restrict__ wfA, float* __restrict__ biasPk){
  int T = blockIdx.x*blockDim.x + threadIdx.x;
  if (T < 14336){
    int j = T & 7;
    int q = T >> 3;
    int l = q & 63; q >>= 6;
    int ks = q % 7, mt = q / 7;
    int m = mt*16 + (l & 15);
    int k = ks*32 + (l >> 4)*8 + j;
    int c = m >> 1, path = m & 1;
    int cls = c >> 3, o = c & 7;
    int ic = k / 7, d = k - ic*7;
    int kk = (cls==0) ? 2 : (cls==1) ? 3 : (cls==2) ? 6 : 7;
    int tp = d - (7 - kk);
    float val = 0.f;
    if (tp >= 0){
      const float* w = (path==0)
        ? (cls==0?fw2:cls==1?fw3:cls==2?fw6:fw7)
        : (cls==0?gw2:cls==1?gw3:cls==2?gw6:gw7);
      val = w[(o*NC + ic)*kk + tp];
    }
    wfA[T] = f2b(val);
  } else if (T < 14336 + 32){
    int c = T - 14336;
    int cls = c >> 3, o = c & 7;
    const float* fb = cls==0?fb2:cls==1?fb3:cls==2?fb6:fb7;
    const float* gb = cls==0?gb2:cls==1?gb3:cls==2?gb6:gb7;
    biasPk[c*2]   = fb[o];
    biasPk[c*2+1] = gb[o];
  }
}

// ---------------- mix conv weights packed as MFMA B-fragments ----------------
// pkB0[((nt*3+ks)*64 + l)*8 + j] = W0[c=nt*16+(l&15)][k=ks*32+(l>>4)*8+j]
//   W0[c][k] = m1w[c*96+k] + (k<32 ? m2w[c*96+k] : 0)
// pkB1[((nt*2+ks)*64 + l)*8 + j] = W1[c][k] = m2w[c*96+32+k]  (k<64)
// biasSum[c] = m1b[c]+m2b[c]
__global__ void k_wprepM(const float* __restrict__ m1w, const float* __restrict__ m2w,
                         const float* __restrict__ m1b, const float* __restrict__ m2b,
                         bf16* __restrict__ pkB0, bf16* __restrict__ pkB1,
                         float* __restrict__ biasSum){
  int id = blockIdx.x*blockDim.x + threadIdx.x;
  if (id < 3072){
    int j = id & 7, l = (id >> 3) & 63, q = id >> 9;   // q = nt*3+ks
    int ks = q % 3, nt = q / 3;
    int k = ks*32 + (l >> 4)*8 + j;
    int c = nt*16 + (l & 15);
    float val = m1w[c*96 + k] + (k < 32 ? m2w[c*96 + k] : 0.f);
    pkB0[id] = f2b(val);
  } else if (id < 5120){
    int id2 = id - 3072;
    int j = id2 & 7, l = (id2 >> 3) & 63, q = id2 >> 9; // q = nt*2+ks
    int ks = q & 1, nt = q >> 1;
    int k = ks*32 + (l >> 4)*8 + j;
    int c = nt*16 + (l & 15);
    pkB1[id2] = f2b(m2w[c*96 + 32 + k]);
  } else if (id < 5152){
    int c = id - 5120;
    biasSum[c] = m1b[c] + m2b[c];
  }
}

// ---------------- dilated inception via MFMA -> Xp[b][n][t][c] bf16 (pad zeroed) ----------------
__global__ void __launch_bounds__(256) k_incepM(const float* __restrict__ x,
    const bf16* __restrict__ wfA, const float* __restrict__ biasPk,
    bf16* __restrict__ Xp){
  __shared__ bf16 xsb[32*72];       // [ic][72] (t padded to 72, zeros in 64..71)
  __shared__ uint4 xim2[28*64];     // [kb][t] : 8 bf16 (k = kb*8+j)
  int b, n; bv_swz(blockIdx.x, b, n);
  int bn = b*NNODE + n;
  int tid = threadIdx.x;
  {
    int c = tid >> 3, t0 = (tid & 7)*8;
    const float* src = x + ((size_t)(b*NC + c)*NNODE + n)*NT + t0;
    float4 v0 = *reinterpret_cast<const float4*>(src);
    float4 v1 = *reinterpret_cast<const float4*>(src + 4);
    float f[8] = {v0.x,v0.y,v0.z,v0.w,v1.x,v1.y,v1.z,v1.w};
    *reinterpret_cast<uint4*>(&xsb[c*72 + t0]) = pack8(f);
    if ((tid & 7) == 7)
      *reinterpret_cast<uint4*>(&xsb[c*72 + 64]) = make_uint4(0,0,0,0);
  }
  __syncthreads();
  #pragma unroll
  for (int i=0;i<7;++i){
    int pr = tid + i*256;
    int kb = pr >> 6, t = pr & 63;
    int k0 = kb*8;
    int ic = k0 / 7, d = k0 - ic*7;
    unsigned sh[8];
    #pragma unroll
    for (int j=0;j<8;++j){
      sh[j] = *reinterpret_cast<const unsigned short*>(&xsb[ic*72 + t + d]);
      ++d; if (d == 7){ d = 0; ++ic; }
    }
    xim2[kb*64 + t] = make_uint4(sh[0]|(sh[1]<<16), sh[2]|(sh[3]<<16),
                                 sh[4]|(sh[5]<<16), sh[6]|(sh[7]<<16));
  }
  __syncthreads();
  int lane = tid & 63;
  int mt = __builtin_amdgcn_readfirstlane(tid >> 6);
  bf16x8 wA[7];
  #pragma unroll
  for (int ks=0; ks<7; ++ks)
    wA[ks] = *reinterpret_cast<const bf16x8*>(wfA + (size_t)((mt*7 + ks)*64 + lane)*8);
  int g = lane >> 4;
  int c0 = mt*8 + 2*g;
  float4 bias2 = *reinterpret_cast<const float4*>(biasPk + c0*2);
  #pragma unroll
  for (int nt=0; nt<4; ++nt){
    int t = (lane & 15) + nt*16;
    f32x4 acc = {0.f, 0.f, 0.f, 0.f};
    #pragma unroll
    for (int ks=0; ks<7; ++ks){
      bf16x8 bfr = __builtin_bit_cast(bf16x8, xim2[(ks*4 + g)*64 + t]);
      acc = __builtin_amdgcn_mfma_f32_16x16x32_bf16(wA[ks], bfr, acc, 0, 0, 0);
    }
    bool act = t < NTOUT;
    float X0 = act ? (ftanh(acc[0] + bias2.x) * fsig(acc[1] + bias2.y)) : 0.f;
    float X1 = act ? (ftanh(acc[2] + bias2.z) * fsig(acc[3] + bias2.w)) : 0.f;
    unsigned pv = (unsigned)bbits(X0) | ((unsigned)bbits(X1) << 16);
    *reinterpret_cast<unsigned*>(Xp + (size_t)bn*PSLAB + t*32 + c0) = pv;
  }
}

// ---------------- skip path ----------------
// wT[kk'][sc], kk' = t*32 + c (bijective onto 0..1855 for t<58)
__global__ void k_wT(const float* __restrict__ sw, float* __restrict__ wT){
  int id = blockIdx.x*blockDim.x + threadIdx.x;
  if (id >= 1856*64) return;
  int kk = id >> 6, sc = id & 63;
  int t = kk >> 5, c = kk & 31;
  wT[kk*64 + sc] = sw[sc*1856 + c*NTOUT + t];
}

__global__ void __launch_bounds__(256) k_skip(const bf16* __restrict__ Xp, const float* __restrict__ wT,
      const float* __restrict__ skip_b, const float* __restrict__ x_skip, float* __restrict__ out){
  __shared__ float Xs[8*1856];
  int tid = threadIdx.x;
  int bp0 = blockIdx.x*8;
  for (int i = tid; i < 8*232; i += 256){
    int p = i / 232, e = i - p*232;
    int gp = bp0 + p; int b = gp / NNODE, n = gp - b*NNODE;
    uint4 d = *reinterpret_cast<const uint4*>(Xp + (size_t)(b*NNODE+n)*PSLAB + e*8);
    float f[8]; unp8(f, d);
    *reinterpret_cast<float4*>(&Xs[p*1856 + e*8])     = make_float4(f[0],f[1],f[2],f[3]);
    *reinterpret_cast<float4*>(&Xs[p*1856 + e*8 + 4]) = make_float4(f[4],f[5],f[6],f[7]);
  }
  __syncthreads();
  int lane = tid & 63, w = tid >> 6;
  int kk0 = w*464;
  float acc[8] = {0,0,0,0,0,0,0,0};
  for (int kk = kk0; kk < kk0+464; kk += 4){
    float wv0 = wT[(kk+0)*64 + lane];
    float wv1 = wT[(kk+1)*64 + lane];
    float wv2 = wT[(kk+2)*64 + lane];
    float wv3 = wT[(kk+3)*64 + lane];
    #pragma unroll
    for (int p=0;p<8;++p){
      const float4 xv = *reinterpret_cast<const float4*>(&Xs[p*1856 + kk]);
      acc[p] = fmaf(xv.x, wv0, acc[p]);
      acc[p] = fmaf(xv.y, wv1, acc[p]);
      acc[p] = fmaf(xv.z, wv2, acc[p]);
      acc[p] = fmaf(xv.w, wv3, acc[p]);
    }
  }
  __syncthreads();
  float* red = Xs;
  #pragma unroll
  for (int p=0;p<8;++p) red[w*512 + p*64 + lane] = acc[p];
  __syncthreads();
  #pragma unroll
  for (int pi=0; pi<2; ++pi){
    int p = w*2 + pi;
    float s = red[p*64+lane] + red[512+p*64+lane] + red[1024+p*64+lane] + red[1536+p*64+lane];
    int gp = bp0 + p, b = gp / NNODE, n = gp - b*NNODE;
    size_t so = (size_t)b*NSKIP*NNODE + (size_t)lane*NNODE + n;
    out[(size_t)XEL + so] = s + skip_b[lane] + x_skip[so];
  }
}

// ---------------- hop1: HA = 0.05*Xp + 0.95*(Ah (x) Xp) ----------------
// thread -> (t = tid>>2, cb = tid&3): uint4 = 8 channels at fixed t; fully coalesced
__global__ void __launch_bounds__(256) k_prop(const bf16* __restrict__ Xp, bf16* __restrict__ HA,
    const int* __restrict__ aidx, const float* __restrict__ aval, const int* __restrict__ acnt,
    int rowoff){
  __shared__ int   sidx[304];
  __shared__ float sval[304];
  int b, v; bv_swz(blockIdx.x, b, v);
  int r = rowoff + v;
  int cnt = acnt[r];
  for (int e = threadIdx.x; e < cnt; e += 256){
    sidx[e] = aidx[r*304 + e] * PSLAB;
    sval[e] = aval[r*304 + e];
  }
  __syncthreads();
  int t = threadIdx.x >> 2, cb = threadIdx.x & 3;
  int off = t*32 + cb*8;
  const bf16* base = Xp + (size_t)b*BPSLAB + off;
  float acc[8] = {0,0,0,0,0,0,0,0};
  #pragma unroll 2
  for (int j=0;j<cnt;++j){
    uint4 d = *reinterpret_cast<const uint4*>(base + sidx[j]);
    fma8(acc, d, sval[j]);
  }
  size_t own = (size_t)b*BPSLAB + (size_t)v*PSLAB + off;
  uint4 dx = *reinterpret_cast<const uint4*>(Xp + own);
  float xf[8]; unp8(xf, dx);
  float h[8];
  #pragma unroll
  for (int k=0;k<8;++k) h[k] = fmaf(0.95f, acc[k], 0.05f*xf[k]);
  *reinterpret_cast<uint4*>(HA + own) = pack8(h);
}

// ---------------- hop2 + 1x1 mix conv (MFMA), fused ----------------
// phase A: gather -> h2T4 LDS [t][c] (channel-minor). phase B:
// C[m=t 64][n=c_out 32] = F[64 t][K] x W[K][32], K=96 (side0: X,HA,H2) / 64 (side1: HA,H2)
__global__ void __launch_bounds__(256) k_fuse(const bf16* __restrict__ Xp, const bf16* __restrict__ HA,
    float* __restrict__ out, const float* __restrict__ x,
    const int* __restrict__ aidx, const float* __restrict__ aval, const int* __restrict__ acnt,
    const bf16* __restrict__ pkB, const float* __restrict__ biasSum,
    int rowoff, int side){
  __shared__ int   sidx[304];
  __shared__ float sval[304];
  __shared__ uint4 h2T4[256];     // [t][cb]: 8 bf16
  int b, v; bv_swz(blockIdx.x, b, v);
  int r = rowoff + v;
  int cnt = acnt[r];
  for (int e = threadIdx.x; e < cnt; e += 256){
    sidx[e] = aidx[r*304 + e] * PSLAB;
    sval[e] = aval[r*304 + e];
  }
  __syncthreads();
  int tid = threadIdx.x;
  size_t bbase = (size_t)b*BPSLAB;
  size_t vbase = bbase + (size_t)v*PSLAB;
  // phase A: hop2 gather over HA
  {
    int t = tid >> 2, cb = tid & 3;
    int off = t*32 + cb*8;
    const bf16* base = HA + bbase + off;
    float acc[8] = {0,0,0,0,0,0,0,0};
    #pragma unroll 2
    for (int j=0;j<cnt;++j){
      uint4 d = *reinterpret_cast<const uint4*>(base + sidx[j]);
      fma8(acc, d, sval[j]);
    }
    uint4 dx = *reinterpret_cast<const uint4*>(Xp + vbase + off);
    float xf[8]; unp8(xf, dx);
    float h[8];
    #pragma unroll
    for (int k=0;k<8;++k) h[k] = fmaf(0.95f, acc[k], 0.05f*xf[k]);
    h2T4[t*4 + cb] = pack8(h);
  }
  __syncthreads();
  // phase B: MFMA 1x1 conv
  int lane = tid & 63;
  int mt = __builtin_amdgcn_readfirstlane(tid >> 6);
  int g = lane >> 4, col = lane & 15;
  int tRow = mt*16 + col;
  const bf16x8* h2p = reinterpret_cast<const bf16x8*>(h2T4);
  bf16x8 aF0, aF1, aF2;
  if (side == 0){
    aF0 = *reinterpret_cast<const bf16x8*>(Xp + vbase + tRow*32 + g*8);
    aF1 = *reinterpret_cast<const bf16x8*>(HA + vbase + tRow*32 + g*8);
    aF2 = h2p[tRow*4 + g];
  } else {
    aF0 = *reinterpret_cast<const bf16x8*>(HA + vbase + tRow*32 + g*8);
    aF1 = h2p[tRow*4 + g];
    aF2 = aF1;  // unused
  }
  int t0 = mt*16 + g*4;
  #pragma unroll
  for (int nt=0; nt<2; ++nt){
    int c_out = nt*16 + col;
    f32x4 acc;
    if (side == 0){
      float bv = biasSum[c_out];
      acc = (f32x4){bv, bv, bv, bv};
      bf16x8 w0 = *reinterpret_cast<const bf16x8*>(pkB + (size_t)((nt*3+0)*64 + lane)*8);
      bf16x8 w1 = *reinterpret_cast<const bf16x8*>(pkB + (size_t)((nt*3+1)*64 + lane)*8);
      bf16x8 w2 = *reinterpret_cast<const bf16x8*>(pkB + (size_t)((nt*3+2)*64 + lane)*8);
      acc = __builtin_amdgcn_mfma_f32_16x16x32_bf16(aF0, w0, acc, 0, 0, 0);
      acc = __builtin_amdgcn_mfma_f32_16x16x32_bf16(aF1, w1, acc, 0, 0, 0);
      acc = __builtin_amdgcn_mfma_f32_16x16x32_bf16(aF2, w2, acc, 0, 0, 0);
      float* po = out + ((size_t)(b*NC + c_out)*NNODE + v)*NTOUT + t0;
      if (t0 <= 54){
        *reinterpret_cast<float2*>(po)     = make_float2(acc[0], acc[1]);
        *reinterpret_cast<float2*>(po + 2) = make_float2(acc[2], acc[3]);
      } else if (t0 == 56){
        *reinterpret_cast<float2*>(po)     = make_float2(acc[0], acc[1]);
      }
    } else {
      acc = (f32x4){0.f, 0.f, 0.f, 0.f};
      bf16x8 w0 = *reinterpret_cast<const bf16x8*>(pkB + (size_t)((nt*2+0)*64 + lane)*8);
      bf16x8 w1 = *reinterpret_cast<const bf16x8*>(pkB + (size_t)((nt*2+1)*64 + lane)*8);
      acc = __builtin_amdgcn_mfma_f32_16x16x32_bf16(aF0, w0, acc, 0, 0, 0);
      acc = __builtin_amdgcn_mfma_f32_16x16x32_bf16(aF1, w1, acc, 0, 0, 0);
      float* po = out + ((size_t)(b*NC + c_out)*NNODE + v)*NTOUT + t0;
      const float* rx = x + ((size_t)(b*NC + c_out)*NNODE + v)*NT + 6 + t0;
      if (t0 <= 54){
        float2 o0 = *reinterpret_cast<const float2*>(po);
        float2 o1 = *reinterpret_cast<const float2*>(po + 2);
        float2 r0 = *reinterpret_cast<const float2*>(rx);
        float2 r1 = *reinterpret_cast<const float2*>(rx + 2);
        *reinterpret_cast<float2*>(po)     = make_float2(o0.x + acc[0] + r0.x, o0.y + acc[1] + r0.y);
        *reinterpret_cast<float2*>(po + 2) = make_float2(o1.x + acc[2] + r1.x, o1.y + acc[3] + r1.y);
      } else if (t0 == 56){
        float2 o0 = *reinterpret_cast<const float2*>(po);
        float2 r0 = *reinterpret_cast<const float2*>(rx);
        *reinterpret_cast<float2*>(po)     = make_float2(o0.x + acc[0] + r0.x, o0.y + acc[1] + r0.y);
      }
    }
  }
}

// ---------------- layernorm ----------------
__global__ void __launch_bounds__(256) k_lnstat(const float* __restrict__ out, double* __restrict__ part){
  int blk = blockIdx.x; int b = blk >> 3, seg = blk & 7;
  const float* p = out + (size_t)b*BSLAB;
  int start = seg*69600, end = start + 69600;
  double s = 0.0, s2 = 0.0;
  for (int i = start + threadIdx.x; i < end; i += 256){
    double v = (double)p[i]; s += v; s2 += v*v;
  }
  #pragma unroll
  for (int off=32; off; off>>=1){ s += __shfl_down(s, off); s2 += __shfl_down(s2, off); }
  __shared__ double ls[4], ls2[4];
  int lane = threadIdx.x & 63, w = threadIdx.x >> 6;
  if (lane==0){ ls[w]=s; ls2[w]=s2; }
  __syncthreads();
  if (threadIdx.x==0){
    double a=0.0, a2=0.0;
    for (int i=0;i<4;++i){ a+=ls[i]; a2+=ls2[i]; }
    part[blk*2]=a; part[blk*2+1]=a2;
  }
}

__global__ void k_lnfin(const double* __restrict__ part, float* __restrict__ stats){
  int b = threadIdx.x; if (b >= 32) return;
  double s=0.0, s2=0.0;
  for (int seg=0; seg<8; ++seg){ s += part[(b*8+seg)*2]; s2 += part[(b*8+seg)*2+1]; }
  double n = (double)BSLAB;
  double mean = s/n;
  double var = s2/n - mean*mean;
  stats[b*2]   = (float)mean;
  stats[b*2+1] = (float)(1.0/sqrt(var + 1e-5));
}

__global__ void __launch_bounds__(256) k_lnapply(float* __restrict__ out, const float* __restrict__ stats,
        const float* __restrict__ lnw, const float* __restrict__ lnb, const int* __restrict__ idxp){
  int o = blockIdx.x*256 + threadIdx.x;
  int t = o % NTOUT; int v = (o / NTOUT) % NNODE; int c = (o / SLAB) % NC; int b = o / BSLAB;
  float mean = stats[b*2], rstd = stats[b*2+1];
  int vn = idxp[v];
  float wv = lnw[((size_t)c*NNODE + vn)*NTOUT + t];
  float bv = lnb[((size_t)c*NNODE + vn)*NTOUT + t];
  float vx = out[o];
  out[o] = (vx - mean)*rstd*wv + bv;
}

extern "C" void kernel_launch(void* const* d_in, const int* in_sizes, int n_in,
                              void* d_out, int out_size, void* d_ws, size_t ws_size,
                              hipStream_t stream) {
  (void)in_sizes; (void)n_in; (void)out_size; (void)ws_size;
  const float* x     = (const float*)d_in[0];
  const float* xskip = (const float*)d_in[1];
  const int*   idxp  = (const int*)d_in[2];
  const float* emb1  = (const float*)d_in[3];
  const float* emb2  = (const float*)d_in[4];
  const float* l1w   = (const float*)d_in[5];
  const float* l1b   = (const float*)d_in[6];
  const float* l2w   = (const float*)d_in[7];
  const float* l2b   = (const float*)d_in[8];
  const float* skw   = (const float*)d_in[9];
  const float* skb   = (const float*)d_in[10];
  const float* m1w   = (const float*)d_in[11];
  const float* m1b   = (const float*)d_in[12];
  const float* m2w   = (const float*)d_in[13];
  const float* m2b   = (const float*)d_in[14];
  const float* lnw   = (const float*)d_in[15];
  const float* lnb   = (const float*)d_in[16];
  const float* fw2=(const float*)d_in[17]; const float* fb2=(const float*)d_in[18];
  const float* gw2=(const float*)d_in[19]; const float* gb2=(const float*)d_in[20];
  const float* fw3=(const float*)d_in[21]; const float* fb3=(const float*)d_in[22];
  const float* gw3=(const float*)d_in[23]; const float* gb3=(const float*)d_in[24];
  const float* fw6=(const float*)d_in[25]; const float* fb6=(const float*)d_in[26];
  const float* gw6=(const float*)d_in[27]; const float* gb6=(const float*)d_in[28];
  const float* fw7=(const float*)d_in[29]; const float* fb7=(const float*)d_in[30];
  const float* gw7=(const float*)d_in[31]; const float* gb7=(const float*)d_in[32];
  float* out = (float*)d_out;

  char* wsbase = (char*)d_ws;
  size_t cur = 0;
  auto alloc = [&](size_t bytes)->char*{
    char* p = wsbase + cur;
    cur = (cur + bytes + 255) & ~(size_t)255;
    return p;
  };
  bf16*  Xp   = (bf16*) alloc((size_t)XPEL*2);
  bf16*  HA   = (bf16*) alloc((size_t)XPEL*2);
  float* n1   = (float*)alloc(12000*4);
  float* n2   = (float*)alloc(12000*4);
  float* Am   = (float*)alloc(90000*4);
  int*   aidx = (int*)  alloc(600*304*4);
  float* aval = (float*)alloc(600*304*4);
  int*   acnt = (int*)  alloc(600*4);
  float* wT   = (float*)alloc(1856*64*4);
  bf16*  wfA  = (bf16*) alloc(14336*2);
  float* biasPk = (float*)alloc(64*4);
  bf16*  pkB0 = (bf16*) alloc(3072*2);
  bf16*  pkB1 = (bf16*) alloc(2048*2);
  float* biasSum = (float*)alloc(32*4);
  double* part = (double*)alloc(256*2*8);
  float* stats = (float*)alloc(64*4);

  // graph construction (tiny)
  k_nodes <<<NNODE, 64, 0, stream>>>(emb1, emb2, l1w, l1b, l2w, l2b, idxp, n1, n2);
  k_adjrow<<<NNODE, 64, 0, stream>>>(n1, n2, Am);
  k_csr   <<<2*NNODE, 64, 0, stream>>>(Am, aidx, aval, acnt);

  // weight prep
  k_wpack2<<<57, 256, 0, stream>>>(fw2,fw3,fw6,fw7, gw2,gw3,gw6,gw7,
                                   fb2,fb3,fb6,fb7, gb2,gb3,gb6,gb7, wfA, biasPk);
  k_wprepM<<<21, 256, 0, stream>>>(m1w, m2w, m1b, m2b, pkB0, pkB1, biasSum);
  k_wT    <<<464, 256, 0, stream>>>(skw, wT);

  // dilated inception -> Xp (MFMA, channel-minor layout)
  k_incepM<<<NB*NNODE, 256, 0, stream>>>(x, wfA, biasPk, Xp);

  // skip path
  k_skip<<<(NB*NNODE)/8, 256, 0, stream>>>(Xp, wT, skb, xskip, out);

  // mixprop side 0 (A)
  k_prop<<<NB*NNODE, 256, 0, stream>>>(Xp, HA, aidx, aval, acnt, 0);
  k_fuse<<<NB*NNODE, 256, 0, stream>>>(Xp, HA, out, x, aidx, aval, acnt, pkB0, biasSum, 0, 0);

  // mixprop side 1 (A^T)
  k_prop<<<NB*NNODE, 256, 0, stream>>>(Xp, HA, aidx, aval, acnt, NNODE);
  k_fuse<<<NB*NNODE, 256, 0, stream>>>(Xp, HA, out, x, aidx, aval, acnt, pkB1, biasSum, NNODE, 1);

  // layernorm
  k_lnstat<<<256, 256, 0, stream>>>(out, part);
  k_lnfin<<<1, 32, 0, stream>>>(part, stats);
  k_lnapply<<<XEL/256, 256, 0, stream>>>(out, stats, lnw, lnb, idxp);
}

// Round 8
// 454.550 us; speedup vs baseline: 3.1863x; 1.0772x over previous
//
#include <hip/hip_runtime.h>
#include <hip/hip_bf16.h>
#include <math.h>

typedef __hip_bfloat16 bf16;
typedef __attribute__((ext_vector_type(8))) short bf16x8;
typedef __attribute__((ext_vector_type(4))) float f32x4;

#define NB 32
#define NC 32
#define NNODE 300
#define NT 64
#define NDIM 40
#define KTOP 20
#define NSKIP 64
#define NTOUT 58
#define SLAB 17400        // NNODE*NTOUT (out layout)
#define BSLAB 556800      // NC*SLAB
#define XEL 17817600      // NB*BSLAB
#define PSLAB 2048        // 64 t x 32 c node slab (channel-minor)
#define BPSLAB 614400     // NNODE*PSLAB
#define XPEL 19660800     // NB*BPSLAB

__device__ __forceinline__ float b2f(bf16 v){ return __bfloat162float(v); }
__device__ __forceinline__ bf16 f2b(float v){ return __float2bfloat16(v); }
__device__ __forceinline__ float fsig(float x){ return 1.0f/(1.0f + __expf(-x)); }
__device__ __forceinline__ float ftanh(float x){ return 2.0f*fsig(2.0f*x) - 1.0f; }

__device__ __forceinline__ unsigned short bbits(float v){
  bf16 h = f2b(v); unsigned short s; __builtin_memcpy(&s, &h, 2); return s;
}

// 8 bf16 in a uint4: acc[k] += vv * e[k]
__device__ __forceinline__ void fma8(float acc[8], uint4 d, float vv){
  acc[0] = fmaf(vv, __uint_as_float(d.x << 16),          acc[0]);
  acc[1] = fmaf(vv, __uint_as_float(d.x & 0xffff0000u),  acc[1]);
  acc[2] = fmaf(vv, __uint_as_float(d.y << 16),          acc[2]);
  acc[3] = fmaf(vv, __uint_as_float(d.y & 0xffff0000u),  acc[3]);
  acc[4] = fmaf(vv, __uint_as_float(d.z << 16),          acc[4]);
  acc[5] = fmaf(vv, __uint_as_float(d.z & 0xffff0000u),  acc[5]);
  acc[6] = fmaf(vv, __uint_as_float(d.w << 16),          acc[6]);
  acc[7] = fmaf(vv, __uint_as_float(d.w & 0xffff0000u),  acc[7]);
}

__device__ __forceinline__ void unp8(float f[8], uint4 d){
  f[0] = __uint_as_float(d.x << 16); f[1] = __uint_as_float(d.x & 0xffff0000u);
  f[2] = __uint_as_float(d.y << 16); f[3] = __uint_as_float(d.y & 0xffff0000u);
  f[4] = __uint_as_float(d.z << 16); f[5] = __uint_as_float(d.z & 0xffff0000u);
  f[6] = __uint_as_float(d.w << 16); f[7] = __uint_as_float(d.w & 0xffff0000u);
}

__device__ __forceinline__ uint4 pack8(const float f[8]){
  uint4 d;
  d.x = (unsigned)bbits(f[0]) | ((unsigned)bbits(f[1]) << 16);
  d.y = (unsigned)bbits(f[2]) | ((unsigned)bbits(f[3]) << 16);
  d.z = (unsigned)bbits(f[4]) | ((unsigned)bbits(f[5]) << 16);
  d.w = (unsigned)bbits(f[6]) | ((unsigned)bbits(f[7]) << 16);
  return d;
}

// XCD-aware swizzle for 9600-block graph kernels
__device__ __forceinline__ void bv_swz(int bid, int& b, int& v){
  int xcd = bid & 7, i = bid >> 3;
  int nb = xcd*1200 + i;
  b = nb / NNODE; v = nb - b*NNODE;
}

// ---------------- graph construction ----------------
__global__ void k_nodes(const float* __restrict__ emb1, const float* __restrict__ emb2,
                        const float* __restrict__ l1w, const float* __restrict__ l1b,
                        const float* __restrict__ l2w, const float* __restrict__ l2b,
                        const int* __restrict__ idxp,
                        float* __restrict__ n1, float* __restrict__ n2){
  int i = blockIdx.x; int d = threadIdx.x;
  if (d >= NDIM) return;
  int r = idxp[i];
  float a1 = l1b[d], a2 = l2b[d];
  for (int k=0;k<NDIM;++k){
    a1 = fmaf(emb1[r*NDIM+k], l1w[d*NDIM+k], a1);
    a2 = fmaf(emb2[r*NDIM+k], l2w[d*NDIM+k], a2);
  }
  n1[i*NDIM+d] = tanhf(3.0f*a1);
  n2[i*NDIM+d] = tanhf(3.0f*a2);
}

__global__ void __launch_bounds__(64) k_adjrow(const float* __restrict__ n1,
                                               const float* __restrict__ n2,
                                               float* __restrict__ Am){
  int i = blockIdx.x; int lane = threadIdx.x;
  __shared__ float rowo[NNODE];
  __shared__ float rowv[NNODE];
  __shared__ int   sel[NNODE];
  for (int j=lane;j<NNODE;j+=64){
    float a = 0.f;
    #pragma unroll
    for (int k=0;k<NDIM;++k){
      float a1 = n1[i*NDIM+k], a2 = n2[i*NDIM+k];
      a = fmaf(a1, n2[j*NDIM+k], a);
      a = fmaf(-a2, n1[j*NDIM+k], a);
    }
    float v = tanhf(3.0f*a);
    v = v > 0.f ? v : 0.f;
    rowo[j]=v; rowv[j]=v; sel[j]=0;
  }
  __syncthreads();
  for (int it=0; it<KTOP; ++it){
    float best = -1.f; int bi = 0x7fffffff;
    for (int j=lane;j<NNODE;j+=64){
      float v = rowv[j];
      if (v > best){ best=v; bi=j; }
    }
    #pragma unroll
    for (int off=32; off; off>>=1){
      float ov = __shfl_xor(best, off);
      int   oi = __shfl_xor(bi, off);
      if (ov > best || (ov == best && oi < bi)){ best=ov; bi=oi; }
    }
    if (lane==0){ sel[bi]=1; rowv[bi]=-2.f; }
    __syncthreads();
  }
  for (int j=lane;j<NNODE;j+=64)
    Am[i*NNODE+j] = sel[j] ? rowo[j] : 0.f;
}

__global__ void __launch_bounds__(64) k_csr(const float* __restrict__ Am,
                                            int* __restrict__ aidx, float* __restrict__ aval,
                                            int* __restrict__ acnt){
  int r = blockIdx.x; int lane = threadIdx.x;
  int v = (r < NNODE) ? r : r - NNODE;
  int*   ip = aidx + r*304;
  float* vp = aval + r*304;
  if (lane==0){ ip[0]=v; vp[0]=1.0f; }
  int cnt = 1; float s = 1.0f;
  for (int base=0; base<NNODE; base+=64){
    int j = base + lane; float val = 0.f; bool p = false;
    if (j < NNODE){
      val = (r < NNODE) ? Am[v*NNODE + j] : Am[j*NNODE + v];
      p = val > 0.f;
    }
    unsigned long long m = __ballot(p);
    int pre = __popcll(m & ((1ull << lane) - 1ull));
    if (p){ ip[cnt+pre]=j; vp[cnt+pre]=val; }
    cnt += __popcll(m);
    float vs = p ? val : 0.f;
    #pragma unroll
    for (int off=32; off; off>>=1) vs += __shfl_xor(vs, off);
    s += vs;
  }
  for (int e=lane; e<cnt; e+=64) vp[e] = vp[e] / s;
  if (lane==0) acnt[r]=cnt;
}

// ---------------- inception weight fragment packing for MFMA ----------------
__global__ void k_wpack2(const float* __restrict__ fw2,const float* __restrict__ fw3,
                         const float* __restrict__ fw6,const float* __restrict__ fw7,
                         const float* __restrict__ gw2,const float* __restrict__ gw3,
                         const float* __restrict__ gw6,const float* __restrict__ gw7,
                         const float* __restrict__ fb2,const float* __restrict__ fb3,
                         const float* __restrict__ fb6,const float* __restrict__ fb7,
                         const float* __restrict__ gb2,const float* __restrict__ gb3,
                         const float* __restrict__ gb6,const float* __restrict__ gb7,
                         bf16* __restrict__ wfA, float* __restrict__ biasPk){
  int T = blockIdx.x*blockDim.x + threadIdx.x;
  if (T < 14336){
    int j = T & 7;
    int q = T >> 3;
    int l = q & 63; q >>= 6;
    int ks = q % 7, mt = q / 7;
    int m = mt*16 + (l & 15);
    int k = ks*32 + (l >> 4)*8 + j;
    int c = m >> 1, path = m & 1;
    int cls = c >> 3, o = c & 7;
    int ic = k / 7, d = k - ic*7;
    int kk = (cls==0) ? 2 : (cls==1) ? 3 : (cls==2) ? 6 : 7;
    int tp = d - (7 - kk);
    float val = 0.f;
    if (tp >= 0){
      const float* w = (path==0)
        ? (cls==0?fw2:cls==1?fw3:cls==2?fw6:fw7)
        : (cls==0?gw2:cls==1?gw3:cls==2?gw6:gw7);
      val = w[(o*NC + ic)*kk + tp];
    }
    wfA[T] = f2b(val);
  } else if (T < 14336 + 32){
    int c = T - 14336;
    int cls = c >> 3, o = c & 7;
    const float* fb = cls==0?fb2:cls==1?fb3:cls==2?fb6:fb7;
    const float* gb = cls==0?gb2:cls==1?gb3:cls==2?gb6:gb7;
    biasPk[c*2]   = fb[o];
    biasPk[c*2+1] = gb[o];
  }
}

// ---------------- mix conv weights packed as MFMA B-fragments ----------------
__global__ void k_wprepM(const float* __restrict__ m1w, const float* __restrict__ m2w,
                         const float* __restrict__ m1b, const float* __restrict__ m2b,
                         bf16* __restrict__ pkB0, bf16* __restrict__ pkB1,
                         float* __restrict__ biasSum){
  int id = blockIdx.x*blockDim.x + threadIdx.x;
  if (id < 3072){
    int j = id & 7, l = (id >> 3) & 63, q = id >> 9;   // q = nt*3+ks
    int ks = q % 3, nt = q / 3;
    int k = ks*32 + (l >> 4)*8 + j;
    int c = nt*16 + (l & 15);
    float val = m1w[c*96 + k] + (k < 32 ? m2w[c*96 + k] : 0.f);
    pkB0[id] = f2b(val);
  } else if (id < 5120){
    int id2 = id - 3072;
    int j = id2 & 7, l = (id2 >> 3) & 63, q = id2 >> 9; // q = nt*2+ks
    int ks = q & 1, nt = q >> 1;
    int k = ks*32 + (l >> 4)*8 + j;
    int c = nt*16 + (l & 15);
    pkB1[id2] = f2b(m2w[c*96 + 32 + k]);
  } else if (id < 5152){
    int c = id - 5120;
    biasSum[c] = m1b[c] + m2b[c];
  }
}

// ---------------- skip weights packed as MFMA B-fragments ----------------
// wTb[((nt*64 + ks)*64 + l)*8 + j] = W[k = ks*32+(l>>4)*8+j][sc = nt*16+(l&15)]
// where k = t*32 + c (Xp channel-minor order); zero for t >= 58
__global__ void k_wTb(const float* __restrict__ sw, bf16* __restrict__ wTb){
  int id = blockIdx.x*blockDim.x + threadIdx.x;
  if (id >= 131072) return;
  int j = id & 7, l = (id >> 3) & 63, q = id >> 9;  // q = nt*64 + ks
  int ks = q & 63, nt = q >> 6;
  int k = ks*32 + (l >> 4)*8 + j;
  int t = k >> 5, c = k & 31;
  int sc = nt*16 + (l & 15);
  float val = (t < NTOUT) ? sw[sc*1856 + c*NTOUT + t] : 0.f;
  wTb[id] = f2b(val);
}

// ---------------- dilated inception via MFMA -> Xp[b][n][t][c] bf16 (pad zeroed) ----------------
__global__ void __launch_bounds__(256) k_incepM(const float* __restrict__ x,
    const bf16* __restrict__ wfA, const float* __restrict__ biasPk,
    bf16* __restrict__ Xp){
  __shared__ bf16 xsb[32*72];       // [ic][72] (t padded to 72, zeros in 64..71)
  __shared__ uint4 xim2[28*64];     // [kb][t] : 8 bf16 (k = kb*8+j)
  int b, n; bv_swz(blockIdx.x, b, n);
  int bn = b*NNODE + n;
  int tid = threadIdx.x;
  {
    int c = tid >> 3, t0 = (tid & 7)*8;
    const float* src = x + ((size_t)(b*NC + c)*NNODE + n)*NT + t0;
    float4 v0 = *reinterpret_cast<const float4*>(src);
    float4 v1 = *reinterpret_cast<const float4*>(src + 4);
    float f[8] = {v0.x,v0.y,v0.z,v0.w,v1.x,v1.y,v1.z,v1.w};
    *reinterpret_cast<uint4*>(&xsb[c*72 + t0]) = pack8(f);
    if ((tid & 7) == 7)
      *reinterpret_cast<uint4*>(&xsb[c*72 + 64]) = make_uint4(0,0,0,0);
  }
  __syncthreads();
  #pragma unroll
  for (int i=0;i<7;++i){
    int pr = tid + i*256;
    int kb = pr >> 6, t = pr & 63;
    int k0 = kb*8;
    int ic = k0 / 7, d = k0 - ic*7;
    unsigned sh[8];
    #pragma unroll
    for (int j=0;j<8;++j){
      sh[j] = *reinterpret_cast<const unsigned short*>(&xsb[ic*72 + t + d]);
      ++d; if (d == 7){ d = 0; ++ic; }
    }
    xim2[kb*64 + t] = make_uint4(sh[0]|(sh[1]<<16), sh[2]|(sh[3]<<16),
                                 sh[4]|(sh[5]<<16), sh[6]|(sh[7]<<16));
  }
  __syncthreads();
  int lane = tid & 63;
  int mt = __builtin_amdgcn_readfirstlane(tid >> 6);
  bf16x8 wA[7];
  #pragma unroll
  for (int ks=0; ks<7; ++ks)
    wA[ks] = *reinterpret_cast<const bf16x8*>(wfA + (size_t)((mt*7 + ks)*64 + lane)*8);
  int g = lane >> 4;
  int c0 = mt*8 + 2*g;
  float4 bias2 = *reinterpret_cast<const float4*>(biasPk + c0*2);
  #pragma unroll
  for (int nt=0; nt<4; ++nt){
    int t = (lane & 15) + nt*16;
    f32x4 acc = {0.f, 0.f, 0.f, 0.f};
    #pragma unroll
    for (int ks=0; ks<7; ++ks){
      bf16x8 bfr = __builtin_bit_cast(bf16x8, xim2[(ks*4 + g)*64 + t]);
      acc = __builtin_amdgcn_mfma_f32_16x16x32_bf16(wA[ks], bfr, acc, 0, 0, 0);
    }
    bool act = t < NTOUT;
    float X0 = act ? (ftanh(acc[0] + bias2.x) * fsig(acc[1] + bias2.y)) : 0.f;
    float X1 = act ? (ftanh(acc[2] + bias2.z) * fsig(acc[3] + bias2.w)) : 0.f;
    unsigned pv = (unsigned)bbits(X0) | ((unsigned)bbits(X1) << 16);
    *reinterpret_cast<unsigned*>(Xp + (size_t)bn*PSLAB + t*32 + c0) = pv;
  }
}

// ---------------- skip path via MFMA ----------------
// C[m=bn rows 16][n=sc 64] = Xp[16 rows][K=2048] x wTb[K][64]; block = 16 rows, wave = sc-tile
__global__ void __launch_bounds__(256) k_skipM(const bf16* __restrict__ Xp, const bf16* __restrict__ wTb,
      const float* __restrict__ skip_b, const float* __restrict__ x_skip, float* __restrict__ out){
  int bn0 = blockIdx.x * 16;
  int tid = threadIdx.x, lane = tid & 63;
  int nt = __builtin_amdgcn_readfirstlane(tid >> 6);
  int g = lane >> 4, col = lane & 15;
  const bf16* aptr = Xp + (size_t)(bn0 + col)*PSLAB + g*8;
  const bf16* bptr = wTb + ((size_t)nt*64*64 + lane)*8;
  f32x4 acc = {0.f, 0.f, 0.f, 0.f};
  #pragma unroll 4
  for (int ks=0; ks<64; ++ks){
    bf16x8 aF = *reinterpret_cast<const bf16x8*>(aptr + ks*32);
    bf16x8 bF = *reinterpret_cast<const bf16x8*>(bptr + (size_t)ks*512);
    acc = __builtin_amdgcn_mfma_f32_16x16x32_bf16(aF, bF, acc, 0, 0, 0);
  }
  int sc = nt*16 + col;
  float sb = skip_b[sc];
  #pragma unroll
  for (int r=0;r<4;++r){
    int bn = bn0 + g*4 + r;
    int b = bn / NNODE, n = bn - b*NNODE;
    size_t so = (size_t)b*NSKIP*NNODE + (size_t)sc*NNODE + n;
    out[(size_t)XEL + so] = acc[r] + sb + x_skip[so];
  }
}

// ---------------- hop1: HA = 0.05*Xp + 0.95*(Ah (x) Xp) ----------------
__global__ void __launch_bounds__(256) k_prop(const bf16* __restrict__ Xp, bf16* __restrict__ HA,
    const int* __restrict__ aidx, const float* __restrict__ aval, const int* __restrict__ acnt,
    int rowoff){
  __shared__ int   sidx[304];
  __shared__ float sval[304];
  int b, v; bv_swz(blockIdx.x, b, v);
  int r = rowoff + v;
  int cnt = acnt[r];
  for (int e = threadIdx.x; e < cnt; e += 256){
    sidx[e] = aidx[r*304 + e] * PSLAB;
    sval[e] = aval[r*304 + e];
  }
  __syncthreads();
  int t = threadIdx.x >> 2, cb = threadIdx.x & 3;
  int off = t*32 + cb*8;
  const bf16* base = Xp + (size_t)b*BPSLAB + off;
  float acc[8] = {0,0,0,0,0,0,0,0};
  #pragma unroll 2
  for (int j=0;j<cnt;++j){
    uint4 d = *reinterpret_cast<const uint4*>(base + sidx[j]);
    fma8(acc, d, sval[j]);
  }
  size_t own = (size_t)b*BPSLAB + (size_t)v*PSLAB + off;
  uint4 dx = *reinterpret_cast<const uint4*>(Xp + own);
  float xf[8]; unp8(xf, dx);
  float h[8];
  #pragma unroll
  for (int k=0;k<8;++k) h[k] = fmaf(0.95f, acc[k], 0.05f*xf[k]);
  *reinterpret_cast<uint4*>(HA + own) = pack8(h);
}

// ---------------- hop2 + 1x1 mix conv (MFMA), fused ----------------
__global__ void __launch_bounds__(256) k_fuse(const bf16* __restrict__ Xp, const bf16* __restrict__ HA,
    float* __restrict__ out, const float* __restrict__ x,
    const int* __restrict__ aidx, const float* __restrict__ aval, const int* __restrict__ acnt,
    const bf16* __restrict__ pkB, const float* __restrict__ biasSum,
    int rowoff, int side){
  __shared__ int   sidx[304];
  __shared__ float sval[304];
  __shared__ uint4 h2T4[256];     // [t][cb]: 8 bf16
  int b, v; bv_swz(blockIdx.x, b, v);
  int r = rowoff + v;
  int cnt = acnt[r];
  for (int e = threadIdx.x; e < cnt; e += 256){
    sidx[e] = aidx[r*304 + e] * PSLAB;
    sval[e] = aval[r*304 + e];
  }
  __syncthreads();
  int tid = threadIdx.x;
  size_t bbase = (size_t)b*BPSLAB;
  size_t vbase = bbase + (size_t)v*PSLAB;
  // phase A: hop2 gather over HA
  {
    int t = tid >> 2, cb = tid & 3;
    int off = t*32 + cb*8;
    const bf16* base = HA + bbase + off;
    float acc[8] = {0,0,0,0,0,0,0,0};
    #pragma unroll 2
    for (int j=0;j<cnt;++j){
      uint4 d = *reinterpret_cast<const uint4*>(base + sidx[j]);
      fma8(acc, d, sval[j]);
    }
    uint4 dx = *reinterpret_cast<const uint4*>(Xp + vbase + off);
    float xf[8]; unp8(xf, dx);
    float h[8];
    #pragma unroll
    for (int k=0;k<8;++k) h[k] = fmaf(0.95f, acc[k], 0.05f*xf[k]);
    h2T4[t*4 + cb] = pack8(h);
  }
  __syncthreads();
  // phase B: MFMA 1x1 conv
  int lane = tid & 63;
  int mt = __builtin_amdgcn_readfirstlane(tid >> 6);
  int g = lane >> 4, col = lane & 15;
  int tRow = mt*16 + col;
  const bf16x8* h2p = reinterpret_cast<const bf16x8*>(h2T4);
  bf16x8 aF0, aF1, aF2;
  if (side == 0){
    aF0 = *reinterpret_cast<const bf16x8*>(Xp + vbase + tRow*32 + g*8);
    aF1 = *reinterpret_cast<const bf16x8*>(HA + vbase + tRow*32 + g*8);
    aF2 = h2p[tRow*4 + g];
  } else {
    aF0 = *reinterpret_cast<const bf16x8*>(HA + vbase + tRow*32 + g*8);
    aF1 = h2p[tRow*4 + g];
    aF2 = aF1;  // unused
  }
  int t0 = mt*16 + g*4;
  #pragma unroll
  for (int nt=0; nt<2; ++nt){
    int c_out = nt*16 + col;
    f32x4 acc;
    if (side == 0){
      float bv = biasSum[c_out];
      acc = (f32x4){bv, bv, bv, bv};
      bf16x8 w0 = *reinterpret_cast<const bf16x8*>(pkB + (size_t)((nt*3+0)*64 + lane)*8);
      bf16x8 w1 = *reinterpret_cast<const bf16x8*>(pkB + (size_t)((nt*3+1)*64 + lane)*8);
      bf16x8 w2 = *reinterpret_cast<const bf16x8*>(pkB + (size_t)((nt*3+2)*64 + lane)*8);
      acc = __builtin_amdgcn_mfma_f32_16x16x32_bf16(aF0, w0, acc, 0, 0, 0);
      acc = __builtin_amdgcn_mfma_f32_16x16x32_bf16(aF1, w1, acc, 0, 0, 0);
      acc = __builtin_amdgcn_mfma_f32_16x16x32_bf16(aF2, w2, acc, 0, 0, 0);
      float* po = out + ((size_t)(b*NC + c_out)*NNODE + v)*NTOUT + t0;
      if (t0 <= 54){
        *reinterpret_cast<float2*>(po)     = make_float2(acc[0], acc[1]);
        *reinterpret_cast<float2*>(po + 2) = make_float2(acc[2], acc[3]);
      } else if (t0 == 56){
        *reinterpret_cast<float2*>(po)     = make_float2(acc[0], acc[1]);
      }
    } else {
      acc = (f32x4){0.f, 0.f, 0.f, 0.f};
      bf16x8 w0 = *reinterpret_cast<const bf16x8*>(pkB + (size_t)((nt*2+0)*64 + lane)*8);
      bf16x8 w1 = *reinterpret_cast<const bf16x8*>(pkB + (size_t)((nt*2+1)*64 + lane)*8);
      acc = __builtin_amdgcn_mfma_f32_16x16x32_bf16(aF0, w0, acc, 0, 0, 0);
      acc = __builtin_amdgcn_mfma_f32_16x16x32_bf16(aF1, w1, acc, 0, 0, 0);
      float* po = out + ((size_t)(b*NC + c_out)*NNODE + v)*NTOUT + t0;
      const float* rx = x + ((size_t)(b*NC + c_out)*NNODE + v)*NT + 6 + t0;
      if (t0 <= 54){
        float2 o0 = *reinterpret_cast<const float2*>(po);
        float2 o1 = *reinterpret_cast<const float2*>(po + 2);
        float2 r0 = *reinterpret_cast<const float2*>(rx);
        float2 r1 = *reinterpret_cast<const float2*>(rx + 2);
        *reinterpret_cast<float2*>(po)     = make_float2(o0.x + acc[0] + r0.x, o0.y + acc[1] + r0.y);
        *reinterpret_cast<float2*>(po + 2) = make_float2(o1.x + acc[2] + r1.x, o1.y + acc[3] + r1.y);
      } else if (t0 == 56){
        float2 o0 = *reinterpret_cast<const float2*>(po);
        float2 r0 = *reinterpret_cast<const float2*>(rx);
        *reinterpret_cast<float2*>(po)     = make_float2(o0.x + acc[0] + r0.x, o0.y + acc[1] + r0.y);
      }
    }
  }
}

// ---------------- layernorm ----------------
__global__ void __launch_bounds__(256) k_lnstat(const float* __restrict__ out, double* __restrict__ part){
  int blk = blockIdx.x; int b = blk >> 3, seg = blk & 7;
  const float* p = out + (size_t)b*BSLAB;
  int start = seg*69600, end = start + 69600;
  double s = 0.0, s2 = 0.0;
  for (int i = start + threadIdx.x; i < end; i += 256){
    double v = (double)p[i]; s += v; s2 += v*v;
  }
  #pragma unroll
  for (int off=32; off; off>>=1){ s += __shfl_down(s, off); s2 += __shfl_down(s2, off); }
  __shared__ double ls[4], ls2[4];
  int lane = threadIdx.x & 63, w = threadIdx.x >> 6;
  if (lane==0){ ls[w]=s; ls2[w]=s2; }
  __syncthreads();
  if (threadIdx.x==0){
    double a=0.0, a2=0.0;
    for (int i=0;i<4;++i){ a+=ls[i]; a2+=ls2[i]; }
    part[blk*2]=a; part[blk*2+1]=a2;
  }
}

__global__ void k_lnfin(const double* __restrict__ part, float* __restrict__ stats){
  int b = threadIdx.x; if (b >= 32) return;
  double s=0.0, s2=0.0;
  for (int seg=0; seg<8; ++seg){ s += part[(b*8+seg)*2]; s2 += part[(b*8+seg)*2+1]; }
  double n = (double)BSLAB;
  double mean = s/n;
  double var = s2/n - mean*mean;
  stats[b*2]   = (float)mean;
  stats[b*2+1] = (float)(1.0/sqrt(var + 1e-5));
}

__global__ void __launch_bounds__(256) k_lnapply(float* __restrict__ out, const float* __restrict__ stats,
        const float* __restrict__ lnw, const float* __restrict__ lnb, const int* __restrict__ idxp){
  int o = blockIdx.x*256 + threadIdx.x;
  int t = o % NTOUT; int v = (o / NTOUT) % NNODE; int c = (o / SLAB) % NC; int b = o / BSLAB;
  float mean = stats[b*2], rstd = stats[b*2+1];
  int vn = idxp[v];
  float wv = lnw[((size_t)c*NNODE + vn)*NTOUT + t];
  float bv = lnb[((size_t)c*NNODE + vn)*NTOUT + t];
  float vx = out[o];
  out[o] = (vx - mean)*rstd*wv + bv;
}

extern "C" void kernel_launch(void* const* d_in, const int* in_sizes, int n_in,
                              void* d_out, int out_size, void* d_ws, size_t ws_size,
                              hipStream_t stream) {
  (void)in_sizes; (void)n_in; (void)out_size; (void)ws_size;
  const float* x     = (const float*)d_in[0];
  const float* xskip = (const float*)d_in[1];
  const int*   idxp  = (const int*)d_in[2];
  const float* emb1  = (const float*)d_in[3];
  const float* emb2  = (const float*)d_in[4];
  const float* l1w   = (const float*)d_in[5];
  const float* l1b   = (const float*)d_in[6];
  const float* l2w   = (const float*)d_in[7];
  const float* l2b   = (const float*)d_in[8];
  const float* skw   = (const float*)d_in[9];
  const float* skb   = (const float*)d_in[10];
  const float* m1w   = (const float*)d_in[11];
  const float* m1b   = (const float*)d_in[12];
  const float* m2w   = (const float*)d_in[13];
  const float* m2b   = (const float*)d_in[14];
  const float* lnw   = (const float*)d_in[15];
  const float* lnb   = (const float*)d_in[16];
  const float* fw2=(const float*)d_in[17]; const float* fb2=(const float*)d_in[18];
  const float* gw2=(const float*)d_in[19]; const float* gb2=(const float*)d_in[20];
  const float* fw3=(const float*)d_in[21]; const float* fb3=(const float*)d_in[22];
  const float* gw3=(const float*)d_in[23]; const float* gb3=(const float*)d_in[24];
  const float* fw6=(const float*)d_in[25]; const float* fb6=(const float*)d_in[26];
  const float* gw6=(const float*)d_in[27]; const float* gb6=(const float*)d_in[28];
  const float* fw7=(const float*)d_in[29]; const float* fb7=(const float*)d_in[30];
  const float* gw7=(const float*)d_in[31]; const float* gb7=(const float*)d_in[32];
  float* out = (float*)d_out;

  char* wsbase = (char*)d_ws;
  size_t cur = 0;
  auto alloc = [&](size_t bytes)->char*{
    char* p = wsbase + cur;
    cur = (cur + bytes + 255) & ~(size_t)255;
    return p;
  };
  bf16*  Xp   = (bf16*) alloc((size_t)XPEL*2);
  bf16*  HA   = (bf16*) alloc((size_t)XPEL*2);
  float* n1   = (float*)alloc(12000*4);
  float* n2   = (float*)alloc(12000*4);
  float* Am   = (float*)alloc(90000*4);
  int*   aidx = (int*)  alloc(600*304*4);
  float* aval = (float*)alloc(600*304*4);
  int*   acnt = (int*)  alloc(600*4);
  bf16*  wTb  = (bf16*) alloc(131072*2);
  bf16*  wfA  = (bf16*) alloc(14336*2);
  float* biasPk = (float*)alloc(64*4);
  bf16*  pkB0 = (bf16*) alloc(3072*2);
  bf16*  pkB1 = (bf16*) alloc(2048*2);
  float* biasSum = (float*)alloc(32*4);
  double* part = (double*)alloc(256*2*8);
  float* stats = (float*)alloc(64*4);

  // graph construction (tiny)
  k_nodes <<<NNODE, 64, 0, stream>>>(emb1, emb2, l1w, l1b, l2w, l2b, idxp, n1, n2);
  k_adjrow<<<NNODE, 64, 0, stream>>>(n1, n2, Am);
  k_csr   <<<2*NNODE, 64, 0, stream>>>(Am, aidx, aval, acnt);

  // weight prep
  k_wpack2<<<57, 256, 0, stream>>>(fw2,fw3,fw6,fw7, gw2,gw3,gw6,gw7,
                                   fb2,fb3,fb6,fb7, gb2,gb3,gb6,gb7, wfA, biasPk);
  k_wprepM<<<21, 256, 0, stream>>>(m1w, m2w, m1b, m2b, pkB0, pkB1, biasSum);
  k_wTb   <<<512, 256, 0, stream>>>(skw, wTb);

  // dilated inception -> Xp (MFMA, channel-minor layout)
  k_incepM<<<NB*NNODE, 256, 0, stream>>>(x, wfA, biasPk, Xp);

  // skip path (MFMA GEMM)
  k_skipM<<<(NB*NNODE)/16, 256, 0, stream>>>(Xp, wTb, skb, xskip, out);

  // mixprop side 0 (A)
  k_prop<<<NB*NNODE, 256, 0, stream>>>(Xp, HA, aidx, aval, acnt, 0);
  k_fuse<<<NB*NNODE, 256, 0, stream>>>(Xp, HA, out, x, aidx, aval, acnt, pkB0, biasSum, 0, 0);

  // mixprop side 1 (A^T)
  k_prop<<<NB*NNODE, 256, 0, stream>>>(Xp, HA, aidx, aval, acnt, NNODE);
  k_fuse<<<NB*NNODE, 256, 0, stream>>>(Xp, HA, out, x, aidx, aval, acnt, pkB1, biasSum, NNODE, 1);

  // layernorm
  k_lnstat<<<256, 256, 0, stream>>>(out, part);
  k_lnfin<<<1, 32, 0, stream>>>(part, stats);
  k_lnapply<<<XEL/256, 256, 0, stream>>>(out, stats, lnw, lnb, idxp);
}

// Round 9
// 448.669 us; speedup vs baseline: 3.2280x; 1.0131x over previous
//
#include <hip/hip_runtime.h>
#include <hip/hip_bf16.h>
#include <math.h>

typedef __hip_bfloat16 bf16;
typedef __attribute__((ext_vector_type(8))) short bf16x8;
typedef __attribute__((ext_vector_type(4))) float f32x4;

#define NB 32
#define NC 32
#define NNODE 300
#define NT 64
#define NDIM 40
#define KTOP 20
#define NSKIP 64
#define NTOUT 58
#define SLAB 17400        // NNODE*NTOUT (out layout)
#define BSLAB 556800      // NC*SLAB
#define XEL 17817600      // NB*BSLAB
#define PSLAB 2048        // 64 t x 32 c node slab (channel-minor)
#define BPSLAB 614400     // NNODE*PSLAB
#define XPEL 19660800     // NB*BPSLAB

__device__ __forceinline__ float b2f(bf16 v){ return __bfloat162float(v); }
__device__ __forceinline__ bf16 f2b(float v){ return __float2bfloat16(v); }
__device__ __forceinline__ float fsig(float x){ return 1.0f/(1.0f + __expf(-x)); }
__device__ __forceinline__ float ftanh(float x){ return 2.0f*fsig(2.0f*x) - 1.0f; }

__device__ __forceinline__ unsigned short bbits(float v){
  bf16 h = f2b(v); unsigned short s; __builtin_memcpy(&s, &h, 2); return s;
}

// 8 bf16 in a uint4: acc[k] += vv * e[k]
__device__ __forceinline__ void fma8(float acc[8], uint4 d, float vv){
  acc[0] = fmaf(vv, __uint_as_float(d.x << 16),          acc[0]);
  acc[1] = fmaf(vv, __uint_as_float(d.x & 0xffff0000u),  acc[1]);
  acc[2] = fmaf(vv, __uint_as_float(d.y << 16),          acc[2]);
  acc[3] = fmaf(vv, __uint_as_float(d.y & 0xffff0000u),  acc[3]);
  acc[4] = fmaf(vv, __uint_as_float(d.z << 16),          acc[4]);
  acc[5] = fmaf(vv, __uint_as_float(d.z & 0xffff0000u),  acc[5]);
  acc[6] = fmaf(vv, __uint_as_float(d.w << 16),          acc[6]);
  acc[7] = fmaf(vv, __uint_as_float(d.w & 0xffff0000u),  acc[7]);
}

__device__ __forceinline__ void unp8(float f[8], uint4 d){
  f[0] = __uint_as_float(d.x << 16); f[1] = __uint_as_float(d.x & 0xffff0000u);
  f[2] = __uint_as_float(d.y << 16); f[3] = __uint_as_float(d.y & 0xffff0000u);
  f[4] = __uint_as_float(d.z << 16); f[5] = __uint_as_float(d.z & 0xffff0000u);
  f[6] = __uint_as_float(d.w << 16); f[7] = __uint_as_float(d.w & 0xffff0000u);
}

__device__ __forceinline__ uint4 pack8(const float f[8]){
  uint4 d;
  d.x = (unsigned)bbits(f[0]) | ((unsigned)bbits(f[1]) << 16);
  d.y = (unsigned)bbits(f[2]) | ((unsigned)bbits(f[3]) << 16);
  d.z = (unsigned)bbits(f[4]) | ((unsigned)bbits(f[5]) << 16);
  d.w = (unsigned)bbits(f[6]) | ((unsigned)bbits(f[7]) << 16);
  return d;
}

// XCD-aware swizzle for 9600-block graph kernels
__device__ __forceinline__ void bv_swz(int bid, int& b, int& v){
  int xcd = bid & 7, i = bid >> 3;
  int nb = xcd*1200 + i;
  b = nb / NNODE; v = nb - b*NNODE;
}

// ---------------- graph construction ----------------
__global__ void k_nodes(const float* __restrict__ emb1, const float* __restrict__ emb2,
                        const float* __restrict__ l1w, const float* __restrict__ l1b,
                        const float* __restrict__ l2w, const float* __restrict__ l2b,
                        const int* __restrict__ idxp,
                        float* __restrict__ n1, float* __restrict__ n2){
  int i = blockIdx.x; int d = threadIdx.x;
  if (d >= NDIM) return;
  int r = idxp[i];
  float a1 = l1b[d], a2 = l2b[d];
  for (int k=0;k<NDIM;++k){
    a1 = fmaf(emb1[r*NDIM+k], l1w[d*NDIM+k], a1);
    a2 = fmaf(emb2[r*NDIM+k], l2w[d*NDIM+k], a2);
  }
  n1[i*NDIM+d] = tanhf(3.0f*a1);
  n2[i*NDIM+d] = tanhf(3.0f*a2);
}

__global__ void __launch_bounds__(64) k_adjrow(const float* __restrict__ n1,
                                               const float* __restrict__ n2,
                                               float* __restrict__ Am){
  int i = blockIdx.x; int lane = threadIdx.x;
  __shared__ float rowo[NNODE];
  __shared__ float rowv[NNODE];
  __shared__ int   sel[NNODE];
  for (int j=lane;j<NNODE;j+=64){
    float a = 0.f;
    #pragma unroll
    for (int k=0;k<NDIM;++k){
      float a1 = n1[i*NDIM+k], a2 = n2[i*NDIM+k];
      a = fmaf(a1, n2[j*NDIM+k], a);
      a = fmaf(-a2, n1[j*NDIM+k], a);
    }
    float v = tanhf(3.0f*a);
    v = v > 0.f ? v : 0.f;
    rowo[j]=v; rowv[j]=v; sel[j]=0;
  }
  __syncthreads();
  for (int it=0; it<KTOP; ++it){
    float best = -1.f; int bi = 0x7fffffff;
    for (int j=lane;j<NNODE;j+=64){
      float v = rowv[j];
      if (v > best){ best=v; bi=j; }
    }
    #pragma unroll
    for (int off=32; off; off>>=1){
      float ov = __shfl_xor(best, off);
      int   oi = __shfl_xor(bi, off);
      if (ov > best || (ov == best && oi < bi)){ best=ov; bi=oi; }
    }
    if (lane==0){ sel[bi]=1; rowv[bi]=-2.f; }
    __syncthreads();
  }
  for (int j=lane;j<NNODE;j+=64)
    Am[i*NNODE+j] = sel[j] ? rowo[j] : 0.f;
}

__global__ void __launch_bounds__(64) k_csr(const float* __restrict__ Am,
                                            int* __restrict__ aidx, float* __restrict__ aval,
                                            int* __restrict__ acnt){
  int r = blockIdx.x; int lane = threadIdx.x;
  int v = (r < NNODE) ? r : r - NNODE;
  int*   ip = aidx + r*304;
  float* vp = aval + r*304;
  if (lane==0){ ip[0]=v; vp[0]=1.0f; }
  int cnt = 1; float s = 1.0f;
  for (int base=0; base<NNODE; base+=64){
    int j = base + lane; float val = 0.f; bool p = false;
    if (j < NNODE){
      val = (r < NNODE) ? Am[v*NNODE + j] : Am[j*NNODE + v];
      p = val > 0.f;
    }
    unsigned long long m = __ballot(p);
    int pre = __popcll(m & ((1ull << lane) - 1ull));
    if (p){ ip[cnt+pre]=j; vp[cnt+pre]=val; }
    cnt += __popcll(m);
    float vs = p ? val : 0.f;
    #pragma unroll
    for (int off=32; off; off>>=1) vs += __shfl_xor(vs, off);
    s += vs;
  }
  for (int e=lane; e<cnt; e+=64) vp[e] = vp[e] / s;
  if (lane==0) acnt[r]=cnt;
}

// ---------------- inception weight fragment packing for MFMA ----------------
__global__ void k_wpack2(const float* __restrict__ fw2,const float* __restrict__ fw3,
                         const float* __restrict__ fw6,const float* __restrict__ fw7,
                         const float* __restrict__ gw2,const float* __restrict__ gw3,
                         const float* __restrict__ gw6,const float* __restrict__ gw7,
                         const float* __restrict__ fb2,const float* __restrict__ fb3,
                         const float* __restrict__ fb6,const float* __restrict__ fb7,
                         const float* __restrict__ gb2,const float* __restrict__ gb3,
                         const float* __restrict__ gb6,const float* __restrict__ gb7,
                         bf16* __restrict__ wfA, float* __restrict__ biasPk){
  int T = blockIdx.x*blockDim.x + threadIdx.x;
  if (T < 14336){
    int j = T & 7;
    int q = T >> 3;
    int l = q & 63; q >>= 6;
    int ks = q % 7, mt = q / 7;
    int m = mt*16 + (l & 15);
    int k = ks*32 + (l >> 4)*8 + j;
    int c = m >> 1, path = m & 1;
    int cls = c >> 3, o = c & 7;
    int ic = k / 7, d = k - ic*7;
    int kk = (cls==0) ? 2 : (cls==1) ? 3 : (cls==2) ? 6 : 7;
    int tp = d - (7 - kk);
    float val = 0.f;
    if (tp >= 0){
      const float* w = (path==0)
        ? (cls==0?fw2:cls==1?fw3:cls==2?fw6:fw7)
        : (cls==0?gw2:cls==1?gw3:cls==2?gw6:gw7);
      val = w[(o*NC + ic)*kk + tp];
    }
    wfA[T] = f2b(val);
  } else if (T < 14336 + 32){
    int c = T - 14336;
    int cls = c >> 3, o = c & 7;
    const float* fb = cls==0?fb2:cls==1?fb3:cls==2?fb6:fb7;
    const float* gb = cls==0?gb2:cls==1?gb3:cls==2?gb6:gb7;
    biasPk[c*2]   = fb[o];
    biasPk[c*2+1] = gb[o];
  }
}

// ---------------- mix conv weights: ONE combined B-fragment buffer, K=160 ----------------
// pkB[((nt*5 + ks)*64 + l)*8 + j]; c = nt*16+(l&15), k = (l>>4)*8+j (0..31)
// ks0: m1w[c,k]+m2w[c,k] (X) | ks1: m1w[c,32+k] (H1a) | ks2: m1w[c,64+k] (H2a)
// ks3: m2w[c,32+k] (H1b)     | ks4: m2w[c,64+k] (H2b)
// biasSum[c] = m1b[c]+m2b[c]
__global__ void k_wprepM(const float* __restrict__ m1w, const float* __restrict__ m2w,
                         const float* __restrict__ m1b, const float* __restrict__ m2b,
                         bf16* __restrict__ pkB, float* __restrict__ biasSum){
  int id = blockIdx.x*blockDim.x + threadIdx.x;
  if (id < 5120){
    int j = id & 7, l = (id >> 3) & 63, q = id >> 9;   // q = nt*5+ks
    int ks = q % 5, nt = q / 5;
    int k = (l >> 4)*8 + j;
    int c = nt*16 + (l & 15);
    float val;
    if      (ks == 0) val = m1w[c*96 + k] + m2w[c*96 + k];
    else if (ks == 1) val = m1w[c*96 + 32 + k];
    else if (ks == 2) val = m1w[c*96 + 64 + k];
    else if (ks == 3) val = m2w[c*96 + 32 + k];
    else              val = m2w[c*96 + 64 + k];
    pkB[id] = f2b(val);
  } else if (id < 5152){
    int c = id - 5120;
    biasSum[c] = m1b[c] + m2b[c];
  }
}

// ---------------- skip weights packed as MFMA B-fragments ----------------
__global__ void k_wTb(const float* __restrict__ sw, bf16* __restrict__ wTb){
  int id = blockIdx.x*blockDim.x + threadIdx.x;
  if (id >= 131072) return;
  int j = id & 7, l = (id >> 3) & 63, q = id >> 9;  // q = nt*64 + ks
  int ks = q & 63, nt = q >> 6;
  int k = ks*32 + (l >> 4)*8 + j;
  int t = k >> 5, c = k & 31;
  int sc = nt*16 + (l & 15);
  float val = (t < NTOUT) ? sw[sc*1856 + c*NTOUT + t] : 0.f;
  wTb[id] = f2b(val);
}

// ---------------- dilated inception via MFMA -> Xp[b][n][t][c] bf16 (pad zeroed) ----------------
__global__ void __launch_bounds__(256) k_incepM(const float* __restrict__ x,
    const bf16* __restrict__ wfA, const float* __restrict__ biasPk,
    bf16* __restrict__ Xp){
  __shared__ bf16 xsb[32*72];       // [ic][72] (t padded to 72, zeros in 64..71)
  __shared__ uint4 xim2[28*64];     // [kb][t] : 8 bf16 (k = kb*8+j)
  int b, n; bv_swz(blockIdx.x, b, n);
  int bn = b*NNODE + n;
  int tid = threadIdx.x;
  {
    int c = tid >> 3, t0 = (tid & 7)*8;
    const float* src = x + ((size_t)(b*NC + c)*NNODE + n)*NT + t0;
    float4 v0 = *reinterpret_cast<const float4*>(src);
    float4 v1 = *reinterpret_cast<const float4*>(src + 4);
    float f[8] = {v0.x,v0.y,v0.z,v0.w,v1.x,v1.y,v1.z,v1.w};
    *reinterpret_cast<uint4*>(&xsb[c*72 + t0]) = pack8(f);
    if ((tid & 7) == 7)
      *reinterpret_cast<uint4*>(&xsb[c*72 + 64]) = make_uint4(0,0,0,0);
  }
  __syncthreads();
  #pragma unroll
  for (int i=0;i<7;++i){
    int pr = tid + i*256;
    int kb = pr >> 6, t = pr & 63;
    int k0 = kb*8;
    int ic = k0 / 7, d = k0 - ic*7;
    unsigned sh[8];
    #pragma unroll
    for (int j=0;j<8;++j){
      sh[j] = *reinterpret_cast<const unsigned short*>(&xsb[ic*72 + t + d]);
      ++d; if (d == 7){ d = 0; ++ic; }
    }
    xim2[kb*64 + t] = make_uint4(sh[0]|(sh[1]<<16), sh[2]|(sh[3]<<16),
                                 sh[4]|(sh[5]<<16), sh[6]|(sh[7]<<16));
  }
  __syncthreads();
  int lane = tid & 63;
  int mt = __builtin_amdgcn_readfirstlane(tid >> 6);
  bf16x8 wA[7];
  #pragma unroll
  for (int ks=0; ks<7; ++ks)
    wA[ks] = *reinterpret_cast<const bf16x8*>(wfA + (size_t)((mt*7 + ks)*64 + lane)*8);
  int g = lane >> 4;
  int c0 = mt*8 + 2*g;
  float4 bias2 = *reinterpret_cast<const float4*>(biasPk + c0*2);
  #pragma unroll
  for (int nt=0; nt<4; ++nt){
    int t = (lane & 15) + nt*16;
    f32x4 acc = {0.f, 0.f, 0.f, 0.f};
    #pragma unroll
    for (int ks=0; ks<7; ++ks){
      bf16x8 bfr = __builtin_bit_cast(bf16x8, xim2[(ks*4 + g)*64 + t]);
      acc = __builtin_amdgcn_mfma_f32_16x16x32_bf16(wA[ks], bfr, acc, 0, 0, 0);
    }
    bool act = t < NTOUT;
    float X0 = act ? (ftanh(acc[0] + bias2.x) * fsig(acc[1] + bias2.y)) : 0.f;
    float X1 = act ? (ftanh(acc[2] + bias2.z) * fsig(acc[3] + bias2.w)) : 0.f;
    unsigned pv = (unsigned)bbits(X0) | ((unsigned)bbits(X1) << 16);
    *reinterpret_cast<unsigned*>(Xp + (size_t)bn*PSLAB + t*32 + c0) = pv;
  }
}

// ---------------- skip path via MFMA ----------------
__global__ void __launch_bounds__(256) k_skipM(const bf16* __restrict__ Xp, const bf16* __restrict__ wTb,
      const float* __restrict__ skip_b, const float* __restrict__ x_skip, float* __restrict__ out){
  int bn0 = blockIdx.x * 16;
  int tid = threadIdx.x, lane = tid & 63;
  int nt = __builtin_amdgcn_readfirstlane(tid >> 6);
  int g = lane >> 4, col = lane & 15;
  const bf16* aptr = Xp + (size_t)(bn0 + col)*PSLAB + g*8;
  const bf16* bptr = wTb + ((size_t)nt*64*64 + lane)*8;
  f32x4 acc = {0.f, 0.f, 0.f, 0.f};
  #pragma unroll 4
  for (int ks=0; ks<64; ++ks){
    bf16x8 aF = *reinterpret_cast<const bf16x8*>(aptr + ks*32);
    bf16x8 bF = *reinterpret_cast<const bf16x8*>(bptr + (size_t)ks*512);
    acc = __builtin_amdgcn_mfma_f32_16x16x32_bf16(aF, bF, acc, 0, 0, 0);
  }
  int sc = nt*16 + col;
  float sb = skip_b[sc];
  #pragma unroll
  for (int r=0;r<4;++r){
    int bn = bn0 + g*4 + r;
    int b = bn / NNODE, n = bn - b*NNODE;
    size_t so = (size_t)b*NSKIP*NNODE + (size_t)sc*NNODE + n;
    out[(size_t)XEL + so] = acc[r] + sb + x_skip[so];
  }
}

// ---------------- hop1 both sides in one launch: HA{0,1} = 0.05*Xp + 0.95*(Ah (x) Xp) ----------------
// 19200 blocks; per XCD, sides interleave at the same (b,v) so Xp gather slabs share L2
__global__ void __launch_bounds__(256) k_prop(const bf16* __restrict__ Xp,
    bf16* __restrict__ HA0, bf16* __restrict__ HA1,
    const int* __restrict__ aidx, const float* __restrict__ aval, const int* __restrict__ acnt){
  __shared__ int   sidx[304];
  __shared__ float sval[304];
  int bid = blockIdx.x;
  int xcd = bid & 7, i = bid >> 3;
  int side = i & 1, jj = i >> 1;
  int nb = xcd*1200 + jj;
  int b = nb / NNODE, v = nb - b*NNODE;
  int r = (side ? NNODE : 0) + v;
  bf16* HA = side ? HA1 : HA0;
  int cnt = acnt[r];
  for (int e = threadIdx.x; e < cnt; e += 256){
    sidx[e] = aidx[r*304 + e] * PSLAB;
    sval[e] = aval[r*304 + e];
  }
  __syncthreads();
  int t = threadIdx.x >> 2, cb = threadIdx.x & 3;
  int off = t*32 + cb*8;
  const bf16* base = Xp + (size_t)b*BPSLAB + off;
  float acc[8] = {0,0,0,0,0,0,0,0};
  #pragma unroll 4
  for (int j=0;j<cnt;++j){
    uint4 d = *reinterpret_cast<const uint4*>(base + sidx[j]);
    fma8(acc, d, sval[j]);
  }
  size_t own = (size_t)b*BPSLAB + (size_t)v*PSLAB + off;
  uint4 dx = *reinterpret_cast<const uint4*>(Xp + own);
  float xf[8]; unp8(xf, dx);
  float h[8];
  #pragma unroll
  for (int k=0;k<8;++k) h[k] = fmaf(0.95f, acc[k], 0.05f*xf[k]);
  *reinterpret_cast<uint4*>(HA + own) = pack8(h);
}

// ---------------- hop2 BOTH sides + full 1x1 mix conv (MFMA K=160), single out write ----------------
__global__ void __launch_bounds__(256) k_fuse(const bf16* __restrict__ Xp,
    const bf16* __restrict__ HA0, const bf16* __restrict__ HA1,
    float* __restrict__ out, const float* __restrict__ x,
    const int* __restrict__ aidx, const float* __restrict__ aval, const int* __restrict__ acnt,
    const bf16* __restrict__ pkB, const float* __restrict__ biasSum){
  __shared__ int   sidx0[304];
  __shared__ float sval0[304];
  __shared__ int   sidx1[304];
  __shared__ float sval1[304];
  __shared__ uint4 xs4[320];    // padded stride 5: idx = t*5+cb
  __shared__ uint4 h1a4[320];
  __shared__ uint4 h2a4[320];
  __shared__ uint4 h1b4[320];
  __shared__ uint4 h2b4[320];
  int b, v; bv_swz(blockIdx.x, b, v);
  int r0 = v, r1 = NNODE + v;
  int cnt0 = acnt[r0], cnt1 = acnt[r1];
  for (int e = threadIdx.x; e < cnt0; e += 256){
    sidx0[e] = aidx[r0*304 + e] * PSLAB;
    sval0[e] = aval[r0*304 + e];
  }
  for (int e = threadIdx.x; e < cnt1; e += 256){
    sidx1[e] = aidx[r1*304 + e] * PSLAB;
    sval1[e] = aval[r1*304 + e];
  }
  __syncthreads();
  int tid = threadIdx.x;
  int t = tid >> 2, cb = tid & 3;
  int off = t*32 + cb*8;
  int idx = t*5 + cb;
  size_t bbase = (size_t)b*BPSLAB;
  size_t vbase = bbase + (size_t)v*PSLAB;
  // phase A: own slabs + both hop2 gathers into LDS
  uint4 dx = *reinterpret_cast<const uint4*>(Xp + vbase + off);
  xs4[idx] = dx;
  float xf[8]; unp8(xf, dx);
  h1a4[idx] = *reinterpret_cast<const uint4*>(HA0 + vbase + off);
  h1b4[idx] = *reinterpret_cast<const uint4*>(HA1 + vbase + off);
  {
    const bf16* base = HA0 + bbase + off;
    float acc[8] = {0,0,0,0,0,0,0,0};
    #pragma unroll 4
    for (int j=0;j<cnt0;++j){
      uint4 d = *reinterpret_cast<const uint4*>(base + sidx0[j]);
      fma8(acc, d, sval0[j]);
    }
    float h[8];
    #pragma unroll
    for (int k=0;k<8;++k) h[k] = fmaf(0.95f, acc[k], 0.05f*xf[k]);
    h2a4[idx] = pack8(h);
  }
  {
    const bf16* base = HA1 + bbase + off;
    float acc[8] = {0,0,0,0,0,0,0,0};
    #pragma unroll 4
    for (int j=0;j<cnt1;++j){
      uint4 d = *reinterpret_cast<const uint4*>(base + sidx1[j]);
      fma8(acc, d, sval1[j]);
    }
    float h[8];
    #pragma unroll
    for (int k=0;k<8;++k) h[k] = fmaf(0.95f, acc[k], 0.05f*xf[k]);
    h2b4[idx] = pack8(h);
  }
  __syncthreads();
  // phase B: C[m=t 64][n=c_out 32] = F[64][160] x W[160][32]
  int lane = tid & 63;
  int mt = __builtin_amdgcn_readfirstlane(tid >> 6);
  int g = lane >> 4, col = lane & 15;
  int tRow = mt*16 + col;
  int fidx = tRow*5 + g;
  bf16x8 aX  = __builtin_bit_cast(bf16x8, xs4[fidx]);
  bf16x8 a1a = __builtin_bit_cast(bf16x8, h1a4[fidx]);
  bf16x8 a2a = __builtin_bit_cast(bf16x8, h2a4[fidx]);
  bf16x8 a1b = __builtin_bit_cast(bf16x8, h1b4[fidx]);
  bf16x8 a2b = __builtin_bit_cast(bf16x8, h2b4[fidx]);
  int t0 = mt*16 + g*4;
  #pragma unroll
  for (int nt=0; nt<2; ++nt){
    int c_out = nt*16 + col;
    float bv = biasSum[c_out];
    f32x4 acc = {bv, bv, bv, bv};
    bf16x8 w0 = *reinterpret_cast<const bf16x8*>(pkB + (size_t)((nt*5+0)*64 + lane)*8);
    bf16x8 w1 = *reinterpret_cast<const bf16x8*>(pkB + (size_t)((nt*5+1)*64 + lane)*8);
    bf16x8 w2 = *reinterpret_cast<const bf16x8*>(pkB + (size_t)((nt*5+2)*64 + lane)*8);
    bf16x8 w3 = *reinterpret_cast<const bf16x8*>(pkB + (size_t)((nt*5+3)*64 + lane)*8);
    bf16x8 w4 = *reinterpret_cast<const bf16x8*>(pkB + (size_t)((nt*5+4)*64 + lane)*8);
    acc = __builtin_amdgcn_mfma_f32_16x16x32_bf16(aX,  w0, acc, 0, 0, 0);
    acc = __builtin_amdgcn_mfma_f32_16x16x32_bf16(a1a, w1, acc, 0, 0, 0);
    acc = __builtin_amdgcn_mfma_f32_16x16x32_bf16(a2a, w2, acc, 0, 0, 0);
    acc = __builtin_amdgcn_mfma_f32_16x16x32_bf16(a1b, w3, acc, 0, 0, 0);
    acc = __builtin_amdgcn_mfma_f32_16x16x32_bf16(a2b, w4, acc, 0, 0, 0);
    float* po = out + ((size_t)(b*NC + c_out)*NNODE + v)*NTOUT + t0;
    const float* rx = x + ((size_t)(b*NC + c_out)*NNODE + v)*NT + 6 + t0;
    if (t0 <= 54){
      float2 r0v = *reinterpret_cast<const float2*>(rx);
      float2 r1v = *reinterpret_cast<const float2*>(rx + 2);
      *reinterpret_cast<float2*>(po)     = make_float2(acc[0] + r0v.x, acc[1] + r0v.y);
      *reinterpret_cast<float2*>(po + 2) = make_float2(acc[2] + r1v.x, acc[3] + r1v.y);
    } else if (t0 == 56){
      float2 r0v = *reinterpret_cast<const float2*>(rx);
      *reinterpret_cast<float2*>(po)     = make_float2(acc[0] + r0v.x, acc[1] + r0v.y);
    }
  }
}

// ---------------- layernorm ----------------
__global__ void __launch_bounds__(256) k_lnstat(const float* __restrict__ out, double* __restrict__ part){
  int blk = blockIdx.x; int b = blk >> 3, seg = blk & 7;
  const float* p = out + (size_t)b*BSLAB;
  int start = seg*69600, end = start + 69600;
  double s = 0.0, s2 = 0.0;
  for (int i = start + threadIdx.x; i < end; i += 256){
    double v = (double)p[i]; s += v; s2 += v*v;
  }
  #pragma unroll
  for (int off=32; off; off>>=1){ s += __shfl_down(s, off); s2 += __shfl_down(s2, off); }
  __shared__ double ls[4], ls2[4];
  int lane = threadIdx.x & 63, w = threadIdx.x >> 6;
  if (lane==0){ ls[w]=s; ls2[w]=s2; }
  __syncthreads();
  if (threadIdx.x==0){
    double a=0.0, a2=0.0;
    for (int i=0;i<4;++i){ a+=ls[i]; a2+=ls2[i]; }
    part[blk*2]=a; part[blk*2+1]=a2;
  }
}

__global__ void k_lnfin(const double* __restrict__ part, float* __restrict__ stats){
  int b = threadIdx.x; if (b >= 32) return;
  double s=0.0, s2=0.0;
  for (int seg=0; seg<8; ++seg){ s += part[(b*8+seg)*2]; s2 += part[(b*8+seg)*2+1]; }
  double n = (double)BSLAB;
  double mean = s/n;
  double var = s2/n - mean*mean;
  stats[b*2]   = (float)mean;
  stats[b*2+1] = (float)(1.0/sqrt(var + 1e-5));
}

__global__ void __launch_bounds__(256) k_lnapply(float* __restrict__ out, const float* __restrict__ stats,
        const float* __restrict__ lnw, const float* __restrict__ lnb, const int* __restrict__ idxp){
  int o = blockIdx.x*256 + threadIdx.x;
  int t = o % NTOUT; int v = (o / NTOUT) % NNODE; int c = (o / SLAB) % NC; int b = o / BSLAB;
  float mean = stats[b*2], rstd = stats[b*2+1];
  int vn = idxp[v];
  float wv = lnw[((size_t)c*NNODE + vn)*NTOUT + t];
  float bv = lnb[((size_t)c*NNODE + vn)*NTOUT + t];
  float vx = out[o];
  out[o] = (vx - mean)*rstd*wv + bv;
}

extern "C" void kernel_launch(void* const* d_in, const int* in_sizes, int n_in,
                              void* d_out, int out_size, void* d_ws, size_t ws_size,
                              hipStream_t stream) {
  (void)in_sizes; (void)n_in; (void)out_size; (void)ws_size;
  const float* x     = (const float*)d_in[0];
  const float* xskip = (const float*)d_in[1];
  const int*   idxp  = (const int*)d_in[2];
  const float* emb1  = (const float*)d_in[3];
  const float* emb2  = (const float*)d_in[4];
  const float* l1w   = (const float*)d_in[5];
  const float* l1b   = (const float*)d_in[6];
  const float* l2w   = (const float*)d_in[7];
  const float* l2b   = (const float*)d_in[8];
  const float* skw   = (const float*)d_in[9];
  const float* skb   = (const float*)d_in[10];
  const float* m1w   = (const float*)d_in[11];
  const float* m1b   = (const float*)d_in[12];
  const float* m2w   = (const float*)d_in[13];
  const float* m2b   = (const float*)d_in[14];
  const float* lnw   = (const float*)d_in[15];
  const float* lnb   = (const float*)d_in[16];
  const float* fw2=(const float*)d_in[17]; const float* fb2=(const float*)d_in[18];
  const float* gw2=(const float*)d_in[19]; const float* gb2=(const float*)d_in[20];
  const float* fw3=(const float*)d_in[21]; const float* fb3=(const float*)d_in[22];
  const float* gw3=(const float*)d_in[23]; const float* gb3=(const float*)d_in[24];
  const float* fw6=(const float*)d_in[25]; const float* fb6=(const float*)d_in[26];
  const float* gw6=(const float*)d_in[27]; const float* gb6=(const float*)d_in[28];
  const float* fw7=(const float*)d_in[29]; const float* fb7=(const float*)d_in[30];
  const float* gw7=(const float*)d_in[31]; const float* gb7=(const float*)d_in[32];
  float* out = (float*)d_out;

  char* wsbase = (char*)d_ws;
  size_t cur = 0;
  auto alloc = [&](size_t bytes)->char*{
    char* p = wsbase + cur;
    cur = (cur + bytes + 255) & ~(size_t)255;
    return p;
  };
  bf16*  Xp   = (bf16*) alloc((size_t)XPEL*2);
  bf16*  HA0  = (bf16*) alloc((size_t)XPEL*2);
  bf16*  HA1  = (bf16*) alloc((size_t)XPEL*2);
  float* n1   = (float*)alloc(12000*4);
  float* n2   = (float*)alloc(12000*4);
  float* Am   = (float*)alloc(90000*4);
  int*   aidx = (int*)  alloc(600*304*4);
  float* aval = (float*)alloc(600*304*4);
  int*   acnt = (int*)  alloc(600*4);
  bf16*  wTb  = (bf16*) alloc(131072*2);
  bf16*  wfA  = (bf16*) alloc(14336*2);
  float* biasPk = (float*)alloc(64*4);
  bf16*  pkB  = (bf16*) alloc(5120*2);
  float* biasSum = (float*)alloc(32*4);
  double* part = (double*)alloc(256*2*8);
  float* stats = (float*)alloc(64*4);

  // graph construction (tiny)
  k_nodes <<<NNODE, 64, 0, stream>>>(emb1, emb2, l1w, l1b, l2w, l2b, idxp, n1, n2);
  k_adjrow<<<NNODE, 64, 0, stream>>>(n1, n2, Am);
  k_csr   <<<2*NNODE, 64, 0, stream>>>(Am, aidx, aval, acnt);

  // weight prep
  k_wpack2<<<57, 256, 0, stream>>>(fw2,fw3,fw6,fw7, gw2,gw3,gw6,gw7,
                                   fb2,fb3,fb6,fb7, gb2,gb3,gb6,gb7, wfA, biasPk);
  k_wprepM<<<21, 256, 0, stream>>>(m1w, m2w, m1b, m2b, pkB, biasSum);
  k_wTb   <<<512, 256, 0, stream>>>(skw, wTb);

  // dilated inception -> Xp (MFMA, channel-minor layout)
  k_incepM<<<NB*NNODE, 256, 0, stream>>>(x, wfA, biasPk, Xp);

  // skip path (MFMA GEMM)
  k_skipM<<<(NB*NNODE)/16, 256, 0, stream>>>(Xp, wTb, skb, xskip, out);

  // hop1, both adjacency sides in one launch
  k_prop<<<2*NB*NNODE, 256, 0, stream>>>(Xp, HA0, HA1, aidx, aval, acnt);

  // hop2 + full mix conv + residual, single out write
  k_fuse<<<NB*NNODE, 256, 0, stream>>>(Xp, HA0, HA1, out, x, aidx, aval, acnt, pkB, biasSum);

  // layernorm
  k_lnstat<<<256, 256, 0, stream>>>(out, part);
  k_lnfin<<<1, 32, 0, stream>>>(part, stats);
  k_lnapply<<<XEL/256, 256, 0, stream>>>(out, stats, lnw, lnb, idxp);
}

// Round 10
// 367.810 us; speedup vs baseline: 3.9377x; 1.2198x over previous
//
#include <hip/hip_runtime.h>
#include <hip/hip_bf16.h>
#include <math.h>

typedef __hip_bfloat16 bf16;
typedef __attribute__((ext_vector_type(8))) short bf16x8;
typedef __attribute__((ext_vector_type(4))) float f32x4;

#define NB 32
#define NC 32
#define NNODE 300
#define NT 64
#define NDIM 40
#define KTOP 20
#define NSKIP 64
#define NTOUT 58
#define SLAB 17400        // NNODE*NTOUT (out layout)
#define BSLAB 556800      // NC*SLAB
#define XEL 17817600      // NB*BSLAB
#define PSLAB 2048        // 64 t x 32 c node slab (channel-minor)
#define BPSLAB 614400     // NNODE*PSLAB
#define XPEL 19660800     // NB*BPSLAB

__device__ __forceinline__ float b2f(bf16 v){ return __bfloat162float(v); }
__device__ __forceinline__ bf16 f2b(float v){ return __float2bfloat16(v); }
__device__ __forceinline__ float fsig(float x){ return 1.0f/(1.0f + __expf(-x)); }
__device__ __forceinline__ float ftanh(float x){ return 2.0f*fsig(2.0f*x) - 1.0f; }

__device__ __forceinline__ unsigned short bbits(float v){
  bf16 h = f2b(v); unsigned short s; __builtin_memcpy(&s, &h, 2); return s;
}

// 8 bf16 in a uint4: acc[k] += vv * e[k]
__device__ __forceinline__ void fma8(float acc[8], uint4 d, float vv){
  acc[0] = fmaf(vv, __uint_as_float(d.x << 16),          acc[0]);
  acc[1] = fmaf(vv, __uint_as_float(d.x & 0xffff0000u),  acc[1]);
  acc[2] = fmaf(vv, __uint_as_float(d.y << 16),          acc[2]);
  acc[3] = fmaf(vv, __uint_as_float(d.y & 0xffff0000u),  acc[3]);
  acc[4] = fmaf(vv, __uint_as_float(d.z << 16),          acc[4]);
  acc[5] = fmaf(vv, __uint_as_float(d.z & 0xffff0000u),  acc[5]);
  acc[6] = fmaf(vv, __uint_as_float(d.w << 16),          acc[6]);
  acc[7] = fmaf(vv, __uint_as_float(d.w & 0xffff0000u),  acc[7]);
}

__device__ __forceinline__ void unp8(float f[8], uint4 d){
  f[0] = __uint_as_float(d.x << 16); f[1] = __uint_as_float(d.x & 0xffff0000u);
  f[2] = __uint_as_float(d.y << 16); f[3] = __uint_as_float(d.y & 0xffff0000u);
  f[4] = __uint_as_float(d.z << 16); f[5] = __uint_as_float(d.z & 0xffff0000u);
  f[6] = __uint_as_float(d.w << 16); f[7] = __uint_as_float(d.w & 0xffff0000u);
}

__device__ __forceinline__ uint4 pack8(const float f[8]){
  uint4 d;
  d.x = (unsigned)bbits(f[0]) | ((unsigned)bbits(f[1]) << 16);
  d.y = (unsigned)bbits(f[2]) | ((unsigned)bbits(f[3]) << 16);
  d.z = (unsigned)bbits(f[4]) | ((unsigned)bbits(f[5]) << 16);
  d.w = (unsigned)bbits(f[6]) | ((unsigned)bbits(f[7]) << 16);
  return d;
}

// XCD-aware swizzle for 9600-block graph kernels
__device__ __forceinline__ void bv_swz(int bid, int& b, int& v){
  int xcd = bid & 7, i = bid >> 3;
  int nb = xcd*1200 + i;
  b = nb / NNODE; v = nb - b*NNODE;
}

// ---------------- graph construction ----------------
__global__ void k_nodes(const float* __restrict__ emb1, const float* __restrict__ emb2,
                        const float* __restrict__ l1w, const float* __restrict__ l1b,
                        const float* __restrict__ l2w, const float* __restrict__ l2b,
                        const int* __restrict__ idxp,
                        float* __restrict__ n1, float* __restrict__ n2){
  int i = blockIdx.x; int d = threadIdx.x;
  if (d >= NDIM) return;
  int r = idxp[i];
  float a1 = l1b[d], a2 = l2b[d];
  for (int k=0;k<NDIM;++k){
    a1 = fmaf(emb1[r*NDIM+k], l1w[d*NDIM+k], a1);
    a2 = fmaf(emb2[r*NDIM+k], l2w[d*NDIM+k], a2);
  }
  n1[i*NDIM+d] = tanhf(3.0f*a1);
  n2[i*NDIM+d] = tanhf(3.0f*a2);
}

__global__ void __launch_bounds__(64) k_adjrow(const float* __restrict__ n1,
                                               const float* __restrict__ n2,
                                               float* __restrict__ Am){
  int i = blockIdx.x; int lane = threadIdx.x;
  __shared__ float rowo[NNODE];
  __shared__ float rowv[NNODE];
  __shared__ int   sel[NNODE];
  for (int j=lane;j<NNODE;j+=64){
    float a = 0.f;
    #pragma unroll
    for (int k=0;k<NDIM;++k){
      float a1 = n1[i*NDIM+k], a2 = n2[i*NDIM+k];
      a = fmaf(a1, n2[j*NDIM+k], a);
      a = fmaf(-a2, n1[j*NDIM+k], a);
    }
    float v = tanhf(3.0f*a);
    v = v > 0.f ? v : 0.f;
    rowo[j]=v; rowv[j]=v; sel[j]=0;
  }
  __syncthreads();
  for (int it=0; it<KTOP; ++it){
    float best = -1.f; int bi = 0x7fffffff;
    for (int j=lane;j<NNODE;j+=64){
      float v = rowv[j];
      if (v > best){ best=v; bi=j; }
    }
    #pragma unroll
    for (int off=32; off; off>>=1){
      float ov = __shfl_xor(best, off);
      int   oi = __shfl_xor(bi, off);
      if (ov > best || (ov == best && oi < bi)){ best=ov; bi=oi; }
    }
    if (lane==0){ sel[bi]=1; rowv[bi]=-2.f; }
    __syncthreads();
  }
  for (int j=lane;j<NNODE;j+=64)
    Am[i*NNODE+j] = sel[j] ? rowo[j] : 0.f;
}

__global__ void __launch_bounds__(64) k_csr(const float* __restrict__ Am,
                                            int* __restrict__ aidx, float* __restrict__ aval,
                                            int* __restrict__ acnt){
  int r = blockIdx.x; int lane = threadIdx.x;
  int v = (r < NNODE) ? r : r - NNODE;
  int*   ip = aidx + r*304;
  float* vp = aval + r*304;
  if (lane==0){ ip[0]=v; vp[0]=1.0f; }
  int cnt = 1; float s = 1.0f;
  for (int base=0; base<NNODE; base+=64){
    int j = base + lane; float val = 0.f; bool p = false;
    if (j < NNODE){
      val = (r < NNODE) ? Am[v*NNODE + j] : Am[j*NNODE + v];
      p = val > 0.f;
    }
    unsigned long long m = __ballot(p);
    int pre = __popcll(m & ((1ull << lane) - 1ull));
    if (p){ ip[cnt+pre]=j; vp[cnt+pre]=val; }
    cnt += __popcll(m);
    float vs = p ? val : 0.f;
    #pragma unroll
    for (int off=32; off; off>>=1) vs += __shfl_xor(vs, off);
    s += vs;
  }
  for (int e=lane; e<cnt; e+=64) vp[e] = vp[e] / s;
  if (lane==0) acnt[r]=cnt;
}

// ---------------- inception weight fragment packing for MFMA ----------------
__global__ void k_wpack2(const float* __restrict__ fw2,const float* __restrict__ fw3,
                         const float* __restrict__ fw6,const float* __restrict__ fw7,
                         const float* __restrict__ gw2,const float* __restrict__ gw3,
                         const float* __restrict__ gw6,const float* __restrict__ gw7,
                         const float* __restrict__ fb2,const float* __restrict__ fb3,
                         const float* __restrict__ fb6,const float* __restrict__ fb7,
                         const float* __restrict__ gb2,const float* __restrict__ gb3,
                         const float* __restrict__ gb6,const float* __restrict__ gb7,
                         bf16* __restrict__ wfA, float* __restrict__ biasPk){
  int T = blockIdx.x*blockDim.x + threadIdx.x;
  if (T < 14336){
    int j = T & 7;
    int q = T >> 3;
    int l = q & 63; q >>= 6;
    int ks = q % 7, mt = q / 7;
    int m = mt*16 + (l & 15);
    int k = ks*32 + (l >> 4)*8 + j;
    int c = m >> 1, path = m & 1;
    int cls = c >> 3, o = c & 7;
    int ic = k / 7, d = k - ic*7;
    int kk = (cls==0) ? 2 : (cls==1) ? 3 : (cls==2) ? 6 : 7;
    int tp = d - (7 - kk);
    float val = 0.f;
    if (tp >= 0){
      const float* w = (path==0)
        ? (cls==0?fw2:cls==1?fw3:cls==2?fw6:fw7)
        : (cls==0?gw2:cls==1?gw3:cls==2?gw6:gw7);
      val = w[(o*NC + ic)*kk + tp];
    }
    wfA[T] = f2b(val);
  } else if (T < 14336 + 32){
    int c = T - 14336;
    int cls = c >> 3, o = c & 7;
    const float* fb = cls==0?fb2:cls==1?fb3:cls==2?fb6:fb7;
    const float* gb = cls==0?gb2:cls==1?gb3:cls==2?gb6:gb7;
    biasPk[c*2]   = fb[o];
    biasPk[c*2+1] = gb[o];
  }
}

// ---------------- mix conv weights: ONE combined B-fragment buffer, K=160 ----------------
__global__ void k_wprepM(const float* __restrict__ m1w, const float* __restrict__ m2w,
                         const float* __restrict__ m1b, const float* __restrict__ m2b,
                         bf16* __restrict__ pkB, float* __restrict__ biasSum){
  int id = blockIdx.x*blockDim.x + threadIdx.x;
  if (id < 5120){
    int j = id & 7, l = (id >> 3) & 63, q = id >> 9;   // q = nt*5+ks
    int ks = q % 5, nt = q / 5;
    int k = (l >> 4)*8 + j;
    int c = nt*16 + (l & 15);
    float val;
    if      (ks == 0) val = m1w[c*96 + k] + m2w[c*96 + k];
    else if (ks == 1) val = m1w[c*96 + 32 + k];
    else if (ks == 2) val = m1w[c*96 + 64 + k];
    else if (ks == 3) val = m2w[c*96 + 32 + k];
    else              val = m2w[c*96 + 64 + k];
    pkB[id] = f2b(val);
  } else if (id < 5152){
    int c = id - 5120;
    biasSum[c] = m1b[c] + m2b[c];
  }
}

// ---------------- skip weights packed as MFMA B-fragments ----------------
__global__ void k_wTb(const float* __restrict__ sw, bf16* __restrict__ wTb){
  int id = blockIdx.x*blockDim.x + threadIdx.x;
  if (id >= 131072) return;
  int j = id & 7, l = (id >> 3) & 63, q = id >> 9;  // q = nt*64 + ks
  int ks = q & 63, nt = q >> 6;
  int k = ks*32 + (l >> 4)*8 + j;
  int t = k >> 5, c = k & 31;
  int sc = nt*16 + (l & 15);
  float val = (t < NTOUT) ? sw[sc*1856 + c*NTOUT + t] : 0.f;
  wTb[id] = f2b(val);
}

// ---------------- dilated inception via MFMA -> Xp[b][n][t][c] bf16 (pad zeroed) ----------------
__global__ void __launch_bounds__(256) k_incepM(const float* __restrict__ x,
    const bf16* __restrict__ wfA, const float* __restrict__ biasPk,
    bf16* __restrict__ Xp){
  __shared__ bf16 xsb[32*72];       // [ic][72] (t padded to 72, zeros in 64..71)
  __shared__ uint4 xim2[28*64];     // [kb][t] : 8 bf16 (k = kb*8+j)
  int b, n; bv_swz(blockIdx.x, b, n);
  int bn = b*NNODE + n;
  int tid = threadIdx.x;
  {
    int c = tid >> 3, t0 = (tid & 7)*8;
    const float* src = x + ((size_t)(b*NC + c)*NNODE + n)*NT + t0;
    float4 v0 = *reinterpret_cast<const float4*>(src);
    float4 v1 = *reinterpret_cast<const float4*>(src + 4);
    float f[8] = {v0.x,v0.y,v0.z,v0.w,v1.x,v1.y,v1.z,v1.w};
    *reinterpret_cast<uint4*>(&xsb[c*72 + t0]) = pack8(f);
    if ((tid & 7) == 7)
      *reinterpret_cast<uint4*>(&xsb[c*72 + 64]) = make_uint4(0,0,0,0);
  }
  __syncthreads();
  #pragma unroll
  for (int i=0;i<7;++i){
    int pr = tid + i*256;
    int kb = pr >> 6, t = pr & 63;
    int k0 = kb*8;
    int ic = k0 / 7, d = k0 - ic*7;
    unsigned sh[8];
    #pragma unroll
    for (int j=0;j<8;++j){
      sh[j] = *reinterpret_cast<const unsigned short*>(&xsb[ic*72 + t + d]);
      ++d; if (d == 7){ d = 0; ++ic; }
    }
    xim2[kb*64 + t] = make_uint4(sh[0]|(sh[1]<<16), sh[2]|(sh[3]<<16),
                                 sh[4]|(sh[5]<<16), sh[6]|(sh[7]<<16));
  }
  __syncthreads();
  int lane = tid & 63;
  int mt = __builtin_amdgcn_readfirstlane(tid >> 6);
  bf16x8 wA[7];
  #pragma unroll
  for (int ks=0; ks<7; ++ks)
    wA[ks] = *reinterpret_cast<const bf16x8*>(wfA + (size_t)((mt*7 + ks)*64 + lane)*8);
  int g = lane >> 4;
  int c0 = mt*8 + 2*g;
  float4 bias2 = *reinterpret_cast<const float4*>(biasPk + c0*2);
  #pragma unroll
  for (int nt=0; nt<4; ++nt){
    int t = (lane & 15) + nt*16;
    f32x4 acc = {0.f, 0.f, 0.f, 0.f};
    #pragma unroll
    for (int ks=0; ks<7; ++ks){
      bf16x8 bfr = __builtin_bit_cast(bf16x8, xim2[(ks*4 + g)*64 + t]);
      acc = __builtin_amdgcn_mfma_f32_16x16x32_bf16(wA[ks], bfr, acc, 0, 0, 0);
    }
    bool act = t < NTOUT;
    float X0 = act ? (ftanh(acc[0] + bias2.x) * fsig(acc[1] + bias2.y)) : 0.f;
    float X1 = act ? (ftanh(acc[2] + bias2.z) * fsig(acc[3] + bias2.w)) : 0.f;
    unsigned pv = (unsigned)bbits(X0) | ((unsigned)bbits(X1) << 16);
    *reinterpret_cast<unsigned*>(Xp + (size_t)bn*PSLAB + t*32 + c0) = pv;
  }
}

// ---------------- skip path via MFMA ----------------
__global__ void __launch_bounds__(256) k_skipM(const bf16* __restrict__ Xp, const bf16* __restrict__ wTb,
      const float* __restrict__ skip_b, const float* __restrict__ x_skip, float* __restrict__ out){
  int bn0 = blockIdx.x * 16;
  int tid = threadIdx.x, lane = tid & 63;
  int nt = __builtin_amdgcn_readfirstlane(tid >> 6);
  int g = lane >> 4, col = lane & 15;
  const bf16* aptr = Xp + (size_t)(bn0 + col)*PSLAB + g*8;
  const bf16* bptr = wTb + ((size_t)nt*64*64 + lane)*8;
  f32x4 acc = {0.f, 0.f, 0.f, 0.f};
  #pragma unroll 4
  for (int ks=0; ks<64; ++ks){
    bf16x8 aF = *reinterpret_cast<const bf16x8*>(aptr + ks*32);
    bf16x8 bF = *reinterpret_cast<const bf16x8*>(bptr + (size_t)ks*512);
    acc = __builtin_amdgcn_mfma_f32_16x16x32_bf16(aF, bF, acc, 0, 0, 0);
  }
  int sc = nt*16 + col;
  float sb = skip_b[sc];
  #pragma unroll
  for (int r=0;r<4;++r){
    int bn = bn0 + g*4 + r;
    int b = bn / NNODE, n = bn - b*NNODE;
    size_t so = (size_t)b*NSKIP*NNODE + (size_t)sc*NNODE + n;
    out[(size_t)XEL + so] = acc[r] + sb + x_skip[so];
  }
}

// ---------------- hop1 both sides in one launch ----------------
__global__ void __launch_bounds__(256) k_prop(const bf16* __restrict__ Xp,
    bf16* __restrict__ HA0, bf16* __restrict__ HA1,
    const int* __restrict__ aidx, const float* __restrict__ aval, const int* __restrict__ acnt){
  __shared__ int   sidx[304];
  __shared__ float sval[304];
  int bid = blockIdx.x;
  int xcd = bid & 7, i = bid >> 3;
  int side = i & 1, jj = i >> 1;
  int nb = xcd*1200 + jj;
  int b = nb / NNODE, v = nb - b*NNODE;
  int r = (side ? NNODE : 0) + v;
  bf16* HA = side ? HA1 : HA0;
  int cnt = acnt[r];
  for (int e = threadIdx.x; e < cnt; e += 256){
    sidx[e] = aidx[r*304 + e] * PSLAB;
    sval[e] = aval[r*304 + e];
  }
  __syncthreads();
  int t = threadIdx.x >> 2, cb = threadIdx.x & 3;
  int off = t*32 + cb*8;
  const bf16* base = Xp + (size_t)b*BPSLAB + off;
  float acc[8] = {0,0,0,0,0,0,0,0};
  #pragma unroll 4
  for (int j=0;j<cnt;++j){
    uint4 d = *reinterpret_cast<const uint4*>(base + sidx[j]);
    fma8(acc, d, sval[j]);
  }
  size_t own = (size_t)b*BPSLAB + (size_t)v*PSLAB + off;
  uint4 dx = *reinterpret_cast<const uint4*>(Xp + own);
  float xf[8]; unp8(xf, dx);
  float h[8];
  #pragma unroll
  for (int k=0;k<8;++k) h[k] = fmaf(0.95f, acc[k], 0.05f*xf[k]);
  *reinterpret_cast<uint4*>(HA + own) = pack8(h);
}

// ---------------- hop2 both sides + 1x1 mix conv (MFMA K=160) + LN partial sums ----------------
// 512 threads: tid<256 -> side0 gather, tid>=256 -> side1 gather. Phase B: 8 waves,
// wave = mt + 4*nt_sel? -> mt = wave&3, nt = wave>>2.
__global__ void __launch_bounds__(512) k_fuse(const bf16* __restrict__ Xp,
    const bf16* __restrict__ HA0, const bf16* __restrict__ HA1,
    float* __restrict__ out, const float* __restrict__ x,
    const int* __restrict__ aidx, const float* __restrict__ aval, const int* __restrict__ acnt,
    const bf16* __restrict__ pkB, const float* __restrict__ biasSum,
    double* __restrict__ part2){
  __shared__ int   sidx[2][304];
  __shared__ float sval[2][304];
  __shared__ uint4 h2s[2][320];      // stride-5 padded [t*5+cb]
  __shared__ float redS[8], redS2[8];
  int b, v; bv_swz(blockIdx.x, b, v);
  int tid = threadIdx.x;
  int side = tid >> 8;
  int st = tid & 255;
  int r = side*NNODE + v;
  int cnt = acnt[r];
  for (int e = st; e < cnt; e += 256){
    sidx[side][e] = aidx[r*304 + e] * PSLAB;
    sval[side][e] = aval[r*304 + e];
  }
  __syncthreads();
  size_t bbase = (size_t)b*BPSLAB;
  size_t vbase = bbase + (size_t)v*PSLAB;
  // phase A: this half's hop2 gather into LDS
  {
    int t = st >> 2, cb = st & 3;
    int off = t*32 + cb*8;
    const bf16* HH = side ? HA1 : HA0;
    const bf16* base = HH + bbase + off;
    const int*   si = sidx[side];
    const float* sv = sval[side];
    float acc[8] = {0,0,0,0,0,0,0,0};
    #pragma unroll 4
    for (int j=0;j<cnt;++j){
      uint4 d = *reinterpret_cast<const uint4*>(base + si[j]);
      fma8(acc, d, sv[j]);
    }
    uint4 dx = *reinterpret_cast<const uint4*>(Xp + vbase + off);
    float xf[8]; unp8(xf, dx);
    float h[8];
    #pragma unroll
    for (int k=0;k<8;++k) h[k] = fmaf(0.95f, acc[k], 0.05f*xf[k]);
    h2s[side][t*5 + cb] = pack8(h);
  }
  __syncthreads();
  // phase B: 8 waves; wave -> (mt = w&3, nt = w>>2)
  int lane = tid & 63;
  int wave = __builtin_amdgcn_readfirstlane(tid >> 6);
  int mt = wave & 3, nt = wave >> 2;
  int g = lane >> 4, col = lane & 15;
  int tRow = mt*16 + col;
  const bf16* slab = Xp + vbase + tRow*32 + g*8;
  bf16x8 aX  = *reinterpret_cast<const bf16x8*>(slab);
  bf16x8 a1a = *reinterpret_cast<const bf16x8*>(HA0 + vbase + tRow*32 + g*8);
  bf16x8 a1b = *reinterpret_cast<const bf16x8*>(HA1 + vbase + tRow*32 + g*8);
  bf16x8 a2a = __builtin_bit_cast(bf16x8, h2s[0][tRow*5 + g]);
  bf16x8 a2b = __builtin_bit_cast(bf16x8, h2s[1][tRow*5 + g]);
  int c_out = nt*16 + col;
  float bv = biasSum[c_out];
  f32x4 acc = {bv, bv, bv, bv};
  {
    bf16x8 w0 = *reinterpret_cast<const bf16x8*>(pkB + (size_t)((nt*5+0)*64 + lane)*8);
    bf16x8 w1 = *reinterpret_cast<const bf16x8*>(pkB + (size_t)((nt*5+1)*64 + lane)*8);
    bf16x8 w2 = *reinterpret_cast<const bf16x8*>(pkB + (size_t)((nt*5+2)*64 + lane)*8);
    bf16x8 w3 = *reinterpret_cast<const bf16x8*>(pkB + (size_t)((nt*5+3)*64 + lane)*8);
    bf16x8 w4 = *reinterpret_cast<const bf16x8*>(pkB + (size_t)((nt*5+4)*64 + lane)*8);
    acc = __builtin_amdgcn_mfma_f32_16x16x32_bf16(aX,  w0, acc, 0, 0, 0);
    acc = __builtin_amdgcn_mfma_f32_16x16x32_bf16(a1a, w1, acc, 0, 0, 0);
    acc = __builtin_amdgcn_mfma_f32_16x16x32_bf16(a2a, w2, acc, 0, 0, 0);
    acc = __builtin_amdgcn_mfma_f32_16x16x32_bf16(a1b, w3, acc, 0, 0, 0);
    acc = __builtin_amdgcn_mfma_f32_16x16x32_bf16(a2b, w4, acc, 0, 0, 0);
  }
  int t0 = mt*16 + g*4;
  float s = 0.f, s2 = 0.f;
  float* po = out + ((size_t)(b*NC + c_out)*NNODE + v)*NTOUT + t0;
  const float* rx = x + ((size_t)(b*NC + c_out)*NNODE + v)*NT + 6 + t0;
  if (t0 <= 54){
    float2 r0v = *reinterpret_cast<const float2*>(rx);
    float2 r1v = *reinterpret_cast<const float2*>(rx + 2);
    float o0 = acc[0] + r0v.x, o1 = acc[1] + r0v.y;
    float o2 = acc[2] + r1v.x, o3 = acc[3] + r1v.y;
    *reinterpret_cast<float2*>(po)     = make_float2(o0, o1);
    *reinterpret_cast<float2*>(po + 2) = make_float2(o2, o3);
    s  = o0 + o1 + o2 + o3;
    s2 = o0*o0 + o1*o1 + o2*o2 + o3*o3;
  } else if (t0 == 56){
    float2 r0v = *reinterpret_cast<const float2*>(rx);
    float o0 = acc[0] + r0v.x, o1 = acc[1] + r0v.y;
    *reinterpret_cast<float2*>(po) = make_float2(o0, o1);
    s  = o0 + o1;
    s2 = o0*o0 + o1*o1;
  }
  // LN partial reduction: wave shfl -> LDS -> block -> atomic
  #pragma unroll
  for (int o=32; o; o>>=1){ s += __shfl_down(s, o); s2 += __shfl_down(s2, o); }
  if (lane == 0){ redS[wave] = s; redS2[wave] = s2; }
  __syncthreads();
  if (tid == 0){
    float as = 0.f, as2 = 0.f;
    #pragma unroll
    for (int w=0; w<8; ++w){ as += redS[w]; as2 += redS2[w]; }
    atomicAdd(&part2[b*2],   (double)as);
    atomicAdd(&part2[b*2+1], (double)as2);
  }
}

// ---------------- layernorm ----------------
__global__ void k_lnfin(const double* __restrict__ part2, float* __restrict__ stats){
  int b = threadIdx.x; if (b >= 32) return;
  double s = part2[b*2], s2 = part2[b*2+1];
  double n = (double)BSLAB;
  double mean = s/n;
  double var = s2/n - mean*mean;
  stats[b*2]   = (float)mean;
  stats[b*2+1] = (float)(1.0/sqrt(var + 1e-5));
}

__global__ void __launch_bounds__(256) k_lnapply(float* __restrict__ out, const float* __restrict__ stats,
        const float* __restrict__ lnw, const float* __restrict__ lnb, const int* __restrict__ idxp){
  int o = blockIdx.x*256 + threadIdx.x;
  int t = o % NTOUT; int v = (o / NTOUT) % NNODE; int c = (o / SLAB) % NC; int b = o / BSLAB;
  float mean = stats[b*2], rstd = stats[b*2+1];
  int vn = idxp[v];
  float wv = lnw[((size_t)c*NNODE + vn)*NTOUT + t];
  float bv = lnb[((size_t)c*NNODE + vn)*NTOUT + t];
  float vx = out[o];
  out[o] = (vx - mean)*rstd*wv + bv;
}

extern "C" void kernel_launch(void* const* d_in, const int* in_sizes, int n_in,
                              void* d_out, int out_size, void* d_ws, size_t ws_size,
                              hipStream_t stream) {
  (void)in_sizes; (void)n_in; (void)out_size; (void)ws_size;
  const float* x     = (const float*)d_in[0];
  const float* xskip = (const float*)d_in[1];
  const int*   idxp  = (const int*)d_in[2];
  const float* emb1  = (const float*)d_in[3];
  const float* emb2  = (const float*)d_in[4];
  const float* l1w   = (const float*)d_in[5];
  const float* l1b   = (const float*)d_in[6];
  const float* l2w   = (const float*)d_in[7];
  const float* l2b   = (const float*)d_in[8];
  const float* skw   = (const float*)d_in[9];
  const float* skb   = (const float*)d_in[10];
  const float* m1w   = (const float*)d_in[11];
  const float* m1b   = (const float*)d_in[12];
  const float* m2w   = (const float*)d_in[13];
  const float* m2b   = (const float*)d_in[14];
  const float* lnw   = (const float*)d_in[15];
  const float* lnb   = (const float*)d_in[16];
  const float* fw2=(const float*)d_in[17]; const float* fb2=(const float*)d_in[18];
  const float* gw2=(const float*)d_in[19]; const float* gb2=(const float*)d_in[20];
  const float* fw3=(const float*)d_in[21]; const float* fb3=(const float*)d_in[22];
  const float* gw3=(const float*)d_in[23]; const float* gb3=(const float*)d_in[24];
  const float* fw6=(const float*)d_in[25]; const float* fb6=(const float*)d_in[26];
  const float* gw6=(const float*)d_in[27]; const float* gb6=(const float*)d_in[28];
  const float* fw7=(const float*)d_in[29]; const float* fb7=(const float*)d_in[30];
  const float* gw7=(const float*)d_in[31]; const float* gb7=(const float*)d_in[32];
  float* out = (float*)d_out;

  char* wsbase = (char*)d_ws;
  size_t cur = 0;
  auto alloc = [&](size_t bytes)->char*{
    char* p = wsbase + cur;
    cur = (cur + bytes + 255) & ~(size_t)255;
    return p;
  };
  bf16*  Xp   = (bf16*) alloc((size_t)XPEL*2);
  bf16*  HA0  = (bf16*) alloc((size_t)XPEL*2);
  bf16*  HA1  = (bf16*) alloc((size_t)XPEL*2);
  float* n1   = (float*)alloc(12000*4);
  float* n2   = (float*)alloc(12000*4);
  float* Am   = (float*)alloc(90000*4);
  int*   aidx = (int*)  alloc(600*304*4);
  float* aval = (float*)alloc(600*304*4);
  int*   acnt = (int*)  alloc(600*4);
  bf16*  wTb  = (bf16*) alloc(131072*2);
  bf16*  wfA  = (bf16*) alloc(14336*2);
  float* biasPk = (float*)alloc(64*4);
  bf16*  pkB  = (bf16*) alloc(5120*2);
  float* biasSum = (float*)alloc(32*4);
  double* part2 = (double*)alloc(64*8);
  float* stats = (float*)alloc(64*4);

  // zero LN accumulators (poisoned by harness)
  hipMemsetAsync(part2, 0, 64*sizeof(double), stream);

  // graph construction (tiny)
  k_nodes <<<NNODE, 64, 0, stream>>>(emb1, emb2, l1w, l1b, l2w, l2b, idxp, n1, n2);
  k_adjrow<<<NNODE, 64, 0, stream>>>(n1, n2, Am);
  k_csr   <<<2*NNODE, 64, 0, stream>>>(Am, aidx, aval, acnt);

  // weight prep
  k_wpack2<<<57, 256, 0, stream>>>(fw2,fw3,fw6,fw7, gw2,gw3,gw6,gw7,
                                   fb2,fb3,fb6,fb7, gb2,gb3,gb6,gb7, wfA, biasPk);
  k_wprepM<<<21, 256, 0, stream>>>(m1w, m2w, m1b, m2b, pkB, biasSum);
  k_wTb   <<<512, 256, 0, stream>>>(skw, wTb);

  // dilated inception -> Xp (MFMA, channel-minor layout)
  k_incepM<<<NB*NNODE, 256, 0, stream>>>(x, wfA, biasPk, Xp);

  // skip path (MFMA GEMM)
  k_skipM<<<(NB*NNODE)/16, 256, 0, stream>>>(Xp, wTb, skb, xskip, out);

  // hop1, both adjacency sides in one launch
  k_prop<<<2*NB*NNODE, 256, 0, stream>>>(Xp, HA0, HA1, aidx, aval, acnt);

  // hop2 + full mix conv + residual + LN partial sums, single out write
  k_fuse<<<NB*NNODE, 512, 0, stream>>>(Xp, HA0, HA1, out, x, aidx, aval, acnt, pkB, biasSum, part2);

  // layernorm
  k_lnfin<<<1, 32, 0, stream>>>(part2, stats);
  k_lnapply<<<XEL/256, 256, 0, stream>>>(out, stats, lnw, lnb, idxp);
}